// Round 8
// baseline (166.740 us; speedup 1.0000x reference)
//
#include <hip/hip_runtime.h>

// CloudCrop fused MFMA kernel, round 8: 4 blocks/CU (160KB LDS total) made
// spill-free by packing phase-D XR to f16 (frees 64 AGPR across the barrier)
// and deferring rinv to the epilogue. B=2,S=1024,N=10000,C=128,NS=64.

typedef _Float16 f16;
typedef _Float16 f16x8 __attribute__((ext_vector_type(8)));
typedef _Float16 f16x4v __attribute__((ext_vector_type(4)));
typedef float f32x4 __attribute__((ext_vector_type(4)));
typedef unsigned int u32;
typedef u32 u32x2 __attribute__((ext_vector_type(2)));

constexpr int Nn = 10000;
constexpr float RAD2 = 0.05f * 0.05f;
constexpr float HMINf = -0.02f, HMAXf = 0.02f;
constexpr float INVV = 0.99999500003749968747f; // 1/sqrt(1+1e-5)

// ws layout:
//   [0, 376832): 368 weight fragment tiles (1KB: [64 lanes][8 f16])
//     WA 0..79 (mlp, K 131->160; k 0..127=feat, 128..130=xyz), WQ 80..111,
//     WV 112..239, WT 240..367
//   [376832, +5.12MB): upT (B, N, 128) f16
#define UPT_OFF 376832

// s_q (8KB) multiplex offsets (temporally disjoint users):
#define CAND_I   0      // int [4][64]          (phase 0..merge)
#define CAND_X   1024   // f16 [4][64]
#define CAND_Y   1536
#define CAND_Z   2048
#define IDX_OFF  2560   // int [64]             (merge..A)
#define CN4_OFF  2816   // int [4]
#define XYZ_OFF  2848   // f16 [64][32]         (merge..A)
// Q/attT: full [64][128B] from phase B; partials f32[64][8] @0 mid-C.

__device__ __forceinline__ int swzb(int row, int colbyte) {
    return colbyte ^ ((row & 7) << 4);
}

__global__ void prep_kernel(const float* __restrict__ mlp_w,
                            const float* __restrict__ qk_w,
                            const float* __restrict__ v_w,
                            const float* __restrict__ t_w,
                            const float* __restrict__ up,
                            unsigned char* __restrict__ ws) {
    const int blk = blockIdx.x;
    if (blk < 92) {
        const int tid = blk * 256 + threadIdx.x;  // < 368*64
        const int tile = tid >> 6, lane = tid & 63;
        const int ln = lane & 15, kg = lane >> 4;
        f16x8 v;
        if (tile < 80) {
            const int kc = tile / 16, ct = tile % 16;
            const int n = ct * 16 + ln, kb = kc * 32 + kg * 8;
            #pragma unroll
            for (int i = 0; i < 8; ++i) {
                const int k = kb + i;
                float x = (k < 128) ? mlp_w[n * 131 + 3 + k]
                        : ((k < 131) ? mlp_w[n * 131 + (k - 128)] : 0.f);
                v[i] = (f16)x;
            }
        } else if (tile < 112) {
            const int t2 = tile - 80; const int kc = t2 >> 2, ct = t2 & 3;
            const int n = ct * 16 + ln, kb = kc * 32 + kg * 8;
            #pragma unroll
            for (int i = 0; i < 8; ++i) v[i] = (f16)qk_w[n * 256 + kb + i];
        } else if (tile < 240) {
            const int t2 = tile - 112; const int kc = t2 >> 4, ct = t2 & 15;
            const int n = ct * 16 + ln, kb = kc * 32 + kg * 8;
            #pragma unroll
            for (int i = 0; i < 8; ++i) v[i] = (f16)v_w[n * 256 + kb + i];
        } else {
            const int t2 = tile - 240; const int kc = t2 >> 4, ct = t2 & 15;
            const int n = ct * 16 + ln, kb = kc * 32 + kg * 8;
            #pragma unroll
            for (int i = 0; i < 8; ++i) v[i] = (f16)t_w[n * 256 + kb + i];
        }
        *(f16x8*)(ws + (size_t)tid * 16) = v;
    } else {
        __shared__ f16 tile[64 * 136];
        const int bidx = blk - 92;
        const int b = bidx / 157;
        const int n0 = (bidx % 157) * 64;
        const int lane = threadIdx.x & 63;
        const int cw = threadIdx.x >> 6;
        const int n = n0 + lane;
        const float* upb = up + (size_t)b * 128 * Nn;
        #pragma unroll
        for (int i = 0; i < 32; ++i) {
            const int c = cw * 32 + i;
            const float x = (n < Nn) ? upb[(size_t)c * Nn + n] : 0.f;
            tile[lane * 136 + c] = (f16)x;
        }
        __syncthreads();
        f16* dst = (f16*)(ws + UPT_OFF) + (size_t)b * Nn * 128;
        #pragma unroll
        for (int p = 0; p < 4; ++p) {
            const int flat8 = threadIdx.x + p * 256;
            const int row = flat8 >> 4;
            const int c = (flat8 & 15) * 8;
            if (n0 + row < Nn)
                *(f16x8*)(dst + ((size_t)(n0 + row)) * 128 + c) =
                    *(const f16x8*)(tile + row * 136 + c);
        }
    }
}

__launch_bounds__(256, 4)
__global__ void cloudcrop_mfma(
    const float* __restrict__ seed,  // (B,S,3)
    const float* __restrict__ pc,    // (B,N,3)
    const float* __restrict__ rot,   // (B,S,3,3)
    const float* __restrict__ mlp_b,
    const float* __restrict__ bn1g,
    const float* __restrict__ bn1b,
    const float* __restrict__ v_b,
    const float* __restrict__ t_b,
    const float* __restrict__ bn2g,
    const float* __restrict__ bn2b,
    const unsigned char* __restrict__ ws,
    float* __restrict__ out)         // (B,256,S) f32
{
    __shared__ __align__(16) unsigned char s_x[64 * 512]; // X [64][256] f16 swz; Y in-place
    __shared__ __align__(16) unsigned char s_q[8192];     // multiplexed (see map above)

    int*   cand_i  = (int*)(s_q + CAND_I);
    f16*   cand_x  = (f16*)(s_q + CAND_X);
    f16*   cand_y  = (f16*)(s_q + CAND_Y);
    f16*   cand_z  = (f16*)(s_q + CAND_Z);
    int*   idx_s   = (int*)(s_q + IDX_OFF);
    int*   cand_n4 = (int*)(s_q + CN4_OFF);
    f16*   s_xyz   = (f16*)(s_q + XYZ_OFF);   // [64][32]
    float* s_part  = (float*)s_q;             // [64][8] mid-C

    const int grp = blockIdx.x;
    const int bb = grp >> 10;
    const int s  = grp & 1023;
    const int t  = threadIdx.x;
    const int lane = t & 63;
    const int w    = t >> 6;
    const int ln   = lane & 15;
    const int kg   = lane >> 4;
    const int kg16 = kg * 16;
    const int g4   = kg * 4;

    // ---------- Phase 0: selection scan, 4 waves x 2500 pts, 2x unroll ------
    {
        const float sx = seed[grp*3+0], sy = seed[grp*3+1], sz = seed[grp*3+2];
        const float R0 = rot[grp*9+0], R1 = rot[grp*9+1], R2 = rot[grp*9+2];
        const float R3 = rot[grp*9+3], R4 = rot[grp*9+4], R5 = rot[grp*9+5];
        const float R6 = rot[grp*9+6], R7 = rot[grp*9+7], R8 = rot[grp*9+8];
        const unsigned long long lmask = (1ull << lane) - 1ull;
        int count = 0;
        const int lo = w * 2500, hi = lo + 2500;
        for (int base = lo; base < hi; base += 128) {
            const int n0i = base + lane, n1i = base + 64 + lane;
            bool m0 = false, m1 = false;
            float rx0=0.f, ry0=0.f, rz0=0.f, rx1=0.f, ry1=0.f, rz1=0.f;
            if (n0i < hi) {
                const float px = pc[(bb*Nn + n0i)*3+0] - sx;
                const float py = pc[(bb*Nn + n0i)*3+1] - sy;
                const float pz = pc[(bb*Nn + n0i)*3+2] - sz;
                rx0 = px*R0 + py*R3 + pz*R6;
                ry0 = px*R1 + py*R4 + pz*R7;
                rz0 = px*R2 + py*R5 + pz*R8;
                m0 = (ry0*ry0 + rz0*rz0 < RAD2) && (rx0 > HMINf) && (rx0 < HMAXf);
            }
            if (n1i < hi) {
                const float px = pc[(bb*Nn + n1i)*3+0] - sx;
                const float py = pc[(bb*Nn + n1i)*3+1] - sy;
                const float pz = pc[(bb*Nn + n1i)*3+2] - sz;
                rx1 = px*R0 + py*R3 + pz*R6;
                ry1 = px*R1 + py*R4 + pz*R7;
                rz1 = px*R2 + py*R5 + pz*R8;
                m1 = (ry1*ry1 + rz1*rz1 < RAD2) && (rx1 > HMINf) && (rx1 < HMAXf);
            }
            const unsigned long long bal0 = __ballot(m0);
            const unsigned long long bal1 = __ballot(m1);
            const int c0 = __popcll(bal0);
            const int pos0 = count + __popcll(bal0 & lmask);
            const int pos1 = count + c0 + __popcll(bal1 & lmask);
            if (m0 && pos0 < 64) {
                cand_i[w*64 + pos0] = n0i;
                cand_x[w*64 + pos0] = (f16)rx0; cand_y[w*64 + pos0] = (f16)ry0;
                cand_z[w*64 + pos0] = (f16)rz0;
            }
            if (m1 && pos1 < 64) {
                cand_i[w*64 + pos1] = n1i;
                cand_x[w*64 + pos1] = (f16)rx1; cand_y[w*64 + pos1] = (f16)ry1;
                cand_z[w*64 + pos1] = (f16)rz1;
            }
            count += c0 + __popcll(bal1);
        }
        if (lane == 0) cand_n4[w] = count < 64 ? count : 64;
    }
    __syncthreads();

    // ---------- Merge (ordered) -> idx_s + xyz tile -------------------------
    if (t < 64) {
        const int c0 = cand_n4[0], c1 = cand_n4[1], c2 = cand_n4[2], c3 = cand_n4[3];
        const int o1 = c0, o2 = c0 + c1, o3 = o2 + c2;
        int total = o3 + c3; if (total > 64) total = 64;
        int myi; f16 hx, hy, hz;
        if (total > 0) {
            const int pp = (t < total) ? t : 0;
            int sw_, sq;
            if      (pp >= o3) { sw_ = 3; sq = pp - o3; }
            else if (pp >= o2) { sw_ = 2; sq = pp - o2; }
            else if (pp >= o1) { sw_ = 1; sq = pp - o1; }
            else               { sw_ = 0; sq = pp; }
            myi = cand_i[sw_*64 + sq];
            hx = cand_x[sw_*64 + sq]; hy = cand_y[sw_*64 + sq]; hz = cand_z[sw_*64 + sq];
        } else {
            const float sx = seed[grp*3+0], sy = seed[grp*3+1], sz = seed[grp*3+2];
            const float px = pc[(bb*Nn)*3+0] - sx;
            const float py = pc[(bb*Nn)*3+1] - sy;
            const float pz = pc[(bb*Nn)*3+2] - sz;
            hx = (f16)(px*rot[grp*9+0] + py*rot[grp*9+3] + pz*rot[grp*9+6]);
            hy = (f16)(px*rot[grp*9+1] + py*rot[grp*9+4] + pz*rot[grp*9+7]);
            hz = (f16)(px*rot[grp*9+2] + py*rot[grp*9+5] + pz*rot[grp*9+8]);
            myi = 0;
        }
        idx_s[t] = myi;
        f16x8 z0 = {};
        z0[0] = hx; z0[1] = hy; z0[2] = hz;
        f16x8 zz = {};
        f16x8* xr = (f16x8*)(s_xyz + t * 32);
        xr[0] = z0; xr[1] = zz; xr[2] = zz; xr[3] = zz;
    }
    __syncthreads();

    // ---------- Phase A (swapped): H = WA @ [feat|xyz]^T -> X ---------------
    {
        int idxr[4];
        #pragma unroll
        for (int nt = 0; nt < 4; ++nt) idxr[nt] = idx_s[nt*16 + ln];
        const f16* upTb = (const f16*)(ws + UPT_OFF) + (size_t)bb * Nn * 128;

        f32x4 acc[4][4] = {};   // [ch-tile jt][sample-tile nt]
        #pragma unroll
        for (int kc = 0; kc < 4; ++kc) {
            f16x8 bX[4];
            #pragma unroll
            for (int nt = 0; nt < 4; ++nt)
                bX[nt] = *(const f16x8*)(upTb + (size_t)idxr[nt]*128 + kc*32 + kg*8);
            #pragma unroll
            for (int jt = 0; jt < 4; ++jt) {
                const f16x8 aw = *(const f16x8*)(ws + (size_t)(kc*16 + 4*w + jt)*1024 + lane*16);
                #pragma unroll
                for (int nt = 0; nt < 4; ++nt)
                    acc[jt][nt] = __builtin_amdgcn_mfma_f32_16x16x32_f16(aw, bX[nt], acc[jt][nt], 0, 0, 0);
            }
        }
        {   // kc = 4: xyz from LDS
            f16x8 bX[4];
            #pragma unroll
            for (int nt = 0; nt < 4; ++nt)
                bX[nt] = *(const f16x8*)(s_xyz + (nt*16 + ln)*32 + kg*8);
            #pragma unroll
            for (int jt = 0; jt < 4; ++jt) {
                const f16x8 aw = *(const f16x8*)(ws + (size_t)(64 + 4*w + jt)*1024 + lane*16);
                #pragma unroll
                for (int nt = 0; nt < 4; ++nt)
                    acc[jt][nt] = __builtin_amdgcn_mfma_f32_16x16x32_f16(aw, bX[nt], acc[jt][nt], 0, 0, 0);
            }
        }
        #pragma unroll
        for (int jt = 0; jt < 4; ++jt) {
            const int chb = (4*w + jt)*16 + g4;
            const f32x4 mb4 = *(const f32x4*)(mlp_b + chb);
            const f32x4 g14 = *(const f32x4*)(bn1g + chb);
            const f32x4 b14 = *(const f32x4*)(bn1b + chb);
            #pragma unroll
            for (int nt = 0; nt < 4; ++nt) {
                const int smp = nt*16 + ln;
                f16x4v hv;
                #pragma unroll
                for (int r = 0; r < 4; ++r)
                    hv[r] = (f16)fmaxf((acc[jt][nt][r] + mb4[r]) * (g14[r]*INVV) + b14[r], 0.f);
                *(f16x4v*)(s_x + smp*512 + swzb(smp, chb*2)) = hv;
            }
        }
    }
    __syncthreads();   // also covers s_q reuse: xyz/cand dead, Q next

    // ---------- Phase B (swapped): Q = WQ @ X^T -> Q[smp][qch] --------------
    {
        f32x4 accq[4] = {};   // [nt]
        #pragma unroll
        for (int kc = 0; kc < 8; ++kc) {
            const f16x8 aw = *(const f16x8*)(ws + (size_t)(80 + kc*4 + w)*1024 + lane*16);
            #pragma unroll
            for (int nt = 0; nt < 4; ++nt) {
                const int row = nt*16 + ln;
                const f16x8 bX = *(const f16x8*)(s_x + row*512 + swzb(row, kc*64 + kg16));
                accq[nt] = __builtin_amdgcn_mfma_f32_16x16x32_f16(aw, bX, accq[nt], 0, 0, 0);
            }
        }
        const int qb = (w*16 + g4) * 2;   // byte offset of 4 consec qch
        #pragma unroll
        for (int nt = 0; nt < 4; ++nt) {
            const int smp = nt*16 + ln;
            f16x4v pk;
            #pragma unroll
            for (int r = 0; r < 4; ++r) pk[r] = (f16)accq[nt][r];
            *(f16x4v*)(s_q + smp*128 + swzb(smp, qb)) = pk;
        }
    }
    __syncthreads();

    // ---------- Phase C: S = Q @ Q^T; partial softmax (s_q-resident) --------
    f32x4 accs[4];
    {
        #pragma unroll
        for (int rt = 0; rt < 4; ++rt) accs[rt] = (f32x4){0.f,0.f,0.f,0.f};
        #pragma unroll
        for (int kc = 0; kc < 2; ++kc) {
            const int rowb = w*16 + ln;
            const f16x8 bQ = *(const f16x8*)(s_q + rowb*128 + swzb(rowb, kc*64 + kg16));
            #pragma unroll
            for (int rt = 0; rt < 4; ++rt) {
                const int row = rt*16 + ln;
                const f16x8 aQ = *(const f16x8*)(s_q + row*128 + swzb(row, kc*64 + kg16));
                accs[rt] = __builtin_amdgcn_mfma_f32_16x16x32_f16(aQ, bQ, accs[rt], 0, 0, 0);
            }
        }
    }
    __syncthreads();   // all Q reads done before partials overwrite s_q[0..2K)
    {
        float pm[4][4];
        #pragma unroll
        for (int rt = 0; rt < 4; ++rt)
            #pragma unroll
            for (int r = 0; r < 4; ++r) {
                float v = accs[rt][r];
                float mx = fmaxf(v, __shfl_xor(v, 1));
                mx = fmaxf(mx, __shfl_xor(mx, 2));
                mx = fmaxf(mx, __shfl_xor(mx, 4));
                mx = fmaxf(mx, __shfl_xor(mx, 8));
                pm[rt][r] = mx;
                const float e = __expf(v - mx);
                accs[rt][r] = e;
                float sm = e + __shfl_xor(e, 1);
                sm += __shfl_xor(sm, 2);
                sm += __shfl_xor(sm, 4);
                sm += __shfl_xor(sm, 8);
                if (ln == 0) {
                    const int row = rt*16 + g4 + r;
                    s_part[row*8 + w*2 + 0] = mx;
                    s_part[row*8 + w*2 + 1] = sm;
                }
            }
        __syncthreads();
        float sc[4][4];
        #pragma unroll
        for (int rt = 0; rt < 4; ++rt)
            #pragma unroll
            for (int r = 0; r < 4; ++r) {
                const int row = rt*16 + g4 + r;    // same addr across ln: broadcast
                const f32x4 pa = *(const f32x4*)(s_part + row*8);
                const f32x4 pb = *(const f32x4*)(s_part + row*8 + 4);
                const float fm = fmaxf(fmaxf(pa.x, pa.z), fmaxf(pb.x, pb.z));
                const float den = pa.y*__expf(pa.x - fm) + pa.w*__expf(pa.z - fm)
                                + pb.y*__expf(pb.x - fm) + pb.w*__expf(pb.z - fm);
                sc[rt][r] = __expf(pm[rt][r] - fm) / den;
            }
        __syncthreads();   // partials consumed before attT overwrites s_q
        const int arow = w*16 + ln;
        #pragma unroll
        for (int rt = 0; rt < 4; ++rt) {
            f16x4v pk;
            #pragma unroll
            for (int r = 0; r < 4; ++r) pk[r] = (f16)(accs[rt][r] * sc[rt][r]);
            *(f16x4v*)(s_q + arow*128 + swzb(arow, (rt*16 + g4)*2)) = pk;
        }
    }
    __syncthreads();

    // ---------- Phase D: V=X@WV+vb; shfl transpose; XR=attT@V -> f16 regs ---
    u32 xrpk[4][4][2];   // [j][rt][pair] f16x2, XR unscaled
    float rinv[4][4];
    {
        f16x8 a2[2][4];
        #pragma unroll
        for (int kc = 0; kc < 2; ++kc)
            #pragma unroll
            for (int rt = 0; rt < 4; ++rt) {
                const int row = rt*16 + ln;
                a2[kc][rt] = *(const f16x8*)(s_q + row*128 + swzb(row, kc*64 + kg16));
            }

        const int sbase = ln + ((lane >> 4) & 1) * 32;   // shfl src base
        const bool hiHalf = (kg >= 2);
        #pragma unroll
        for (int j = 0; j < 4; ++j) {
            const float vb = v_b[(4*w + j)*16 + ln];
            f32x4 accv[4] = {};
            #pragma unroll 2
            for (int kc = 0; kc < 8; ++kc) {
                const f16x8 bf = *(const f16x8*)(ws + (size_t)(112 + kc*16 + 4*w + j)*1024 + lane*16);
                #pragma unroll
                for (int rt = 0; rt < 4; ++rt) {
                    const int row = rt*16 + ln;
                    const f16x8 aX = *(const f16x8*)(s_x + row*512 + swzb(row, kc*64 + kg16));
                    accv[rt] = __builtin_amdgcn_mfma_f32_16x16x32_f16(aX, bf, accv[rt], 0, 0, 0);
                }
            }
            // pack V to f16 pairs: pk[rt][p] = samples rt*16+g4+{2p,2p+1}
            u32 pk[4][2];
            #pragma unroll
            for (int rt = 0; rt < 4; ++rt) {
                f16x4v v4;
                #pragma unroll
                for (int r = 0; r < 4; ++r) v4[r] = (f16)(accv[rt][r] + vb);
                const u32x2 p2 = __builtin_bit_cast(u32x2, v4);
                pk[rt][0] = p2.x; pk[rt][1] = p2.y;
            }
            // route + XR MFMAs, result packed to f16 immediately
            f32x4 accrj[4] = {};
            #pragma unroll
            for (int kc = 0; kc < 2; ++kc) {
                union { u32 u[4]; f16x8 v; } bu;
                #pragma unroll
                for (int q = 0; q < 4; ++q) {
                    const int srcl = sbase + 16*(q >> 1);
                    const u32 lo = (u32)__shfl((int)pk[2*kc + 0][q & 1], srcl);
                    const u32 hi = (u32)__shfl((int)pk[2*kc + 1][q & 1], srcl);
                    bu.u[q] = hiHalf ? hi : lo;
                }
                #pragma unroll
                for (int rt = 0; rt < 4; ++rt)
                    accrj[rt] = __builtin_amdgcn_mfma_f32_16x16x32_f16(a2[kc][rt], bu.v, accrj[rt], 0, 0, 0);
            }
            #pragma unroll
            for (int rt = 0; rt < 4; ++rt) {
                f16x4v v4;
                #pragma unroll
                for (int r = 0; r < 4; ++r) v4[r] = (f16)accrj[rt][r];
                const u32x2 p2 = __builtin_bit_cast(u32x2, v4);
                xrpk[j][rt][0] = p2.x; xrpk[j][rt][1] = p2.y;
            }
        }
        // colsum via ones-MFMA, after j-loop (keeps it out of peak pressure)
        {
            f16x8 onef;
            #pragma unroll
            for (int i = 0; i < 8; ++i) onef[i] = (f16)1.0f;
            f32x4 accONE[4];
            #pragma unroll
            for (int rt = 0; rt < 4; ++rt) accONE[rt] = (f32x4){0.f,0.f,0.f,0.f};
            #pragma unroll
            for (int kc = 0; kc < 2; ++kc)
                #pragma unroll
                for (int rt = 0; rt < 4; ++rt)
                    accONE[rt] = __builtin_amdgcn_mfma_f32_16x16x32_f16(a2[kc][rt], onef, accONE[rt], 0, 0, 0);
            #pragma unroll
            for (int rt = 0; rt < 4; ++rt)
                #pragma unroll
                for (int r = 0; r < 4; ++r)
                    rinv[rt][r] = __builtin_amdgcn_rcpf(1e-9f + accONE[rt][r]);
        }
    }
    __syncthreads();  // all waves' X reads done before Y overwrite

    // ---------- D-epilogue: Y = X - XR*rinv (in-place), keep X in regs ------
    f16x4v xsave[4][4];
    #pragma unroll
    for (int j = 0; j < 4; ++j) {
        const int col = (4*w + j)*16 + ln;
        #pragma unroll
        for (int rt = 0; rt < 4; ++rt) {
            const u32x2 p2 = { xrpk[j][rt][0], xrpk[j][rt][1] };
            const f16x4v xr4 = __builtin_bit_cast(f16x4v, p2);
            f16x4v xs4;
            #pragma unroll
            for (int r = 0; r < 4; ++r) {
                const int row = rt*16 + g4 + r;
                const f16 xv = *(const f16*)(s_x + row*512 + swzb(row, col*2));
                xs4[r] = xv;
                const float yv = (float)xv - (float)xr4[r] * rinv[rt][r];
                *(f16*)(s_x + row*512 + swzb(row, col*2)) = (f16)yv;
            }
            xsave[j][rt] = xs4;
        }
    }
    __syncthreads();

    // ---------- Phase E: T = Y @ WT + t_b; out = maxpool(X + relu(BN2)) -----
    {
        f32x4 acct[4][4] = {};
        #pragma unroll 2
        for (int kc = 0; kc < 8; ++kc) {
            f16x8 a[4];
            #pragma unroll
            for (int rt = 0; rt < 4; ++rt) {
                const int row = rt*16 + ln;
                a[rt] = *(const f16x8*)(s_x + row*512 + swzb(row, kc*64 + kg16));  // Y
            }
            #pragma unroll
            for (int j = 0; j < 4; ++j) {
                const f16x8 bf = *(const f16x8*)(ws + (size_t)(240 + kc*16 + 4*w + j)*1024 + lane*16);
                #pragma unroll
                for (int rt = 0; rt < 4; ++rt)
                    acct[rt][j] = __builtin_amdgcn_mfma_f32_16x16x32_f16(a[rt], bf, acct[rt][j], 0, 0, 0);
            }
        }
        #pragma unroll
        for (int j = 0; j < 4; ++j) {
            const int col = (4*w + j)*16 + ln;
            const float tb = t_b[col], g2 = bn2g[col]*INVV, b2 = bn2b[col];
            float m = -3.4e38f;
            #pragma unroll
            for (int rt = 0; rt < 4; ++rt)
                #pragma unroll
                for (int r = 0; r < 4; ++r) {
                    const float tv = acct[rt][j][r] + tb;
                    const float rl = fmaxf(tv*g2 + b2, 0.f);
                    const float xv = (float)xsave[j][rt][r];
                    m = fmaxf(m, xv + rl);
                }
            m = fmaxf(m, __shfl_xor(m, 16));
            m = fmaxf(m, __shfl_xor(m, 32));
            if (kg == 0)
                out[((size_t)bb*256 + col)*1024 + s] = m;
        }
    }
}

extern "C" void kernel_launch(void* const* d_in, const int* in_sizes, int n_in,
                              void* d_out, int out_size, void* d_ws, size_t ws_size,
                              hipStream_t stream) {
    (void)in_sizes; (void)n_in; (void)out_size; (void)ws_size;
    unsigned char* ws = (unsigned char*)d_ws;
    prep_kernel<<<92 + 314, 256, 0, stream>>>(
        (const float*)d_in[4],   // mlp_w
        (const float*)d_in[8],   // qk_w
        (const float*)d_in[9],   // v_w
        (const float*)d_in[11],  // t_w
        (const float*)d_in[3],   // up_feature
        ws);
    cloudcrop_mfma<<<2048, 256, 0, stream>>>(
        (const float*)d_in[0],   // seed_xyz
        (const float*)d_in[1],   // pointcloud
        (const float*)d_in[2],   // vp_rot
        (const float*)d_in[5],   // mlp_b
        (const float*)d_in[6],   // bn1_g
        (const float*)d_in[7],   // bn1_b
        (const float*)d_in[10],  // v_b
        (const float*)d_in[12],  // t_b
        (const float*)d_in[13],  // bn2_g
        (const float*)d_in[14],  // bn2_b
        ws,
        (float*)d_out);
}

// Round 9
// 124.072 us; speedup vs baseline: 1.3439x; 1.3439x over previous
//
#include <hip/hip_runtime.h>

// CloudCrop fused MFMA kernel, round 9: R7 register schedule (spill-free,
// 3 blocks/CU) + in-wave softmax (wave owns 16-row strip of S; no cross-wave
// partial exchange, 2 fewer barriers). B=2,S=1024,N=10000,C=128,NS=64.

typedef _Float16 f16;
typedef _Float16 f16x8 __attribute__((ext_vector_type(8)));
typedef _Float16 f16x4v __attribute__((ext_vector_type(4)));
typedef float f32x4 __attribute__((ext_vector_type(4)));
typedef unsigned int u32;
typedef u32 u32x2 __attribute__((ext_vector_type(2)));

constexpr int Nn = 10000;
constexpr float RAD2 = 0.05f * 0.05f;
constexpr float HMINf = -0.02f, HMAXf = 0.02f;
constexpr float INVV = 0.99999500003749968747f; // 1/sqrt(1+1e-5)

// ws layout:
//   [0, 376832): 368 weight fragment tiles (1KB: [64 lanes][8 f16])
//     WA 0..79 (mlp, K 131->160; k 0..127=feat, 128..130=xyz), WQ 80..111,
//     WV 112..239, WT 240..367
//   [376832, +5.12MB): upT (B, N, 128) f16
#define UPT_OFF 376832

// s_q (8KB) multiplex offsets (temporally disjoint users):
#define CAND_I   0      // int [4][64]          (phase 0..merge)
#define CAND_X   1024   // f16 [4][64]
#define CAND_Y   1536
#define CAND_Z   2048
#define IDX_OFF  2560   // int [64]             (merge..A)
#define CN4_OFF  2816   // int [4]
#define XYZ_OFF  2848   // f16 [64][32]         (merge..A)
// Q then attT: full [64][128B] from phase B onward.

__device__ __forceinline__ int swzb(int row, int colbyte) {
    return colbyte ^ ((row & 7) << 4);
}

__global__ void prep_kernel(const float* __restrict__ mlp_w,
                            const float* __restrict__ qk_w,
                            const float* __restrict__ v_w,
                            const float* __restrict__ t_w,
                            const float* __restrict__ up,
                            unsigned char* __restrict__ ws) {
    const int blk = blockIdx.x;
    if (blk < 92) {
        const int tid = blk * 256 + threadIdx.x;  // < 368*64
        const int tile = tid >> 6, lane = tid & 63;
        const int ln = lane & 15, kg = lane >> 4;
        f16x8 v;
        if (tile < 80) {
            const int kc = tile / 16, ct = tile % 16;
            const int n = ct * 16 + ln, kb = kc * 32 + kg * 8;
            #pragma unroll
            for (int i = 0; i < 8; ++i) {
                const int k = kb + i;
                float x = (k < 128) ? mlp_w[n * 131 + 3 + k]
                        : ((k < 131) ? mlp_w[n * 131 + (k - 128)] : 0.f);
                v[i] = (f16)x;
            }
        } else if (tile < 112) {
            const int t2 = tile - 80; const int kc = t2 >> 2, ct = t2 & 3;
            const int n = ct * 16 + ln, kb = kc * 32 + kg * 8;
            #pragma unroll
            for (int i = 0; i < 8; ++i) v[i] = (f16)qk_w[n * 256 + kb + i];
        } else if (tile < 240) {
            const int t2 = tile - 112; const int kc = t2 >> 4, ct = t2 & 15;
            const int n = ct * 16 + ln, kb = kc * 32 + kg * 8;
            #pragma unroll
            for (int i = 0; i < 8; ++i) v[i] = (f16)v_w[n * 256 + kb + i];
        } else {
            const int t2 = tile - 240; const int kc = t2 >> 4, ct = t2 & 15;
            const int n = ct * 16 + ln, kb = kc * 32 + kg * 8;
            #pragma unroll
            for (int i = 0; i < 8; ++i) v[i] = (f16)t_w[n * 256 + kb + i];
        }
        *(f16x8*)(ws + (size_t)tid * 16) = v;
    } else {
        __shared__ f16 tile[64 * 136];
        const int bidx = blk - 92;
        const int b = bidx / 157;
        const int n0 = (bidx % 157) * 64;
        const int lane = threadIdx.x & 63;
        const int cw = threadIdx.x >> 6;
        const int n = n0 + lane;
        const float* upb = up + (size_t)b * 128 * Nn;
        #pragma unroll
        for (int i = 0; i < 32; ++i) {
            const int c = cw * 32 + i;
            const float x = (n < Nn) ? upb[(size_t)c * Nn + n] : 0.f;
            tile[lane * 136 + c] = (f16)x;
        }
        __syncthreads();
        f16* dst = (f16*)(ws + UPT_OFF) + (size_t)b * Nn * 128;
        #pragma unroll
        for (int p = 0; p < 4; ++p) {
            const int flat8 = threadIdx.x + p * 256;
            const int row = flat8 >> 4;
            const int c = (flat8 & 15) * 8;
            if (n0 + row < Nn)
                *(f16x8*)(dst + ((size_t)(n0 + row)) * 128 + c) =
                    *(const f16x8*)(tile + row * 136 + c);
        }
    }
}

__launch_bounds__(256, 3)
__global__ void cloudcrop_mfma(
    const float* __restrict__ seed,  // (B,S,3)
    const float* __restrict__ pc,    // (B,N,3)
    const float* __restrict__ rot,   // (B,S,3,3)
    const float* __restrict__ mlp_b,
    const float* __restrict__ bn1g,
    const float* __restrict__ bn1b,
    const float* __restrict__ v_b,
    const float* __restrict__ t_b,
    const float* __restrict__ bn2g,
    const float* __restrict__ bn2b,
    const unsigned char* __restrict__ ws,
    float* __restrict__ out)         // (B,256,S) f32
{
    __shared__ __align__(16) unsigned char s_x[64 * 512]; // X [64][256] f16 swz; Y in-place
    __shared__ __align__(16) unsigned char s_q[8192];     // multiplexed (see map above)

    int*   cand_i  = (int*)(s_q + CAND_I);
    f16*   cand_x  = (f16*)(s_q + CAND_X);
    f16*   cand_y  = (f16*)(s_q + CAND_Y);
    f16*   cand_z  = (f16*)(s_q + CAND_Z);
    int*   idx_s   = (int*)(s_q + IDX_OFF);
    int*   cand_n4 = (int*)(s_q + CN4_OFF);
    f16*   s_xyz   = (f16*)(s_q + XYZ_OFF);   // [64][32]

    const int grp = blockIdx.x;
    const int bb = grp >> 10;
    const int s  = grp & 1023;
    const int t  = threadIdx.x;
    const int lane = t & 63;
    const int w    = t >> 6;
    const int ln   = lane & 15;
    const int kg   = lane >> 4;
    const int kg16 = kg * 16;
    const int g4   = kg * 4;

    // ---------- Phase 0: selection scan, 4 waves x 2500 pts, 2x unroll ------
    {
        const float sx = seed[grp*3+0], sy = seed[grp*3+1], sz = seed[grp*3+2];
        const float R0 = rot[grp*9+0], R1 = rot[grp*9+1], R2 = rot[grp*9+2];
        const float R3 = rot[grp*9+3], R4 = rot[grp*9+4], R5 = rot[grp*9+5];
        const float R6 = rot[grp*9+6], R7 = rot[grp*9+7], R8 = rot[grp*9+8];
        const unsigned long long lmask = (1ull << lane) - 1ull;
        int count = 0;
        const int lo = w * 2500, hi = lo + 2500;
        for (int base = lo; base < hi; base += 128) {
            const int n0i = base + lane, n1i = base + 64 + lane;
            bool m0 = false, m1 = false;
            float rx0=0.f, ry0=0.f, rz0=0.f, rx1=0.f, ry1=0.f, rz1=0.f;
            if (n0i < hi) {
                const float px = pc[(bb*Nn + n0i)*3+0] - sx;
                const float py = pc[(bb*Nn + n0i)*3+1] - sy;
                const float pz = pc[(bb*Nn + n0i)*3+2] - sz;
                rx0 = px*R0 + py*R3 + pz*R6;
                ry0 = px*R1 + py*R4 + pz*R7;
                rz0 = px*R2 + py*R5 + pz*R8;
                m0 = (ry0*ry0 + rz0*rz0 < RAD2) && (rx0 > HMINf) && (rx0 < HMAXf);
            }
            if (n1i < hi) {
                const float px = pc[(bb*Nn + n1i)*3+0] - sx;
                const float py = pc[(bb*Nn + n1i)*3+1] - sy;
                const float pz = pc[(bb*Nn + n1i)*3+2] - sz;
                rx1 = px*R0 + py*R3 + pz*R6;
                ry1 = px*R1 + py*R4 + pz*R7;
                rz1 = px*R2 + py*R5 + pz*R8;
                m1 = (ry1*ry1 + rz1*rz1 < RAD2) && (rx1 > HMINf) && (rx1 < HMAXf);
            }
            const unsigned long long bal0 = __ballot(m0);
            const unsigned long long bal1 = __ballot(m1);
            const int c0 = __popcll(bal0);
            const int pos0 = count + __popcll(bal0 & lmask);
            const int pos1 = count + c0 + __popcll(bal1 & lmask);
            if (m0 && pos0 < 64) {
                cand_i[w*64 + pos0] = n0i;
                cand_x[w*64 + pos0] = (f16)rx0; cand_y[w*64 + pos0] = (f16)ry0;
                cand_z[w*64 + pos0] = (f16)rz0;
            }
            if (m1 && pos1 < 64) {
                cand_i[w*64 + pos1] = n1i;
                cand_x[w*64 + pos1] = (f16)rx1; cand_y[w*64 + pos1] = (f16)ry1;
                cand_z[w*64 + pos1] = (f16)rz1;
            }
            count += c0 + __popcll(bal1);
        }
        if (lane == 0) cand_n4[w] = count < 64 ? count : 64;
    }
    __syncthreads();

    // ---------- Merge (ordered) -> idx_s + xyz tile -------------------------
    if (t < 64) {
        const int c0 = cand_n4[0], c1 = cand_n4[1], c2 = cand_n4[2], c3 = cand_n4[3];
        const int o1 = c0, o2 = c0 + c1, o3 = o2 + c2;
        int total = o3 + c3; if (total > 64) total = 64;
        int myi; f16 hx, hy, hz;
        if (total > 0) {
            const int pp = (t < total) ? t : 0;
            int sw_, sq;
            if      (pp >= o3) { sw_ = 3; sq = pp - o3; }
            else if (pp >= o2) { sw_ = 2; sq = pp - o2; }
            else if (pp >= o1) { sw_ = 1; sq = pp - o1; }
            else               { sw_ = 0; sq = pp; }
            myi = cand_i[sw_*64 + sq];
            hx = cand_x[sw_*64 + sq]; hy = cand_y[sw_*64 + sq]; hz = cand_z[sw_*64 + sq];
        } else {
            const float sx = seed[grp*3+0], sy = seed[grp*3+1], sz = seed[grp*3+2];
            const float px = pc[(bb*Nn)*3+0] - sx;
            const float py = pc[(bb*Nn)*3+1] - sy;
            const float pz = pc[(bb*Nn)*3+2] - sz;
            hx = (f16)(px*rot[grp*9+0] + py*rot[grp*9+3] + pz*rot[grp*9+6]);
            hy = (f16)(px*rot[grp*9+1] + py*rot[grp*9+4] + pz*rot[grp*9+7]);
            hz = (f16)(px*rot[grp*9+2] + py*rot[grp*9+5] + pz*rot[grp*9+8]);
            myi = 0;
        }
        idx_s[t] = myi;
        f16x8 z0 = {};
        z0[0] = hx; z0[1] = hy; z0[2] = hz;
        f16x8 zz = {};
        f16x8* xr = (f16x8*)(s_xyz + t * 32);
        xr[0] = z0; xr[1] = zz; xr[2] = zz; xr[3] = zz;
    }
    __syncthreads();

    // ---------- Phase A (swapped): H = WA @ [feat|xyz]^T -> X ---------------
    {
        int idxr[4];
        #pragma unroll
        for (int nt = 0; nt < 4; ++nt) idxr[nt] = idx_s[nt*16 + ln];
        const f16* upTb = (const f16*)(ws + UPT_OFF) + (size_t)bb * Nn * 128;

        f32x4 acc[4][4] = {};   // [ch-tile jt][sample-tile nt]
        #pragma unroll
        for (int kc = 0; kc < 4; ++kc) {
            f16x8 bX[4];
            #pragma unroll
            for (int nt = 0; nt < 4; ++nt)
                bX[nt] = *(const f16x8*)(upTb + (size_t)idxr[nt]*128 + kc*32 + kg*8);
            #pragma unroll
            for (int jt = 0; jt < 4; ++jt) {
                const f16x8 aw = *(const f16x8*)(ws + (size_t)(kc*16 + 4*w + jt)*1024 + lane*16);
                #pragma unroll
                for (int nt = 0; nt < 4; ++nt)
                    acc[jt][nt] = __builtin_amdgcn_mfma_f32_16x16x32_f16(aw, bX[nt], acc[jt][nt], 0, 0, 0);
            }
        }
        {   // kc = 4: xyz from LDS
            f16x8 bX[4];
            #pragma unroll
            for (int nt = 0; nt < 4; ++nt)
                bX[nt] = *(const f16x8*)(s_xyz + (nt*16 + ln)*32 + kg*8);
            #pragma unroll
            for (int jt = 0; jt < 4; ++jt) {
                const f16x8 aw = *(const f16x8*)(ws + (size_t)(64 + 4*w + jt)*1024 + lane*16);
                #pragma unroll
                for (int nt = 0; nt < 4; ++nt)
                    acc[jt][nt] = __builtin_amdgcn_mfma_f32_16x16x32_f16(aw, bX[nt], acc[jt][nt], 0, 0, 0);
            }
        }
        #pragma unroll
        for (int jt = 0; jt < 4; ++jt) {
            const int chb = (4*w + jt)*16 + g4;
            const f32x4 mb4 = *(const f32x4*)(mlp_b + chb);
            const f32x4 g14 = *(const f32x4*)(bn1g + chb);
            const f32x4 b14 = *(const f32x4*)(bn1b + chb);
            #pragma unroll
            for (int nt = 0; nt < 4; ++nt) {
                const int smp = nt*16 + ln;
                f16x4v hv;
                #pragma unroll
                for (int r = 0; r < 4; ++r)
                    hv[r] = (f16)fmaxf((acc[jt][nt][r] + mb4[r]) * (g14[r]*INVV) + b14[r], 0.f);
                *(f16x4v*)(s_x + smp*512 + swzb(smp, chb*2)) = hv;
            }
        }
    }
    __syncthreads();   // also covers s_q reuse: xyz/cand dead, Q next

    // ---------- Phase B (swapped): Q = WQ @ X^T -> Q[smp][qch] --------------
    {
        f32x4 accq[4] = {};   // [nt]
        #pragma unroll
        for (int kc = 0; kc < 8; ++kc) {
            const f16x8 aw = *(const f16x8*)(ws + (size_t)(80 + kc*4 + w)*1024 + lane*16);
            #pragma unroll
            for (int nt = 0; nt < 4; ++nt) {
                const int row = nt*16 + ln;
                const f16x8 bX = *(const f16x8*)(s_x + row*512 + swzb(row, kc*64 + kg16));
                accq[nt] = __builtin_amdgcn_mfma_f32_16x16x32_f16(aw, bX, accq[nt], 0, 0, 0);
            }
        }
        const int qb = (w*16 + g4) * 2;   // byte offset of 4 consec qch
        #pragma unroll
        for (int nt = 0; nt < 4; ++nt) {
            const int smp = nt*16 + ln;
            f16x4v pk;
            #pragma unroll
            for (int r = 0; r < 4; ++r) pk[r] = (f16)accq[nt][r];
            *(f16x4v*)(s_q + smp*128 + swzb(smp, qb)) = pk;
        }
    }
    __syncthreads();

    // ---------- Phase C: wave w owns rows w*16..+15 of S; in-wave softmax ---
    {
        // A-frag: this wave's 16 rows of Q; B-frags: all 4 col-tiles
        f16x8 aQ[2];
        #pragma unroll
        for (int kc = 0; kc < 2; ++kc) {
            const int rowA = w*16 + ln;
            aQ[kc] = *(const f16x8*)(s_q + rowA*128 + swzb(rowA, kc*64 + kg16));
        }
        f32x4 accs[4];  // [ct]: S[w*16 + kg*4 + r][ct*16 + ln]
        #pragma unroll
        for (int ct = 0; ct < 4; ++ct) accs[ct] = (f32x4){0.f,0.f,0.f,0.f};
        #pragma unroll
        for (int kc = 0; kc < 2; ++kc) {
            #pragma unroll
            for (int ct = 0; ct < 4; ++ct) {
                const int rowB = ct*16 + ln;
                const f16x8 bQ = *(const f16x8*)(s_q + rowB*128 + swzb(rowB, kc*64 + kg16));
                accs[ct] = __builtin_amdgcn_mfma_f32_16x16x32_f16(aQ[kc], bQ, accs[ct], 0, 0, 0);
            }
        }
        // in-wave softmax per row r (row's 64 vals: 4 regs x 16 ln-lanes)
        float inv[4];
        #pragma unroll
        for (int r = 0; r < 4; ++r) {
            float mx = fmaxf(fmaxf(accs[0][r], accs[1][r]),
                             fmaxf(accs[2][r], accs[3][r]));
            mx = fmaxf(mx, __shfl_xor(mx, 1));
            mx = fmaxf(mx, __shfl_xor(mx, 2));
            mx = fmaxf(mx, __shfl_xor(mx, 4));
            mx = fmaxf(mx, __shfl_xor(mx, 8));
            float sm = 0.f;
            #pragma unroll
            for (int ct = 0; ct < 4; ++ct) {
                const float e = __expf(accs[ct][r] - mx);
                accs[ct][r] = e; sm += e;
            }
            sm += __shfl_xor(sm, 1);
            sm += __shfl_xor(sm, 2);
            sm += __shfl_xor(sm, 4);
            sm += __shfl_xor(sm, 8);
            inv[r] = 1.0f / sm;
        }
        __syncthreads();   // all waves done reading Q before attT overwrites
        #pragma unroll
        for (int ct = 0; ct < 4; ++ct) {
            const int j = ct*16 + ln;
            #pragma unroll
            for (int r = 0; r < 4; ++r) {
                const int i = w*16 + g4 + r;
                *(f16*)(s_q + j*128 + swzb(j, i*2)) = (f16)(accs[ct][r] * inv[r]);
            }
        }
    }
    __syncthreads();

    // ---------- Phase D: V=X@WV+vb; in-reg transpose via shfl; XR=attT@V ----
    f32x4 accr[4][4];
    float rinv[4][4];
    {
        f16x8 a2[2][4];
        #pragma unroll
        for (int kc = 0; kc < 2; ++kc)
            #pragma unroll
            for (int rt = 0; rt < 4; ++rt) {
                const int row = rt*16 + ln;
                a2[kc][rt] = *(const f16x8*)(s_q + row*128 + swzb(row, kc*64 + kg16));
            }
        // colsum via ones-MFMA, converted to rinv immediately (frees accONE)
        {
            f16x8 onef;
            #pragma unroll
            for (int i = 0; i < 8; ++i) onef[i] = (f16)1.0f;
            f32x4 accONE[4];
            #pragma unroll
            for (int rt = 0; rt < 4; ++rt) accONE[rt] = (f32x4){0.f,0.f,0.f,0.f};
            #pragma unroll
            for (int kc = 0; kc < 2; ++kc)
                #pragma unroll
                for (int rt = 0; rt < 4; ++rt)
                    accONE[rt] = __builtin_amdgcn_mfma_f32_16x16x32_f16(a2[kc][rt], onef, accONE[rt], 0, 0, 0);
            #pragma unroll
            for (int rt = 0; rt < 4; ++rt)
                #pragma unroll
                for (int r = 0; r < 4; ++r)
                    rinv[rt][r] = __builtin_amdgcn_rcpf(1e-9f + accONE[rt][r]);
        }

        #pragma unroll
        for (int rt = 0; rt < 4; ++rt)
            #pragma unroll
            for (int j = 0; j < 4; ++j) accr[rt][j] = (f32x4){0.f,0.f,0.f,0.f};

        const int sbase = ln + ((lane >> 4) & 1) * 32;   // shfl src base
        const bool hiHalf = (kg >= 2);
        #pragma unroll
        for (int j = 0; j < 4; ++j) {
            const float vb = v_b[(4*w + j)*16 + ln];
            f32x4 accv[4] = {};
            #pragma unroll 2
            for (int kc = 0; kc < 8; ++kc) {
                const f16x8 bf = *(const f16x8*)(ws + (size_t)(112 + kc*16 + 4*w + j)*1024 + lane*16);
                #pragma unroll
                for (int rt = 0; rt < 4; ++rt) {
                    const int row = rt*16 + ln;
                    const f16x8 aX = *(const f16x8*)(s_x + row*512 + swzb(row, kc*64 + kg16));
                    accv[rt] = __builtin_amdgcn_mfma_f32_16x16x32_f16(aX, bf, accv[rt], 0, 0, 0);
                }
            }
            // pack to f16 pairs: pk[rt][p] = samples rt*16+g4+{2p,2p+1}
            u32 pk[4][2];
            #pragma unroll
            for (int rt = 0; rt < 4; ++rt) {
                f16x4v v4;
                #pragma unroll
                for (int r = 0; r < 4; ++r) v4[r] = (f16)(accv[rt][r] + vb);
                const u32x2 p2 = __builtin_bit_cast(u32x2, v4);
                pk[rt][0] = p2.x; pk[rt][1] = p2.y;
            }
            // route: B-frag reg q <- lane (sbase + 16*(q>>1)), pk[2kc+(kg>>1)][q&1]
            #pragma unroll
            for (int kc = 0; kc < 2; ++kc) {
                union { u32 u[4]; f16x8 v; } bu;
                #pragma unroll
                for (int q = 0; q < 4; ++q) {
                    const int srcl = sbase + 16*(q >> 1);
                    const u32 lo = (u32)__shfl((int)pk[2*kc + 0][q & 1], srcl);
                    const u32 hi = (u32)__shfl((int)pk[2*kc + 1][q & 1], srcl);
                    bu.u[q] = hiHalf ? hi : lo;
                }
                #pragma unroll
                for (int rt = 0; rt < 4; ++rt)
                    accr[rt][j] = __builtin_amdgcn_mfma_f32_16x16x32_f16(a2[kc][rt], bu.v, accr[rt][j], 0, 0, 0);
            }
        }
    }
    __syncthreads();  // all waves' X reads done before Y overwrite

    // ---------- D-epilogue: Y = X - XR*rinv (in-place), keep X in regs ------
    f16x4v xsave[4][4];
    #pragma unroll
    for (int j = 0; j < 4; ++j) {
        const int col = (4*w + j)*16 + ln;
        #pragma unroll
        for (int rt = 0; rt < 4; ++rt) {
            f16x4v xs4;
            #pragma unroll
            for (int r = 0; r < 4; ++r) {
                const int row = rt*16 + g4 + r;
                const f16 xv = *(const f16*)(s_x + row*512 + swzb(row, col*2));
                xs4[r] = xv;
                const float yv = (float)xv - accr[rt][j][r] * rinv[rt][r];
                *(f16*)(s_x + row*512 + swzb(row, col*2)) = (f16)yv;
            }
            xsave[j][rt] = xs4;
        }
    }
    __syncthreads();

    // ---------- Phase E: T = Y @ WT + t_b; out = maxpool(X + relu(BN2)) -----
    {
        f32x4 acct[4][4] = {};
        #pragma unroll 2
        for (int kc = 0; kc < 8; ++kc) {
            f16x8 a[4];
            #pragma unroll
            for (int rt = 0; rt < 4; ++rt) {
                const int row = rt*16 + ln;
                a[rt] = *(const f16x8*)(s_x + row*512 + swzb(row, kc*64 + kg16));  // Y
            }
            #pragma unroll
            for (int j = 0; j < 4; ++j) {
                const f16x8 bf = *(const f16x8*)(ws + (size_t)(240 + kc*16 + 4*w + j)*1024 + lane*16);
                #pragma unroll
                for (int rt = 0; rt < 4; ++rt)
                    acct[rt][j] = __builtin_amdgcn_mfma_f32_16x16x32_f16(a[rt], bf, acct[rt][j], 0, 0, 0);
            }
        }
        #pragma unroll
        for (int j = 0; j < 4; ++j) {
            const int col = (4*w + j)*16 + ln;
            const float tb = t_b[col], g2 = bn2g[col]*INVV, b2 = bn2b[col];
            float m = -3.4e38f;
            #pragma unroll
            for (int rt = 0; rt < 4; ++rt)
                #pragma unroll
                for (int r = 0; r < 4; ++r) {
                    const float tv = acct[rt][j][r] + tb;
                    const float rl = fmaxf(tv*g2 + b2, 0.f);
                    const float xv = (float)xsave[j][rt][r];
                    m = fmaxf(m, xv + rl);
                }
            m = fmaxf(m, __shfl_xor(m, 16));
            m = fmaxf(m, __shfl_xor(m, 32));
            if (kg == 0)
                out[((size_t)bb*256 + col)*1024 + s] = m;
        }
    }
}

extern "C" void kernel_launch(void* const* d_in, const int* in_sizes, int n_in,
                              void* d_out, int out_size, void* d_ws, size_t ws_size,
                              hipStream_t stream) {
    (void)in_sizes; (void)n_in; (void)out_size; (void)ws_size;
    unsigned char* ws = (unsigned char*)d_ws;
    prep_kernel<<<92 + 314, 256, 0, stream>>>(
        (const float*)d_in[4],   // mlp_w
        (const float*)d_in[8],   // qk_w
        (const float*)d_in[9],   // v_w
        (const float*)d_in[11],  // t_w
        (const float*)d_in[3],   // up_feature
        ws);
    cloudcrop_mfma<<<2048, 256, 0, stream>>>(
        (const float*)d_in[0],   // seed_xyz
        (const float*)d_in[1],   // pointcloud
        (const float*)d_in[2],   // vp_rot
        (const float*)d_in[5],   // mlp_b
        (const float*)d_in[6],   // bn1_g
        (const float*)d_in[7],   // bn1_b
        (const float*)d_in[10],  // v_b
        (const float*)d_in[12],  // t_b
        (const float*)d_in[13],  // bn2_g
        (const float*)d_in[14],  // bn2_b
        ws,
        (float*)d_out);
}

// Round 10
// 119.978 us; speedup vs baseline: 1.3897x; 1.0341x over previous
//
#include <hip/hip_runtime.h>

// CloudCrop fused MFMA kernel, round 10: R9 + XCD-bijective swizzle (out-line
// L2 merging), BN/bias affine folding in prep (v_b folded into t-bias), attT
// f16x4 packed stores. B=2,S=1024,N=10000,C=128,NS=64,hidden=256.

typedef _Float16 f16;
typedef _Float16 f16x8 __attribute__((ext_vector_type(8)));
typedef _Float16 f16x4v __attribute__((ext_vector_type(4)));
typedef float f32x4 __attribute__((ext_vector_type(4)));
typedef unsigned int u32;
typedef u32 u32x2 __attribute__((ext_vector_type(2)));

constexpr int Nn = 10000;
constexpr float RAD2 = 0.05f * 0.05f;
constexpr float HMINf = -0.02f, HMAXf = 0.02f;
constexpr float INVV = 0.99999500003749968747f; // 1/sqrt(1+1e-5)

// ws layout:
//   [0, 376832): 368 weight fragment tiles (1KB: [64 lanes][8 f16])
//     WA 0..79 (mlp, K 131->160), WQ 80..111, WV 112..239, WT 240..367
//   [376832, +5.12MB): upT (B, N, 128) f16
//   [5496832, +4KB): folded scalars G1[256] C1[256] G2[256] C2[256] f32
#define UPT_OFF 376832
#define SCAL_OFF 5496832

// s_q (8KB) multiplex offsets (temporally disjoint users):
#define CAND_I   0      // int [4][64]          (phase 0..merge)
#define CAND_X   1024   // f16 [4][64]
#define CAND_Y   1536
#define CAND_Z   2048
#define IDX_OFF  2560   // int [64]             (merge..A)
#define CN4_OFF  2816   // int [4]
#define XYZ_OFF  2848   // f16 [64][32]         (merge..A)
// Q then attT: full [64][128B] from phase B onward.

__device__ __forceinline__ int swzb(int row, int colbyte) {
    return colbyte ^ ((row & 7) << 4);
}

__global__ void prep_kernel(const float* __restrict__ mlp_w,
                            const float* __restrict__ qk_w,
                            const float* __restrict__ v_w,
                            const float* __restrict__ t_w,
                            const float* __restrict__ up,
                            const float* __restrict__ mlp_b,
                            const float* __restrict__ bn1g,
                            const float* __restrict__ bn1b,
                            const float* __restrict__ v_b,
                            const float* __restrict__ t_b,
                            const float* __restrict__ bn2g,
                            const float* __restrict__ bn2b,
                            unsigned char* __restrict__ ws) {
    const int blk = blockIdx.x;
    if (blk < 92) {
        const int tid = blk * 256 + threadIdx.x;  // < 368*64
        const int tile = tid >> 6, lane = tid & 63;
        const int ln = lane & 15, kg = lane >> 4;
        f16x8 v;
        if (tile < 80) {
            const int kc = tile / 16, ct = tile % 16;
            const int n = ct * 16 + ln, kb = kc * 32 + kg * 8;
            #pragma unroll
            for (int i = 0; i < 8; ++i) {
                const int k = kb + i;
                float x = (k < 128) ? mlp_w[n * 131 + 3 + k]
                        : ((k < 131) ? mlp_w[n * 131 + (k - 128)] : 0.f);
                v[i] = (f16)x;
            }
        } else if (tile < 112) {
            const int t2 = tile - 80; const int kc = t2 >> 2, ct = t2 & 3;
            const int n = ct * 16 + ln, kb = kc * 32 + kg * 8;
            #pragma unroll
            for (int i = 0; i < 8; ++i) v[i] = (f16)qk_w[n * 256 + kb + i];
        } else if (tile < 240) {
            const int t2 = tile - 112; const int kc = t2 >> 4, ct = t2 & 15;
            const int n = ct * 16 + ln, kb = kc * 32 + kg * 8;
            #pragma unroll
            for (int i = 0; i < 8; ++i) v[i] = (f16)v_w[n * 256 + kb + i];
        } else {
            const int t2 = tile - 240; const int kc = t2 >> 4, ct = t2 & 15;
            const int n = ct * 16 + ln, kb = kc * 32 + kg * 8;
            #pragma unroll
            for (int i = 0; i < 8; ++i) v[i] = (f16)t_w[n * 256 + kb + i];
        }
        *(f16x8*)(ws + (size_t)tid * 16) = v;
    } else if (blk < 92 + 314) {
        __shared__ f16 tile[64 * 136];
        const int bidx = blk - 92;
        const int b = bidx / 157;
        const int n0 = (bidx % 157) * 64;
        const int lane = threadIdx.x & 63;
        const int cw = threadIdx.x >> 6;
        const int n = n0 + lane;
        const float* upb = up + (size_t)b * 128 * Nn;
        #pragma unroll
        for (int i = 0; i < 32; ++i) {
            const int c = cw * 32 + i;
            const float x = (n < Nn) ? upb[(size_t)c * Nn + n] : 0.f;
            tile[lane * 136 + c] = (f16)x;
        }
        __syncthreads();
        f16* dst = (f16*)(ws + UPT_OFF) + (size_t)b * Nn * 128;
        #pragma unroll
        for (int p = 0; p < 4; ++p) {
            const int flat8 = threadIdx.x + p * 256;
            const int row = flat8 >> 4;
            const int c = (flat8 & 15) * 8;
            if (n0 + row < Nn)
                *(f16x8*)(dst + ((size_t)(n0 + row)) * 128 + c) =
                    *(const f16x8*)(tile + row * 136 + c);
        }
    } else {
        // folded scalars
        const int o = threadIdx.x;   // 0..255
        float* G1 = (float*)(ws + SCAL_OFF);
        float* C1 = G1 + 256;
        float* G2 = G1 + 512;
        float* C2 = G1 + 768;
        const float g1 = bn1g[o] * INVV;
        G1[o] = g1;
        C1[o] = mlp_b[o] * g1 + bn1b[o];
        const float g2 = bn2g[o] * INVV;
        G2[o] = g2;
        // vbwt[o] = sum_c v_b[c] * t_w[o][c]; C2 = (t_b - vbwt)*g2 + bn2b
        float vbwt = 0.f;
        const float* tw = t_w + o * 256;
        #pragma unroll 4
        for (int c = 0; c < 256; ++c) vbwt += v_b[c] * tw[c];
        C2[o] = (t_b[o] - vbwt) * g2 + bn2b[o];
    }
}

__launch_bounds__(256, 3)
__global__ void cloudcrop_mfma(
    const float* __restrict__ seed,  // (B,S,3)
    const float* __restrict__ pc,    // (B,N,3)
    const float* __restrict__ rot,   // (B,S,3,3)
    const unsigned char* __restrict__ ws,
    float* __restrict__ out)         // (B,256,S) f32
{
    __shared__ __align__(16) unsigned char s_x[64 * 512]; // X [64][256] f16 swz; Y in-place
    __shared__ __align__(16) unsigned char s_q[8192];     // multiplexed (see map above)

    int*   cand_i  = (int*)(s_q + CAND_I);
    f16*   cand_x  = (f16*)(s_q + CAND_X);
    f16*   cand_y  = (f16*)(s_q + CAND_Y);
    f16*   cand_z  = (f16*)(s_q + CAND_Z);
    int*   idx_s   = (int*)(s_q + IDX_OFF);
    int*   cand_n4 = (int*)(s_q + CN4_OFF);
    f16*   s_xyz   = (f16*)(s_q + XYZ_OFF);   // [64][32]

    const float* G1 = (const float*)(ws + SCAL_OFF);
    const float* C1 = G1 + 256;
    const float* G2 = G1 + 512;
    const float* C2 = G1 + 768;

    // XCD-bijective swizzle: XCD k (hw: blockIdx%8) owns 256 consecutive grps
    const int grp = ((blockIdx.x & 7) << 8) | (blockIdx.x >> 3);
    const int bb = grp >> 10;
    const int s  = grp & 1023;
    const int t  = threadIdx.x;
    const int lane = t & 63;
    const int w    = t >> 6;
    const int ln   = lane & 15;
    const int kg   = lane >> 4;
    const int kg16 = kg * 16;
    const int g4   = kg * 4;

    // ---------- Phase 0: selection scan, 4 waves x 2500 pts, 2x unroll ------
    {
        const float sx = seed[grp*3+0], sy = seed[grp*3+1], sz = seed[grp*3+2];
        const float R0 = rot[grp*9+0], R1 = rot[grp*9+1], R2 = rot[grp*9+2];
        const float R3 = rot[grp*9+3], R4 = rot[grp*9+4], R5 = rot[grp*9+5];
        const float R6 = rot[grp*9+6], R7 = rot[grp*9+7], R8 = rot[grp*9+8];
        const unsigned long long lmask = (1ull << lane) - 1ull;
        int count = 0;
        const int lo = w * 2500, hi = lo + 2500;
        for (int base = lo; base < hi; base += 128) {
            const int n0i = base + lane, n1i = base + 64 + lane;
            bool m0 = false, m1 = false;
            float rx0=0.f, ry0=0.f, rz0=0.f, rx1=0.f, ry1=0.f, rz1=0.f;
            if (n0i < hi) {
                const float px = pc[(bb*Nn + n0i)*3+0] - sx;
                const float py = pc[(bb*Nn + n0i)*3+1] - sy;
                const float pz = pc[(bb*Nn + n0i)*3+2] - sz;
                rx0 = px*R0 + py*R3 + pz*R6;
                ry0 = px*R1 + py*R4 + pz*R7;
                rz0 = px*R2 + py*R5 + pz*R8;
                m0 = (ry0*ry0 + rz0*rz0 < RAD2) && (rx0 > HMINf) && (rx0 < HMAXf);
            }
            if (n1i < hi) {
                const float px = pc[(bb*Nn + n1i)*3+0] - sx;
                const float py = pc[(bb*Nn + n1i)*3+1] - sy;
                const float pz = pc[(bb*Nn + n1i)*3+2] - sz;
                rx1 = px*R0 + py*R3 + pz*R6;
                ry1 = px*R1 + py*R4 + pz*R7;
                rz1 = px*R2 + py*R5 + pz*R8;
                m1 = (ry1*ry1 + rz1*rz1 < RAD2) && (rx1 > HMINf) && (rx1 < HMAXf);
            }
            const unsigned long long bal0 = __ballot(m0);
            const unsigned long long bal1 = __ballot(m1);
            const int c0 = __popcll(bal0);
            const int pos0 = count + __popcll(bal0 & lmask);
            const int pos1 = count + c0 + __popcll(bal1 & lmask);
            if (m0 && pos0 < 64) {
                cand_i[w*64 + pos0] = n0i;
                cand_x[w*64 + pos0] = (f16)rx0; cand_y[w*64 + pos0] = (f16)ry0;
                cand_z[w*64 + pos0] = (f16)rz0;
            }
            if (m1 && pos1 < 64) {
                cand_i[w*64 + pos1] = n1i;
                cand_x[w*64 + pos1] = (f16)rx1; cand_y[w*64 + pos1] = (f16)ry1;
                cand_z[w*64 + pos1] = (f16)rz1;
            }
            count += c0 + __popcll(bal1);
        }
        if (lane == 0) cand_n4[w] = count < 64 ? count : 64;
    }
    __syncthreads();

    // ---------- Merge (ordered) -> idx_s + xyz tile -------------------------
    if (t < 64) {
        const int c0 = cand_n4[0], c1 = cand_n4[1], c2 = cand_n4[2], c3 = cand_n4[3];
        const int o1 = c0, o2 = c0 + c1, o3 = o2 + c2;
        int total = o3 + c3; if (total > 64) total = 64;
        int myi; f16 hx, hy, hz;
        if (total > 0) {
            const int pp = (t < total) ? t : 0;
            int sw_, sq;
            if      (pp >= o3) { sw_ = 3; sq = pp - o3; }
            else if (pp >= o2) { sw_ = 2; sq = pp - o2; }
            else if (pp >= o1) { sw_ = 1; sq = pp - o1; }
            else               { sw_ = 0; sq = pp; }
            myi = cand_i[sw_*64 + sq];
            hx = cand_x[sw_*64 + sq]; hy = cand_y[sw_*64 + sq]; hz = cand_z[sw_*64 + sq];
        } else {
            const float sx = seed[grp*3+0], sy = seed[grp*3+1], sz = seed[grp*3+2];
            const float px = pc[(bb*Nn)*3+0] - sx;
            const float py = pc[(bb*Nn)*3+1] - sy;
            const float pz = pc[(bb*Nn)*3+2] - sz;
            hx = (f16)(px*rot[grp*9+0] + py*rot[grp*9+3] + pz*rot[grp*9+6]);
            hy = (f16)(px*rot[grp*9+1] + py*rot[grp*9+4] + pz*rot[grp*9+7]);
            hz = (f16)(px*rot[grp*9+2] + py*rot[grp*9+5] + pz*rot[grp*9+8]);
            myi = 0;
        }
        idx_s[t] = myi;
        f16x8 z0 = {};
        z0[0] = hx; z0[1] = hy; z0[2] = hz;
        f16x8 zz = {};
        f16x8* xr = (f16x8*)(s_xyz + t * 32);
        xr[0] = z0; xr[1] = zz; xr[2] = zz; xr[3] = zz;
    }
    __syncthreads();

    // ---------- Phase A (swapped): H = WA @ [feat|xyz]^T -> X ---------------
    {
        int idxr[4];
        #pragma unroll
        for (int nt = 0; nt < 4; ++nt) idxr[nt] = idx_s[nt*16 + ln];
        const f16* upTb = (const f16*)(ws + UPT_OFF) + (size_t)bb * Nn * 128;

        f32x4 acc[4][4] = {};   // [ch-tile jt][sample-tile nt]
        #pragma unroll
        for (int kc = 0; kc < 4; ++kc) {
            f16x8 bX[4];
            #pragma unroll
            for (int nt = 0; nt < 4; ++nt)
                bX[nt] = *(const f16x8*)(upTb + (size_t)idxr[nt]*128 + kc*32 + kg*8);
            #pragma unroll
            for (int jt = 0; jt < 4; ++jt) {
                const f16x8 aw = *(const f16x8*)(ws + (size_t)(kc*16 + 4*w + jt)*1024 + lane*16);
                #pragma unroll
                for (int nt = 0; nt < 4; ++nt)
                    acc[jt][nt] = __builtin_amdgcn_mfma_f32_16x16x32_f16(aw, bX[nt], acc[jt][nt], 0, 0, 0);
            }
        }
        {   // kc = 4: xyz from LDS
            f16x8 bX[4];
            #pragma unroll
            for (int nt = 0; nt < 4; ++nt)
                bX[nt] = *(const f16x8*)(s_xyz + (nt*16 + ln)*32 + kg*8);
            #pragma unroll
            for (int jt = 0; jt < 4; ++jt) {
                const f16x8 aw = *(const f16x8*)(ws + (size_t)(64 + 4*w + jt)*1024 + lane*16);
                #pragma unroll
                for (int nt = 0; nt < 4; ++nt)
                    acc[jt][nt] = __builtin_amdgcn_mfma_f32_16x16x32_f16(aw, bX[nt], acc[jt][nt], 0, 0, 0);
            }
        }
        #pragma unroll
        for (int jt = 0; jt < 4; ++jt) {
            const int chb = (4*w + jt)*16 + g4;
            const f32x4 g14 = *(const f32x4*)(G1 + chb);
            const f32x4 c14 = *(const f32x4*)(C1 + chb);
            #pragma unroll
            for (int nt = 0; nt < 4; ++nt) {
                const int smp = nt*16 + ln;
                f16x4v hv;
                #pragma unroll
                for (int r = 0; r < 4; ++r)
                    hv[r] = (f16)fmaxf(acc[jt][nt][r] * g14[r] + c14[r], 0.f);
                *(f16x4v*)(s_x + smp*512 + swzb(smp, chb*2)) = hv;
            }
        }
    }
    __syncthreads();   // also covers s_q reuse: xyz/cand dead, Q next

    // ---------- Phase B (swapped): Q = WQ @ X^T -> Q[smp][qch] --------------
    {
        f32x4 accq[4] = {};   // [nt]
        #pragma unroll
        for (int kc = 0; kc < 8; ++kc) {
            const f16x8 aw = *(const f16x8*)(ws + (size_t)(80 + kc*4 + w)*1024 + lane*16);
            #pragma unroll
            for (int nt = 0; nt < 4; ++nt) {
                const int row = nt*16 + ln;
                const f16x8 bX = *(const f16x8*)(s_x + row*512 + swzb(row, kc*64 + kg16));
                accq[nt] = __builtin_amdgcn_mfma_f32_16x16x32_f16(aw, bX, accq[nt], 0, 0, 0);
            }
        }
        const int qb = (w*16 + g4) * 2;   // byte offset of 4 consec qch
        #pragma unroll
        for (int nt = 0; nt < 4; ++nt) {
            const int smp = nt*16 + ln;
            f16x4v pk;
            #pragma unroll
            for (int r = 0; r < 4; ++r) pk[r] = (f16)accq[nt][r];
            *(f16x4v*)(s_q + smp*128 + swzb(smp, qb)) = pk;
        }
    }
    __syncthreads();

    // ---------- Phase C: wave w owns rows w*16..+15 of S; in-wave softmax ---
    {
        f16x8 aQ[2];
        #pragma unroll
        for (int kc = 0; kc < 2; ++kc) {
            const int rowA = w*16 + ln;
            aQ[kc] = *(const f16x8*)(s_q + rowA*128 + swzb(rowA, kc*64 + kg16));
        }
        f32x4 accs[4];  // [ct]: S[w*16 + kg*4 + r][ct*16 + ln]
        #pragma unroll
        for (int ct = 0; ct < 4; ++ct) accs[ct] = (f32x4){0.f,0.f,0.f,0.f};
        #pragma unroll
        for (int kc = 0; kc < 2; ++kc) {
            #pragma unroll
            for (int ct = 0; ct < 4; ++ct) {
                const int rowB = ct*16 + ln;
                const f16x8 bQ = *(const f16x8*)(s_q + rowB*128 + swzb(rowB, kc*64 + kg16));
                accs[ct] = __builtin_amdgcn_mfma_f32_16x16x32_f16(aQ[kc], bQ, accs[ct], 0, 0, 0);
            }
        }
        // in-wave softmax per row r (row's 64 vals: 4 regs x 16 ln-lanes)
        float inv[4];
        #pragma unroll
        for (int r = 0; r < 4; ++r) {
            float mx = fmaxf(fmaxf(accs[0][r], accs[1][r]),
                             fmaxf(accs[2][r], accs[3][r]));
            mx = fmaxf(mx, __shfl_xor(mx, 1));
            mx = fmaxf(mx, __shfl_xor(mx, 2));
            mx = fmaxf(mx, __shfl_xor(mx, 4));
            mx = fmaxf(mx, __shfl_xor(mx, 8));
            float sm = 0.f;
            #pragma unroll
            for (int ct = 0; ct < 4; ++ct) {
                const float e = __expf(accs[ct][r] - mx);
                accs[ct][r] = e; sm += e;
            }
            sm += __shfl_xor(sm, 1);
            sm += __shfl_xor(sm, 2);
            sm += __shfl_xor(sm, 4);
            sm += __shfl_xor(sm, 8);
            inv[r] = 1.0f / sm;
        }
        __syncthreads();   // all waves done reading Q before attT overwrites
        const int ib = (w*16 + g4) * 2;   // byte offset of 4 consec i
        #pragma unroll
        for (int ct = 0; ct < 4; ++ct) {
            const int j = ct*16 + ln;
            f16x4v pk;
            #pragma unroll
            for (int r = 0; r < 4; ++r) pk[r] = (f16)(accs[ct][r] * inv[r]);
            *(f16x4v*)(s_q + j*128 + swzb(j, ib)) = pk;
        }
    }
    __syncthreads();

    // ---------- Phase D: V=X@WV; in-reg transpose via shfl; XR=attT@V -------
    f32x4 accr[4][4];
    float rinv[4][4];
    {
        f16x8 a2[2][4];
        #pragma unroll
        for (int kc = 0; kc < 2; ++kc)
            #pragma unroll
            for (int rt = 0; rt < 4; ++rt) {
                const int row = rt*16 + ln;
                a2[kc][rt] = *(const f16x8*)(s_q + row*128 + swzb(row, kc*64 + kg16));
            }
        // colsum via ones-MFMA, converted to rinv immediately
        {
            f16x8 onef;
            #pragma unroll
            for (int i = 0; i < 8; ++i) onef[i] = (f16)1.0f;
            f32x4 accONE[4];
            #pragma unroll
            for (int rt = 0; rt < 4; ++rt) accONE[rt] = (f32x4){0.f,0.f,0.f,0.f};
            #pragma unroll
            for (int kc = 0; kc < 2; ++kc)
                #pragma unroll
                for (int rt = 0; rt < 4; ++rt)
                    accONE[rt] = __builtin_amdgcn_mfma_f32_16x16x32_f16(a2[kc][rt], onef, accONE[rt], 0, 0, 0);
            #pragma unroll
            for (int rt = 0; rt < 4; ++rt)
                #pragma unroll
                for (int r = 0; r < 4; ++r)
                    rinv[rt][r] = __builtin_amdgcn_rcpf(1e-9f + accONE[rt][r]);
        }

        #pragma unroll
        for (int rt = 0; rt < 4; ++rt)
            #pragma unroll
            for (int j = 0; j < 4; ++j) accr[rt][j] = (f32x4){0.f,0.f,0.f,0.f};

        const int sbase = ln + ((lane >> 4) & 1) * 32;   // shfl src base
        const bool hiHalf = (kg >= 2);
        #pragma unroll
        for (int j = 0; j < 4; ++j) {
            f32x4 accv[4] = {};
            #pragma unroll 2
            for (int kc = 0; kc < 8; ++kc) {
                const f16x8 bf = *(const f16x8*)(ws + (size_t)(112 + kc*16 + 4*w + j)*1024 + lane*16);
                #pragma unroll
                for (int rt = 0; rt < 4; ++rt) {
                    const int row = rt*16 + ln;
                    const f16x8 aX = *(const f16x8*)(s_x + row*512 + swzb(row, kc*64 + kg16));
                    accv[rt] = __builtin_amdgcn_mfma_f32_16x16x32_f16(aX, bf, accv[rt], 0, 0, 0);
                }
            }
            // pack to f16 pairs: pk[rt][p] = samples rt*16+g4+{2p,2p+1}
            u32 pk[4][2];
            #pragma unroll
            for (int rt = 0; rt < 4; ++rt) {
                f16x4v v4;
                #pragma unroll
                for (int r = 0; r < 4; ++r) v4[r] = (f16)accv[rt][r];
                const u32x2 p2 = __builtin_bit_cast(u32x2, v4);
                pk[rt][0] = p2.x; pk[rt][1] = p2.y;
            }
            // route: B-frag reg q <- lane (sbase + 16*(q>>1)), pk[2kc+(kg>>1)][q&1]
            #pragma unroll
            for (int kc = 0; kc < 2; ++kc) {
                union { u32 u[4]; f16x8 v; } bu;
                #pragma unroll
                for (int q = 0; q < 4; ++q) {
                    const int srcl = sbase + 16*(q >> 1);
                    const u32 lo = (u32)__shfl((int)pk[2*kc + 0][q & 1], srcl);
                    const u32 hi = (u32)__shfl((int)pk[2*kc + 1][q & 1], srcl);
                    bu.u[q] = hiHalf ? hi : lo;
                }
                #pragma unroll
                for (int rt = 0; rt < 4; ++rt)
                    accr[rt][j] = __builtin_amdgcn_mfma_f32_16x16x32_f16(a2[kc][rt], bu.v, accr[rt][j], 0, 0, 0);
            }
        }
    }
    __syncthreads();  // all waves' X reads done before Y overwrite

    // ---------- D-epilogue: Y' = X - XR*rinv (in-place; vb folded into C2) --
    f16x4v xsave[4][4];
    #pragma unroll
    for (int j = 0; j < 4; ++j) {
        const int col = (4*w + j)*16 + ln;
        #pragma unroll
        for (int rt = 0; rt < 4; ++rt) {
            f16x4v xs4;
            #pragma unroll
            for (int r = 0; r < 4; ++r) {
                const int row = rt*16 + g4 + r;
                const f16 xv = *(const f16*)(s_x + row*512 + swzb(row, col*2));
                xs4[r] = xv;
                const float yv = (float)xv - accr[rt][j][r] * rinv[rt][r];
                *(f16*)(s_x + row*512 + swzb(row, col*2)) = (f16)yv;
            }
            xsave[j][rt] = xs4;
        }
    }
    __syncthreads();

    // ---------- Phase E: T = Y' @ WT; out = maxpool(X + relu(T*G2 + C2)) ----
    {
        f32x4 acct[4][4] = {};
        #pragma unroll 2
        for (int kc = 0; kc < 8; ++kc) {
            f16x8 a[4];
            #pragma unroll
            for (int rt = 0; rt < 4; ++rt) {
                const int row = rt*16 + ln;
                a[rt] = *(const f16x8*)(s_x + row*512 + swzb(row, kc*64 + kg16));  // Y'
            }
            #pragma unroll
            for (int j = 0; j < 4; ++j) {
                const f16x8 bf = *(const f16x8*)(ws + (size_t)(240 + kc*16 + 4*w + j)*1024 + lane*16);
                #pragma unroll
                for (int rt = 0; rt < 4; ++rt)
                    acct[rt][j] = __builtin_amdgcn_mfma_f32_16x16x32_f16(a[rt], bf, acct[rt][j], 0, 0, 0);
            }
        }
        #pragma unroll
        for (int j = 0; j < 4; ++j) {
            const int col = (4*w + j)*16 + ln;
            const float g2 = G2[col], c2 = C2[col];
            float m = -3.4e38f;
            #pragma unroll
            for (int rt = 0; rt < 4; ++rt)
                #pragma unroll
                for (int r = 0; r < 4; ++r) {
                    const float rl = fmaxf(acct[rt][j][r] * g2 + c2, 0.f);
                    const float xv = (float)xsave[j][rt][r];
                    m = fmaxf(m, xv + rl);
                }
            m = fmaxf(m, __shfl_xor(m, 16));
            m = fmaxf(m, __shfl_xor(m, 32));
            if (kg == 0)
                out[((size_t)bb*256 + col)*1024 + s] = m;
        }
    }
}

extern "C" void kernel_launch(void* const* d_in, const int* in_sizes, int n_in,
                              void* d_out, int out_size, void* d_ws, size_t ws_size,
                              hipStream_t stream) {
    (void)in_sizes; (void)n_in; (void)out_size; (void)ws_size;
    unsigned char* ws = (unsigned char*)d_ws;
    prep_kernel<<<92 + 314 + 1, 256, 0, stream>>>(
        (const float*)d_in[4],   // mlp_w
        (const float*)d_in[8],   // qk_w
        (const float*)d_in[9],   // v_w
        (const float*)d_in[11],  // t_w
        (const float*)d_in[3],   // up_feature
        (const float*)d_in[5],   // mlp_b
        (const float*)d_in[6],   // bn1_g
        (const float*)d_in[7],   // bn1_b
        (const float*)d_in[10],  // v_b
        (const float*)d_in[12],  // t_b
        (const float*)d_in[13],  // bn2_g
        (const float*)d_in[14],  // bn2_b
        ws);
    cloudcrop_mfma<<<2048, 256, 0, stream>>>(
        (const float*)d_in[0],   // seed_xyz
        (const float*)d_in[1],   // pointcloud
        (const float*)d_in[2],   // vp_rot
        ws,
        (float*)d_out);
}

// Round 11
// 115.239 us; speedup vs baseline: 1.4469x; 1.0411x over previous
//
#include <hip/hip_runtime.h>

// CloudCrop fused MFMA kernel, round 11: every phase trimmed to <=128 live
// regs (D: per-j XR packed to f16; E: split into two j-pairs) to reach
// 4 blocks/CU spill-free. B=2,S=1024,N=10000,C=128,NS=64,hidden=256.

typedef _Float16 f16;
typedef _Float16 f16x8 __attribute__((ext_vector_type(8)));
typedef _Float16 f16x4v __attribute__((ext_vector_type(4)));
typedef float f32x4 __attribute__((ext_vector_type(4)));
typedef unsigned int u32;
typedef u32 u32x2 __attribute__((ext_vector_type(2)));

constexpr int Nn = 10000;
constexpr float RAD2 = 0.05f * 0.05f;
constexpr float HMINf = -0.02f, HMAXf = 0.02f;
constexpr float INVV = 0.99999500003749968747f; // 1/sqrt(1+1e-5)

// ws layout:
//   [0, 376832): 368 weight fragment tiles (1KB: [64 lanes][8 f16])
//     WA 0..79 (mlp, K 131->160), WQ 80..111, WV 112..239, WT 240..367
//   [376832, +5.12MB): upT (B, N, 128) f16
//   [5496832, +4KB): folded scalars G1[256] C1[256] G2[256] C2[256] f32
#define UPT_OFF 376832
#define SCAL_OFF 5496832

// s_q (8KB) multiplex offsets (temporally disjoint users):
#define CAND_I   0      // int [4][64]          (phase 0..merge)
#define CAND_X   1024   // f16 [4][64]
#define CAND_Y   1536
#define CAND_Z   2048
#define IDX_OFF  2560   // int [64]             (merge..A)
#define CN4_OFF  2816   // int [4]
#define XYZ_OFF  2848   // f16 [64][32]         (merge..A)
// Q then attT: full [64][128B] from phase B onward.

__device__ __forceinline__ int swzb(int row, int colbyte) {
    return colbyte ^ ((row & 7) << 4);
}

__global__ void prep_kernel(const float* __restrict__ mlp_w,
                            const float* __restrict__ qk_w,
                            const float* __restrict__ v_w,
                            const float* __restrict__ t_w,
                            const float* __restrict__ up,
                            const float* __restrict__ mlp_b,
                            const float* __restrict__ bn1g,
                            const float* __restrict__ bn1b,
                            const float* __restrict__ v_b,
                            const float* __restrict__ t_b,
                            const float* __restrict__ bn2g,
                            const float* __restrict__ bn2b,
                            unsigned char* __restrict__ ws) {
    const int blk = blockIdx.x;
    if (blk < 92) {
        const int tid = blk * 256 + threadIdx.x;  // < 368*64
        const int tile = tid >> 6, lane = tid & 63;
        const int ln = lane & 15, kg = lane >> 4;
        f16x8 v;
        if (tile < 80) {
            const int kc = tile / 16, ct = tile % 16;
            const int n = ct * 16 + ln, kb = kc * 32 + kg * 8;
            #pragma unroll
            for (int i = 0; i < 8; ++i) {
                const int k = kb + i;
                float x = (k < 128) ? mlp_w[n * 131 + 3 + k]
                        : ((k < 131) ? mlp_w[n * 131 + (k - 128)] : 0.f);
                v[i] = (f16)x;
            }
        } else if (tile < 112) {
            const int t2 = tile - 80; const int kc = t2 >> 2, ct = t2 & 3;
            const int n = ct * 16 + ln, kb = kc * 32 + kg * 8;
            #pragma unroll
            for (int i = 0; i < 8; ++i) v[i] = (f16)qk_w[n * 256 + kb + i];
        } else if (tile < 240) {
            const int t2 = tile - 112; const int kc = t2 >> 4, ct = t2 & 15;
            const int n = ct * 16 + ln, kb = kc * 32 + kg * 8;
            #pragma unroll
            for (int i = 0; i < 8; ++i) v[i] = (f16)v_w[n * 256 + kb + i];
        } else {
            const int t2 = tile - 240; const int kc = t2 >> 4, ct = t2 & 15;
            const int n = ct * 16 + ln, kb = kc * 32 + kg * 8;
            #pragma unroll
            for (int i = 0; i < 8; ++i) v[i] = (f16)t_w[n * 256 + kb + i];
        }
        *(f16x8*)(ws + (size_t)tid * 16) = v;
    } else if (blk < 92 + 314) {
        __shared__ f16 tile[64 * 136];
        const int bidx = blk - 92;
        const int b = bidx / 157;
        const int n0 = (bidx % 157) * 64;
        const int lane = threadIdx.x & 63;
        const int cw = threadIdx.x >> 6;
        const int n = n0 + lane;
        const float* upb = up + (size_t)b * 128 * Nn;
        #pragma unroll
        for (int i = 0; i < 32; ++i) {
            const int c = cw * 32 + i;
            const float x = (n < Nn) ? upb[(size_t)c * Nn + n] : 0.f;
            tile[lane * 136 + c] = (f16)x;
        }
        __syncthreads();
        f16* dst = (f16*)(ws + UPT_OFF) + (size_t)b * Nn * 128;
        #pragma unroll
        for (int p = 0; p < 4; ++p) {
            const int flat8 = threadIdx.x + p * 256;
            const int row = flat8 >> 4;
            const int c = (flat8 & 15) * 8;
            if (n0 + row < Nn)
                *(f16x8*)(dst + ((size_t)(n0 + row)) * 128 + c) =
                    *(const f16x8*)(tile + row * 136 + c);
        }
    } else {
        // folded scalars
        const int o = threadIdx.x;   // 0..255
        float* G1 = (float*)(ws + SCAL_OFF);
        float* C1 = G1 + 256;
        float* G2 = G1 + 512;
        float* C2 = G1 + 768;
        const float g1 = bn1g[o] * INVV;
        G1[o] = g1;
        C1[o] = mlp_b[o] * g1 + bn1b[o];
        const float g2 = bn2g[o] * INVV;
        G2[o] = g2;
        // vbwt[o] = sum_c v_b[c] * t_w[o][c]; C2 = (t_b - vbwt)*g2 + bn2b
        float vbwt = 0.f;
        const float* tw = t_w + o * 256;
        #pragma unroll 4
        for (int c = 0; c < 256; ++c) vbwt += v_b[c] * tw[c];
        C2[o] = (t_b[o] - vbwt) * g2 + bn2b[o];
    }
}

__launch_bounds__(256, 4)
__global__ void cloudcrop_mfma(
    const float* __restrict__ seed,  // (B,S,3)
    const float* __restrict__ pc,    // (B,N,3)
    const float* __restrict__ rot,   // (B,S,3,3)
    const unsigned char* __restrict__ ws,
    float* __restrict__ out)         // (B,256,S) f32
{
    __shared__ __align__(16) unsigned char s_x[64 * 512]; // X [64][256] f16 swz; Y in-place
    __shared__ __align__(16) unsigned char s_q[8192];     // multiplexed (see map above)

    int*   cand_i  = (int*)(s_q + CAND_I);
    f16*   cand_x  = (f16*)(s_q + CAND_X);
    f16*   cand_y  = (f16*)(s_q + CAND_Y);
    f16*   cand_z  = (f16*)(s_q + CAND_Z);
    int*   idx_s   = (int*)(s_q + IDX_OFF);
    int*   cand_n4 = (int*)(s_q + CN4_OFF);
    f16*   s_xyz   = (f16*)(s_q + XYZ_OFF);   // [64][32]

    const float* G1 = (const float*)(ws + SCAL_OFF);
    const float* C1 = G1 + 256;
    const float* G2 = G1 + 512;
    const float* C2 = G1 + 768;

    // XCD-bijective swizzle: XCD k (hw: blockIdx%8) owns 256 consecutive grps
    const int grp = ((blockIdx.x & 7) << 8) | (blockIdx.x >> 3);
    const int bb = grp >> 10;
    const int s  = grp & 1023;
    const int t  = threadIdx.x;
    const int lane = t & 63;
    const int w    = t >> 6;
    const int ln   = lane & 15;
    const int kg   = lane >> 4;
    const int kg16 = kg * 16;
    const int g4   = kg * 4;

    // ---------- Phase 0: selection scan, 4 waves x 2500 pts, 2x unroll ------
    {
        const float sx = seed[grp*3+0], sy = seed[grp*3+1], sz = seed[grp*3+2];
        const float R0 = rot[grp*9+0], R1 = rot[grp*9+1], R2 = rot[grp*9+2];
        const float R3 = rot[grp*9+3], R4 = rot[grp*9+4], R5 = rot[grp*9+5];
        const float R6 = rot[grp*9+6], R7 = rot[grp*9+7], R8 = rot[grp*9+8];
        const unsigned long long lmask = (1ull << lane) - 1ull;
        int count = 0;
        const int lo = w * 2500, hi = lo + 2500;
        for (int base = lo; base < hi; base += 128) {
            const int n0i = base + lane, n1i = base + 64 + lane;
            bool m0 = false, m1 = false;
            float rx0=0.f, ry0=0.f, rz0=0.f, rx1=0.f, ry1=0.f, rz1=0.f;
            if (n0i < hi) {
                const float px = pc[(bb*Nn + n0i)*3+0] - sx;
                const float py = pc[(bb*Nn + n0i)*3+1] - sy;
                const float pz = pc[(bb*Nn + n0i)*3+2] - sz;
                rx0 = px*R0 + py*R3 + pz*R6;
                ry0 = px*R1 + py*R4 + pz*R7;
                rz0 = px*R2 + py*R5 + pz*R8;
                m0 = (ry0*ry0 + rz0*rz0 < RAD2) && (rx0 > HMINf) && (rx0 < HMAXf);
            }
            if (n1i < hi) {
                const float px = pc[(bb*Nn + n1i)*3+0] - sx;
                const float py = pc[(bb*Nn + n1i)*3+1] - sy;
                const float pz = pc[(bb*Nn + n1i)*3+2] - sz;
                rx1 = px*R0 + py*R3 + pz*R6;
                ry1 = px*R1 + py*R4 + pz*R7;
                rz1 = px*R2 + py*R5 + pz*R8;
                m1 = (ry1*ry1 + rz1*rz1 < RAD2) && (rx1 > HMINf) && (rx1 < HMAXf);
            }
            const unsigned long long bal0 = __ballot(m0);
            const unsigned long long bal1 = __ballot(m1);
            const int c0 = __popcll(bal0);
            const int pos0 = count + __popcll(bal0 & lmask);
            const int pos1 = count + c0 + __popcll(bal1 & lmask);
            if (m0 && pos0 < 64) {
                cand_i[w*64 + pos0] = n0i;
                cand_x[w*64 + pos0] = (f16)rx0; cand_y[w*64 + pos0] = (f16)ry0;
                cand_z[w*64 + pos0] = (f16)rz0;
            }
            if (m1 && pos1 < 64) {
                cand_i[w*64 + pos1] = n1i;
                cand_x[w*64 + pos1] = (f16)rx1; cand_y[w*64 + pos1] = (f16)ry1;
                cand_z[w*64 + pos1] = (f16)rz1;
            }
            count += c0 + __popcll(bal1);
        }
        if (lane == 0) cand_n4[w] = count < 64 ? count : 64;
    }
    __syncthreads();

    // ---------- Merge (ordered) -> idx_s + xyz tile -------------------------
    if (t < 64) {
        const int c0 = cand_n4[0], c1 = cand_n4[1], c2 = cand_n4[2], c3 = cand_n4[3];
        const int o1 = c0, o2 = c0 + c1, o3 = o2 + c2;
        int total = o3 + c3; if (total > 64) total = 64;
        int myi; f16 hx, hy, hz;
        if (total > 0) {
            const int pp = (t < total) ? t : 0;
            int sw_, sq;
            if      (pp >= o3) { sw_ = 3; sq = pp - o3; }
            else if (pp >= o2) { sw_ = 2; sq = pp - o2; }
            else if (pp >= o1) { sw_ = 1; sq = pp - o1; }
            else               { sw_ = 0; sq = pp; }
            myi = cand_i[sw_*64 + sq];
            hx = cand_x[sw_*64 + sq]; hy = cand_y[sw_*64 + sq]; hz = cand_z[sw_*64 + sq];
        } else {
            const float sx = seed[grp*3+0], sy = seed[grp*3+1], sz = seed[grp*3+2];
            const float px = pc[(bb*Nn)*3+0] - sx;
            const float py = pc[(bb*Nn)*3+1] - sy;
            const float pz = pc[(bb*Nn)*3+2] - sz;
            hx = (f16)(px*rot[grp*9+0] + py*rot[grp*9+3] + pz*rot[grp*9+6]);
            hy = (f16)(px*rot[grp*9+1] + py*rot[grp*9+4] + pz*rot[grp*9+7]);
            hz = (f16)(px*rot[grp*9+2] + py*rot[grp*9+5] + pz*rot[grp*9+8]);
            myi = 0;
        }
        idx_s[t] = myi;
        f16x8 z0 = {};
        z0[0] = hx; z0[1] = hy; z0[2] = hz;
        f16x8 zz = {};
        f16x8* xr = (f16x8*)(s_xyz + t * 32);
        xr[0] = z0; xr[1] = zz; xr[2] = zz; xr[3] = zz;
    }
    __syncthreads();

    // ---------- Phase A (swapped): H = WA @ [feat|xyz]^T -> X ---------------
    {
        int idxr[4];
        #pragma unroll
        for (int nt = 0; nt < 4; ++nt) idxr[nt] = idx_s[nt*16 + ln];
        const f16* upTb = (const f16*)(ws + UPT_OFF) + (size_t)bb * Nn * 128;

        f32x4 acc[4][4] = {};   // [ch-tile jt][sample-tile nt]
        #pragma unroll
        for (int kc = 0; kc < 4; ++kc) {
            f16x8 bX[4];
            #pragma unroll
            for (int nt = 0; nt < 4; ++nt)
                bX[nt] = *(const f16x8*)(upTb + (size_t)idxr[nt]*128 + kc*32 + kg*8);
            #pragma unroll
            for (int jt = 0; jt < 4; ++jt) {
                const f16x8 aw = *(const f16x8*)(ws + (size_t)(kc*16 + 4*w + jt)*1024 + lane*16);
                #pragma unroll
                for (int nt = 0; nt < 4; ++nt)
                    acc[jt][nt] = __builtin_amdgcn_mfma_f32_16x16x32_f16(aw, bX[nt], acc[jt][nt], 0, 0, 0);
            }
        }
        {   // kc = 4: xyz from LDS
            f16x8 bX[4];
            #pragma unroll
            for (int nt = 0; nt < 4; ++nt)
                bX[nt] = *(const f16x8*)(s_xyz + (nt*16 + ln)*32 + kg*8);
            #pragma unroll
            for (int jt = 0; jt < 4; ++jt) {
                const f16x8 aw = *(const f16x8*)(ws + (size_t)(64 + 4*w + jt)*1024 + lane*16);
                #pragma unroll
                for (int nt = 0; nt < 4; ++nt)
                    acc[jt][nt] = __builtin_amdgcn_mfma_f32_16x16x32_f16(aw, bX[nt], acc[jt][nt], 0, 0, 0);
            }
        }
        #pragma unroll
        for (int jt = 0; jt < 4; ++jt) {
            const int chb = (4*w + jt)*16 + g4;
            const f32x4 g14 = *(const f32x4*)(G1 + chb);
            const f32x4 c14 = *(const f32x4*)(C1 + chb);
            #pragma unroll
            for (int nt = 0; nt < 4; ++nt) {
                const int smp = nt*16 + ln;
                f16x4v hv;
                #pragma unroll
                for (int r = 0; r < 4; ++r)
                    hv[r] = (f16)fmaxf(acc[jt][nt][r] * g14[r] + c14[r], 0.f);
                *(f16x4v*)(s_x + smp*512 + swzb(smp, chb*2)) = hv;
            }
        }
    }
    __syncthreads();   // also covers s_q reuse: xyz/cand dead, Q next

    // ---------- Phase B (swapped): Q = WQ @ X^T -> Q[smp][qch] --------------
    {
        f32x4 accq[4] = {};   // [nt]
        #pragma unroll
        for (int kc = 0; kc < 8; ++kc) {
            const f16x8 aw = *(const f16x8*)(ws + (size_t)(80 + kc*4 + w)*1024 + lane*16);
            #pragma unroll
            for (int nt = 0; nt < 4; ++nt) {
                const int row = nt*16 + ln;
                const f16x8 bX = *(const f16x8*)(s_x + row*512 + swzb(row, kc*64 + kg16));
                accq[nt] = __builtin_amdgcn_mfma_f32_16x16x32_f16(aw, bX, accq[nt], 0, 0, 0);
            }
        }
        const int qb = (w*16 + g4) * 2;   // byte offset of 4 consec qch
        #pragma unroll
        for (int nt = 0; nt < 4; ++nt) {
            const int smp = nt*16 + ln;
            f16x4v pk;
            #pragma unroll
            for (int r = 0; r < 4; ++r) pk[r] = (f16)accq[nt][r];
            *(f16x4v*)(s_q + smp*128 + swzb(smp, qb)) = pk;
        }
    }
    __syncthreads();

    // ---------- Phase C: wave w owns rows w*16..+15 of S; in-wave softmax ---
    {
        f16x8 aQ[2];
        #pragma unroll
        for (int kc = 0; kc < 2; ++kc) {
            const int rowA = w*16 + ln;
            aQ[kc] = *(const f16x8*)(s_q + rowA*128 + swzb(rowA, kc*64 + kg16));
        }
        f32x4 accs[4];  // [ct]: S[w*16 + kg*4 + r][ct*16 + ln]
        #pragma unroll
        for (int ct = 0; ct < 4; ++ct) accs[ct] = (f32x4){0.f,0.f,0.f,0.f};
        #pragma unroll
        for (int kc = 0; kc < 2; ++kc) {
            #pragma unroll
            for (int ct = 0; ct < 4; ++ct) {
                const int rowB = ct*16 + ln;
                const f16x8 bQ = *(const f16x8*)(s_q + rowB*128 + swzb(rowB, kc*64 + kg16));
                accs[ct] = __builtin_amdgcn_mfma_f32_16x16x32_f16(aQ[kc], bQ, accs[ct], 0, 0, 0);
            }
        }
        // in-wave softmax per row r (row's 64 vals: 4 regs x 16 ln-lanes)
        float inv[4];
        #pragma unroll
        for (int r = 0; r < 4; ++r) {
            float mx = fmaxf(fmaxf(accs[0][r], accs[1][r]),
                             fmaxf(accs[2][r], accs[3][r]));
            mx = fmaxf(mx, __shfl_xor(mx, 1));
            mx = fmaxf(mx, __shfl_xor(mx, 2));
            mx = fmaxf(mx, __shfl_xor(mx, 4));
            mx = fmaxf(mx, __shfl_xor(mx, 8));
            float sm = 0.f;
            #pragma unroll
            for (int ct = 0; ct < 4; ++ct) {
                const float e = __expf(accs[ct][r] - mx);
                accs[ct][r] = e; sm += e;
            }
            sm += __shfl_xor(sm, 1);
            sm += __shfl_xor(sm, 2);
            sm += __shfl_xor(sm, 4);
            sm += __shfl_xor(sm, 8);
            inv[r] = 1.0f / sm;
        }
        __syncthreads();   // all waves done reading Q before attT overwrites
        const int ib = (w*16 + g4) * 2;   // byte offset of 4 consec i
        #pragma unroll
        for (int ct = 0; ct < 4; ++ct) {
            const int j = ct*16 + ln;
            f16x4v pk;
            #pragma unroll
            for (int r = 0; r < 4; ++r) pk[r] = (f16)(accs[ct][r] * inv[r]);
            *(f16x4v*)(s_q + j*128 + swzb(j, ib)) = pk;
        }
    }
    __syncthreads();

    // ---------- Phase D: V=X@WV; shfl transpose; XR=attT@V -> f16 regs ------
    u32 xrpk[4][4][2];   // [j][rt][pair] f16x2, XR unscaled (32 VGPR)
    float rinv[4][4];
    {
        f16x8 a2[2][4];
        #pragma unroll
        for (int kc = 0; kc < 2; ++kc)
            #pragma unroll
            for (int rt = 0; rt < 4; ++rt) {
                const int row = rt*16 + ln;
                a2[kc][rt] = *(const f16x8*)(s_q + row*128 + swzb(row, kc*64 + kg16));
            }

        const int sbase = ln + ((lane >> 4) & 1) * 32;   // shfl src base
        const bool hiHalf = (kg >= 2);
        #pragma unroll
        for (int j = 0; j < 4; ++j) {
            f32x4 accv[4] = {};
            #pragma unroll 2
            for (int kc = 0; kc < 8; ++kc) {
                const f16x8 bf = *(const f16x8*)(ws + (size_t)(112 + kc*16 + 4*w + j)*1024 + lane*16);
                #pragma unroll
                for (int rt = 0; rt < 4; ++rt) {
                    const int row = rt*16 + ln;
                    const f16x8 aX = *(const f16x8*)(s_x + row*512 + swzb(row, kc*64 + kg16));
                    accv[rt] = __builtin_amdgcn_mfma_f32_16x16x32_f16(aX, bf, accv[rt], 0, 0, 0);
                }
            }
            // pack V to f16 pairs: pk[rt][p] = samples rt*16+g4+{2p,2p+1}
            u32 pk[4][2];
            #pragma unroll
            for (int rt = 0; rt < 4; ++rt) {
                f16x4v v4;
                #pragma unroll
                for (int r = 0; r < 4; ++r) v4[r] = (f16)accv[rt][r];
                const u32x2 p2 = __builtin_bit_cast(u32x2, v4);
                pk[rt][0] = p2.x; pk[rt][1] = p2.y;
            }
            // route + XR MFMAs, result packed to f16 immediately
            f32x4 accrj[4] = {};
            #pragma unroll
            for (int kc = 0; kc < 2; ++kc) {
                union { u32 u[4]; f16x8 v; } bu;
                #pragma unroll
                for (int q = 0; q < 4; ++q) {
                    const int srcl = sbase + 16*(q >> 1);
                    const u32 lo = (u32)__shfl((int)pk[2*kc + 0][q & 1], srcl);
                    const u32 hi = (u32)__shfl((int)pk[2*kc + 1][q & 1], srcl);
                    bu.u[q] = hiHalf ? hi : lo;
                }
                #pragma unroll
                for (int rt = 0; rt < 4; ++rt)
                    accrj[rt] = __builtin_amdgcn_mfma_f32_16x16x32_f16(a2[kc][rt], bu.v, accrj[rt], 0, 0, 0);
            }
            #pragma unroll
            for (int rt = 0; rt < 4; ++rt) {
                f16x4v v4;
                #pragma unroll
                for (int r = 0; r < 4; ++r) v4[r] = (f16)accrj[rt][r];
                const u32x2 p2 = __builtin_bit_cast(u32x2, v4);
                xrpk[j][rt][0] = p2.x; xrpk[j][rt][1] = p2.y;
            }
        }
        // colsum via ones-MFMA after the j-loop (out of peak pressure)
        {
            f16x8 onef;
            #pragma unroll
            for (int i = 0; i < 8; ++i) onef[i] = (f16)1.0f;
            f32x4 accONE[4];
            #pragma unroll
            for (int rt = 0; rt < 4; ++rt) accONE[rt] = (f32x4){0.f,0.f,0.f,0.f};
            #pragma unroll
            for (int kc = 0; kc < 2; ++kc)
                #pragma unroll
                for (int rt = 0; rt < 4; ++rt)
                    accONE[rt] = __builtin_amdgcn_mfma_f32_16x16x32_f16(a2[kc][rt], onef, accONE[rt], 0, 0, 0);
            #pragma unroll
            for (int rt = 0; rt < 4; ++rt)
                #pragma unroll
                for (int r = 0; r < 4; ++r)
                    rinv[rt][r] = __builtin_amdgcn_rcpf(1e-9f + accONE[rt][r]);
        }
    }
    __syncthreads();  // all waves' X reads done before Y overwrite

    // ---------- D-epilogue: Y' = X - XR*rinv (in-place), keep X in regs -----
    f16x4v xsave[4][4];
    #pragma unroll
    for (int j = 0; j < 4; ++j) {
        const int col = (4*w + j)*16 + ln;
        #pragma unroll
        for (int rt = 0; rt < 4; ++rt) {
            const u32x2 p2 = { xrpk[j][rt][0], xrpk[j][rt][1] };
            const f16x4v xr4 = __builtin_bit_cast(f16x4v, p2);
            f16x4v xs4;
            #pragma unroll
            for (int r = 0; r < 4; ++r) {
                const int row = rt*16 + g4 + r;
                const f16 xv = *(const f16*)(s_x + row*512 + swzb(row, col*2));
                xs4[r] = xv;
                const float yv = (float)xv - (float)xr4[r] * rinv[rt][r];
                *(f16*)(s_x + row*512 + swzb(row, col*2)) = (f16)yv;
            }
            xsave[j][rt] = xs4;
        }
    }
    __syncthreads();

    // ---------- Phase E (split j-pairs): T = Y' @ WT; maxpool epilogue ------
    #pragma unroll
    for (int jp = 0; jp < 2; ++jp) {
        f32x4 acct[2][4] = {};   // [jj][rt] - 32 AGPR per pair
        #pragma unroll 2
        for (int kc = 0; kc < 8; ++kc) {
            f16x8 a[4];
            #pragma unroll
            for (int rt = 0; rt < 4; ++rt) {
                const int row = rt*16 + ln;
                a[rt] = *(const f16x8*)(s_x + row*512 + swzb(row, kc*64 + kg16));  // Y'
            }
            #pragma unroll
            for (int jj = 0; jj < 2; ++jj) {
                const int j = jp*2 + jj;
                const f16x8 bf = *(const f16x8*)(ws + (size_t)(240 + kc*16 + 4*w + j)*1024 + lane*16);
                #pragma unroll
                for (int rt = 0; rt < 4; ++rt)
                    acct[jj][rt] = __builtin_amdgcn_mfma_f32_16x16x32_f16(a[rt], bf, acct[jj][rt], 0, 0, 0);
            }
        }
        #pragma unroll
        for (int jj = 0; jj < 2; ++jj) {
            const int j = jp*2 + jj;
            const int col = (4*w + j)*16 + ln;
            const float g2 = G2[col], c2 = C2[col];
            float m = -3.4e38f;
            #pragma unroll
            for (int rt = 0; rt < 4; ++rt)
                #pragma unroll
                for (int r = 0; r < 4; ++r) {
                    const float rl = fmaxf(acct[jj][rt][r] * g2 + c2, 0.f);
                    const float xv = (float)xsave[j][rt][r];
                    m = fmaxf(m, xv + rl);
                }
            m = fmaxf(m, __shfl_xor(m, 16));
            m = fmaxf(m, __shfl_xor(m, 32));
            if (kg == 0)
                out[((size_t)bb*256 + col)*1024 + s] = m;
        }
    }
}

extern "C" void kernel_launch(void* const* d_in, const int* in_sizes, int n_in,
                              void* d_out, int out_size, void* d_ws, size_t ws_size,
                              hipStream_t stream) {
    (void)in_sizes; (void)n_in; (void)out_size; (void)ws_size;
    unsigned char* ws = (unsigned char*)d_ws;
    prep_kernel<<<92 + 314 + 1, 256, 0, stream>>>(
        (const float*)d_in[4],   // mlp_w
        (const float*)d_in[8],   // qk_w
        (const float*)d_in[9],   // v_w
        (const float*)d_in[11],  // t_w
        (const float*)d_in[3],   // up_feature
        (const float*)d_in[5],   // mlp_b
        (const float*)d_in[6],   // bn1_g
        (const float*)d_in[7],   // bn1_b
        (const float*)d_in[10],  // v_b
        (const float*)d_in[12],  // t_b
        (const float*)d_in[13],  // bn2_g
        (const float*)d_in[14],  // bn2_b
        ws);
    cloudcrop_mfma<<<2048, 256, 0, stream>>>(
        (const float*)d_in[0],   // seed_xyz
        (const float*)d_in[1],   // pointcloud
        (const float*)d_in[2],   // vp_rot
        ws,
        (float*)d_out);
}

// Round 12
// 96.587 us; speedup vs baseline: 1.7263x; 1.1931x over previous
//
#include <hip/hip_runtime.h>

// CloudCrop fused MFMA kernel, round 12: R11 + vectorized float4 selection
// scan (exact-order 4-ballot), cvt_pkrtz packed f32->f16, rcp, setprio
// around MFMA clusters. B=2,S=1024,N=10000,C=128,NS=64,hidden=256.

typedef _Float16 f16;
typedef _Float16 f16x2 __attribute__((ext_vector_type(2)));
typedef _Float16 f16x8 __attribute__((ext_vector_type(8)));
typedef _Float16 f16x4v __attribute__((ext_vector_type(4)));
typedef float f32x4 __attribute__((ext_vector_type(4)));
typedef unsigned int u32;
typedef u32 u32x2 __attribute__((ext_vector_type(2)));

constexpr int Nn = 10000;
constexpr float RAD2 = 0.05f * 0.05f;
constexpr float HMINf = -0.02f, HMAXf = 0.02f;
constexpr float INVV = 0.99999500003749968747f; // 1/sqrt(1+1e-5)

#define UPT_OFF 376832
#define SCAL_OFF 5496832

#define CAND_I   0      // int [4][64]
#define CAND_X   1024   // f16 [4][64]
#define CAND_Y   1536
#define CAND_Z   2048
#define IDX_OFF  2560   // int [64]
#define CN4_OFF  2816   // int [4]
#define XYZ_OFF  2848   // f16 [64][32]

__device__ __forceinline__ int swzb(int row, int colbyte) {
    return colbyte ^ ((row & 7) << 4);
}
__device__ __forceinline__ u32 pk2(float a, float b) {
    return __builtin_bit_cast(u32, __builtin_amdgcn_cvt_pkrtz(a, b));
}

__global__ void prep_kernel(const float* __restrict__ mlp_w,
                            const float* __restrict__ qk_w,
                            const float* __restrict__ v_w,
                            const float* __restrict__ t_w,
                            const float* __restrict__ up,
                            const float* __restrict__ mlp_b,
                            const float* __restrict__ bn1g,
                            const float* __restrict__ bn1b,
                            const float* __restrict__ v_b,
                            const float* __restrict__ t_b,
                            const float* __restrict__ bn2g,
                            const float* __restrict__ bn2b,
                            unsigned char* __restrict__ ws) {
    const int blk = blockIdx.x;
    if (blk < 92) {
        const int tid = blk * 256 + threadIdx.x;  // < 368*64
        const int tile = tid >> 6, lane = tid & 63;
        const int ln = lane & 15, kg = lane >> 4;
        f16x8 v;
        if (tile < 80) {
            const int kc = tile / 16, ct = tile % 16;
            const int n = ct * 16 + ln, kb = kc * 32 + kg * 8;
            #pragma unroll
            for (int i = 0; i < 8; ++i) {
                const int k = kb + i;
                float x = (k < 128) ? mlp_w[n * 131 + 3 + k]
                        : ((k < 131) ? mlp_w[n * 131 + (k - 128)] : 0.f);
                v[i] = (f16)x;
            }
        } else if (tile < 112) {
            const int t2 = tile - 80; const int kc = t2 >> 2, ct = t2 & 3;
            const int n = ct * 16 + ln, kb = kc * 32 + kg * 8;
            #pragma unroll
            for (int i = 0; i < 8; ++i) v[i] = (f16)qk_w[n * 256 + kb + i];
        } else if (tile < 240) {
            const int t2 = tile - 112; const int kc = t2 >> 4, ct = t2 & 15;
            const int n = ct * 16 + ln, kb = kc * 32 + kg * 8;
            #pragma unroll
            for (int i = 0; i < 8; ++i) v[i] = (f16)v_w[n * 256 + kb + i];
        } else {
            const int t2 = tile - 240; const int kc = t2 >> 4, ct = t2 & 15;
            const int n = ct * 16 + ln, kb = kc * 32 + kg * 8;
            #pragma unroll
            for (int i = 0; i < 8; ++i) v[i] = (f16)t_w[n * 256 + kb + i];
        }
        *(f16x8*)(ws + (size_t)tid * 16) = v;
    } else if (blk < 92 + 314) {
        __shared__ f16 tile[64 * 136];
        const int bidx = blk - 92;
        const int b = bidx / 157;
        const int n0 = (bidx % 157) * 64;
        const int lane = threadIdx.x & 63;
        const int cw = threadIdx.x >> 6;
        const int n = n0 + lane;
        const float* upb = up + (size_t)b * 128 * Nn;
        #pragma unroll
        for (int i = 0; i < 32; ++i) {
            const int c = cw * 32 + i;
            const float x = (n < Nn) ? upb[(size_t)c * Nn + n] : 0.f;
            tile[lane * 136 + c] = (f16)x;
        }
        __syncthreads();
        f16* dst = (f16*)(ws + UPT_OFF) + (size_t)b * Nn * 128;
        #pragma unroll
        for (int p = 0; p < 4; ++p) {
            const int flat8 = threadIdx.x + p * 256;
            const int row = flat8 >> 4;
            const int c = (flat8 & 15) * 8;
            if (n0 + row < Nn)
                *(f16x8*)(dst + ((size_t)(n0 + row)) * 128 + c) =
                    *(const f16x8*)(tile + row * 136 + c);
        }
    } else {
        const int o = threadIdx.x;   // 0..255
        float* G1 = (float*)(ws + SCAL_OFF);
        float* C1 = G1 + 256;
        float* G2 = G1 + 512;
        float* C2 = G1 + 768;
        const float g1 = bn1g[o] * INVV;
        G1[o] = g1;
        C1[o] = mlp_b[o] * g1 + bn1b[o];
        const float g2 = bn2g[o] * INVV;
        G2[o] = g2;
        float vbwt = 0.f;
        const float* tw = t_w + o * 256;
        #pragma unroll 4
        for (int c = 0; c < 256; ++c) vbwt += v_b[c] * tw[c];
        C2[o] = (t_b[o] - vbwt) * g2 + bn2b[o];
    }
}

__launch_bounds__(256, 4)
__global__ void cloudcrop_mfma(
    const float* __restrict__ seed,  // (B,S,3)
    const float* __restrict__ pc,    // (B,N,3)
    const float* __restrict__ rot,   // (B,S,3,3)
    const unsigned char* __restrict__ ws,
    float* __restrict__ out)         // (B,256,S) f32
{
    __shared__ __align__(16) unsigned char s_x[64 * 512]; // X [64][256] f16 swz; Y in-place
    __shared__ __align__(16) unsigned char s_q[8192];     // multiplexed

    int*   cand_i  = (int*)(s_q + CAND_I);
    f16*   cand_x  = (f16*)(s_q + CAND_X);
    f16*   cand_y  = (f16*)(s_q + CAND_Y);
    f16*   cand_z  = (f16*)(s_q + CAND_Z);
    int*   idx_s   = (int*)(s_q + IDX_OFF);
    int*   cand_n4 = (int*)(s_q + CN4_OFF);
    f16*   s_xyz   = (f16*)(s_q + XYZ_OFF);   // [64][32]

    const float* G1 = (const float*)(ws + SCAL_OFF);
    const float* C1 = G1 + 256;
    const float* G2 = G1 + 512;
    const float* C2 = G1 + 768;

    // XCD-bijective swizzle: XCD k owns 256 consecutive grps
    const int grp = ((blockIdx.x & 7) << 8) | (blockIdx.x >> 3);
    const int bb = grp >> 10;
    const int s  = grp & 1023;
    const int t  = threadIdx.x;
    const int lane = t & 63;
    const int w    = t >> 6;
    const int ln   = lane & 15;
    const int kg   = lane >> 4;
    const int kg16 = kg * 16;
    const int g4   = kg * 4;

    // ---------- Phase 0: selection scan, float4-vectorized, exact order -----
    {
        const float sx = seed[grp*3+0], sy = seed[grp*3+1], sz = seed[grp*3+2];
        const float R0 = rot[grp*9+0], R1 = rot[grp*9+1], R2 = rot[grp*9+2];
        const float R3 = rot[grp*9+3], R4 = rot[grp*9+4], R5 = rot[grp*9+5];
        const float R6 = rot[grp*9+6], R7 = rot[grp*9+7], R8 = rot[grp*9+8];
        const unsigned long long lmask = (1ull << lane) - 1ull;
        int count = 0;
        const int lo = w * 2500, hi = lo + 2500;
        // 9 full iterations of 256 points (lane holds 4 consecutive points)
        for (int it = 0; it < 9; ++it) {
            const int nb = lo + it*256 + lane*4;
            const float* p0 = pc + ((size_t)bb*Nn + nb)*3;
            const f32x4 A0 = *(const f32x4*)(p0);
            const f32x4 A1 = *(const f32x4*)(p0 + 4);
            const f32x4 A2 = *(const f32x4*)(p0 + 8);
            const float X[4] = {A0.x, A0.w, A1.z, A2.y};
            const float Y[4] = {A0.y, A1.x, A1.w, A2.z};
            const float Z[4] = {A0.z, A1.y, A2.x, A2.w};
            bool m[4]; float RX[4], RY[4], RZ[4];
            #pragma unroll
            for (int p = 0; p < 4; ++p) {
                const float px = X[p] - sx, py = Y[p] - sy, pz = Z[p] - sz;
                RX[p] = px*R0 + py*R3 + pz*R6;
                RY[p] = px*R1 + py*R4 + pz*R7;
                RZ[p] = px*R2 + py*R5 + pz*R8;
                m[p] = (RY[p]*RY[p] + RZ[p]*RZ[p] < RAD2)
                       && (RX[p] > HMINf) && (RX[p] < HMAXf);
            }
            unsigned long long b[4];
            #pragma unroll
            for (int p = 0; p < 4; ++p) b[p] = __ballot(m[p]);
            int below = 0, tot = 0;
            #pragma unroll
            for (int p = 0; p < 4; ++p) {
                below += __popcll(b[p] & lmask);
                tot   += __popcll(b[p]);
            }
            int prefix = 0;
            #pragma unroll
            for (int p = 0; p < 4; ++p) {
                const int pos = count + below + prefix;
                if (m[p] && pos < 64) {
                    cand_i[w*64 + pos] = nb + p;
                    cand_x[w*64 + pos] = (f16)RX[p];
                    cand_y[w*64 + pos] = (f16)RY[p];
                    cand_z[w*64 + pos] = (f16)RZ[p];
                }
                prefix += (int)((b[p] >> lane) & 1ull);
            }
            count += tot;
        }
        // tail: points lo+2304 .. hi-1 (196), scalar guarded
        for (int base = lo + 2304; base < hi; base += 64) {
            const int n = base + lane;
            bool m = false; float rx = 0.f, ry = 0.f, rz = 0.f;
            if (n < hi) {
                const float px = pc[(bb*Nn + n)*3+0] - sx;
                const float py = pc[(bb*Nn + n)*3+1] - sy;
                const float pz = pc[(bb*Nn + n)*3+2] - sz;
                rx = px*R0 + py*R3 + pz*R6;
                ry = px*R1 + py*R4 + pz*R7;
                rz = px*R2 + py*R5 + pz*R8;
                m = (ry*ry + rz*rz < RAD2) && (rx > HMINf) && (rx < HMAXf);
            }
            const unsigned long long bal = __ballot(m);
            const int pos = count + __popcll(bal & lmask);
            if (m && pos < 64) {
                cand_i[w*64 + pos] = n;
                cand_x[w*64 + pos] = (f16)rx; cand_y[w*64 + pos] = (f16)ry;
                cand_z[w*64 + pos] = (f16)rz;
            }
            count += __popcll(bal);
        }
        if (lane == 0) cand_n4[w] = count < 64 ? count : 64;
    }
    __syncthreads();

    // ---------- Merge (ordered) -> idx_s + xyz tile -------------------------
    if (t < 64) {
        const int c0 = cand_n4[0], c1 = cand_n4[1], c2 = cand_n4[2], c3 = cand_n4[3];
        const int o1 = c0, o2 = c0 + c1, o3 = o2 + c2;
        int total = o3 + c3; if (total > 64) total = 64;
        int myi; f16 hx, hy, hz;
        if (total > 0) {
            const int pp = (t < total) ? t : 0;
            int sw_, sq;
            if      (pp >= o3) { sw_ = 3; sq = pp - o3; }
            else if (pp >= o2) { sw_ = 2; sq = pp - o2; }
            else if (pp >= o1) { sw_ = 1; sq = pp - o1; }
            else               { sw_ = 0; sq = pp; }
            myi = cand_i[sw_*64 + sq];
            hx = cand_x[sw_*64 + sq]; hy = cand_y[sw_*64 + sq]; hz = cand_z[sw_*64 + sq];
        } else {
            const float sx = seed[grp*3+0], sy = seed[grp*3+1], sz = seed[grp*3+2];
            const float px = pc[(bb*Nn)*3+0] - sx;
            const float py = pc[(bb*Nn)*3+1] - sy;
            const float pz = pc[(bb*Nn)*3+2] - sz;
            hx = (f16)(px*rot[grp*9+0] + py*rot[grp*9+3] + pz*rot[grp*9+6]);
            hy = (f16)(px*rot[grp*9+1] + py*rot[grp*9+4] + pz*rot[grp*9+7]);
            hz = (f16)(px*rot[grp*9+2] + py*rot[grp*9+5] + pz*rot[grp*9+8]);
            myi = 0;
        }
        idx_s[t] = myi;
        f16x8 z0 = {};
        z0[0] = hx; z0[1] = hy; z0[2] = hz;
        f16x8 zz = {};
        f16x8* xr = (f16x8*)(s_xyz + t * 32);
        xr[0] = z0; xr[1] = zz; xr[2] = zz; xr[3] = zz;
    }
    __syncthreads();

    // ---------- Phase A (swapped): H = WA @ [feat|xyz]^T -> X ---------------
    {
        int idxr[4];
        #pragma unroll
        for (int nt = 0; nt < 4; ++nt) idxr[nt] = idx_s[nt*16 + ln];
        const f16* upTb = (const f16*)(ws + UPT_OFF) + (size_t)bb * Nn * 128;

        f32x4 acc[4][4] = {};   // [ch-tile jt][sample-tile nt]
        __builtin_amdgcn_s_setprio(1);
        #pragma unroll
        for (int kc = 0; kc < 4; ++kc) {
            f16x8 bX[4];
            #pragma unroll
            for (int nt = 0; nt < 4; ++nt)
                bX[nt] = *(const f16x8*)(upTb + (size_t)idxr[nt]*128 + kc*32 + kg*8);
            #pragma unroll
            for (int jt = 0; jt < 4; ++jt) {
                const f16x8 aw = *(const f16x8*)(ws + (size_t)(kc*16 + 4*w + jt)*1024 + lane*16);
                #pragma unroll
                for (int nt = 0; nt < 4; ++nt)
                    acc[jt][nt] = __builtin_amdgcn_mfma_f32_16x16x32_f16(aw, bX[nt], acc[jt][nt], 0, 0, 0);
            }
        }
        {   // kc = 4: xyz from LDS
            f16x8 bX[4];
            #pragma unroll
            for (int nt = 0; nt < 4; ++nt)
                bX[nt] = *(const f16x8*)(s_xyz + (nt*16 + ln)*32 + kg*8);
            #pragma unroll
            for (int jt = 0; jt < 4; ++jt) {
                const f16x8 aw = *(const f16x8*)(ws + (size_t)(64 + 4*w + jt)*1024 + lane*16);
                #pragma unroll
                for (int nt = 0; nt < 4; ++nt)
                    acc[jt][nt] = __builtin_amdgcn_mfma_f32_16x16x32_f16(aw, bX[nt], acc[jt][nt], 0, 0, 0);
            }
        }
        __builtin_amdgcn_s_setprio(0);
        #pragma unroll
        for (int jt = 0; jt < 4; ++jt) {
            const int chb = (4*w + jt)*16 + g4;
            const f32x4 g14 = *(const f32x4*)(G1 + chb);
            const f32x4 c14 = *(const f32x4*)(C1 + chb);
            #pragma unroll
            for (int nt = 0; nt < 4; ++nt) {
                const int smp = nt*16 + ln;
                float h[4];
                #pragma unroll
                for (int r = 0; r < 4; ++r)
                    h[r] = fmaxf(acc[jt][nt][r] * g14[r] + c14[r], 0.f);
                const u32x2 hv = { pk2(h[0], h[1]), pk2(h[2], h[3]) };
                *(u32x2*)(s_x + smp*512 + swzb(smp, chb*2)) = hv;
            }
        }
    }
    __syncthreads();

    // ---------- Phase B (swapped): Q = WQ @ X^T -> Q[smp][qch] --------------
    {
        f32x4 accq[4] = {};   // [nt]
        __builtin_amdgcn_s_setprio(1);
        #pragma unroll
        for (int kc = 0; kc < 8; ++kc) {
            const f16x8 aw = *(const f16x8*)(ws + (size_t)(80 + kc*4 + w)*1024 + lane*16);
            #pragma unroll
            for (int nt = 0; nt < 4; ++nt) {
                const int row = nt*16 + ln;
                const f16x8 bX = *(const f16x8*)(s_x + row*512 + swzb(row, kc*64 + kg16));
                accq[nt] = __builtin_amdgcn_mfma_f32_16x16x32_f16(aw, bX, accq[nt], 0, 0, 0);
            }
        }
        __builtin_amdgcn_s_setprio(0);
        const int qb = (w*16 + g4) * 2;   // byte offset of 4 consec qch
        #pragma unroll
        for (int nt = 0; nt < 4; ++nt) {
            const int smp = nt*16 + ln;
            const u32x2 pk = { pk2(accq[nt][0], accq[nt][1]),
                               pk2(accq[nt][2], accq[nt][3]) };
            *(u32x2*)(s_q + smp*128 + swzb(smp, qb)) = pk;
        }
    }
    __syncthreads();

    // ---------- Phase C: wave w owns rows w*16..+15 of S; in-wave softmax ---
    {
        f16x8 aQ[2];
        #pragma unroll
        for (int kc = 0; kc < 2; ++kc) {
            const int rowA = w*16 + ln;
            aQ[kc] = *(const f16x8*)(s_q + rowA*128 + swzb(rowA, kc*64 + kg16));
        }
        f32x4 accs[4];  // [ct]: S[w*16 + kg*4 + r][ct*16 + ln]
        #pragma unroll
        for (int ct = 0; ct < 4; ++ct) accs[ct] = (f32x4){0.f,0.f,0.f,0.f};
        #pragma unroll
        for (int kc = 0; kc < 2; ++kc) {
            #pragma unroll
            for (int ct = 0; ct < 4; ++ct) {
                const int rowB = ct*16 + ln;
                const f16x8 bQ = *(const f16x8*)(s_q + rowB*128 + swzb(rowB, kc*64 + kg16));
                accs[ct] = __builtin_amdgcn_mfma_f32_16x16x32_f16(aQ[kc], bQ, accs[ct], 0, 0, 0);
            }
        }
        // in-wave softmax per row r (row's 64 vals: 4 regs x 16 ln-lanes)
        float inv[4];
        #pragma unroll
        for (int r = 0; r < 4; ++r) {
            float mx = fmaxf(fmaxf(accs[0][r], accs[1][r]),
                             fmaxf(accs[2][r], accs[3][r]));
            mx = fmaxf(mx, __shfl_xor(mx, 1));
            mx = fmaxf(mx, __shfl_xor(mx, 2));
            mx = fmaxf(mx, __shfl_xor(mx, 4));
            mx = fmaxf(mx, __shfl_xor(mx, 8));
            float sm = 0.f;
            #pragma unroll
            for (int ct = 0; ct < 4; ++ct) {
                const float e = __expf(accs[ct][r] - mx);
                accs[ct][r] = e; sm += e;
            }
            sm += __shfl_xor(sm, 1);
            sm += __shfl_xor(sm, 2);
            sm += __shfl_xor(sm, 4);
            sm += __shfl_xor(sm, 8);
            inv[r] = __builtin_amdgcn_rcpf(sm);
        }
        __syncthreads();   // all waves done reading Q before attT overwrites
        const int ib = (w*16 + g4) * 2;   // byte offset of 4 consec i
        #pragma unroll
        for (int ct = 0; ct < 4; ++ct) {
            const int j = ct*16 + ln;
            const u32x2 pk = { pk2(accs[ct][0]*inv[0], accs[ct][1]*inv[1]),
                               pk2(accs[ct][2]*inv[2], accs[ct][3]*inv[3]) };
            *(u32x2*)(s_q + j*128 + swzb(j, ib)) = pk;
        }
    }
    __syncthreads();

    // ---------- Phase D: V=X@WV; shfl transpose; XR=attT@V -> f16 regs ------
    u32 xrpk[4][4][2];   // [j][rt][pair] f16x2, XR unscaled (32 VGPR)
    float rinv[4][4];
    {
        f16x8 a2[2][4];
        #pragma unroll
        for (int kc = 0; kc < 2; ++kc)
            #pragma unroll
            for (int rt = 0; rt < 4; ++rt) {
                const int row = rt*16 + ln;
                a2[kc][rt] = *(const f16x8*)(s_q + row*128 + swzb(row, kc*64 + kg16));
            }

        const int sbase = ln + ((lane >> 4) & 1) * 32;   // shfl src base
        const bool hiHalf = (kg >= 2);
        #pragma unroll
        for (int j = 0; j < 4; ++j) {
            f32x4 accv[4] = {};
            __builtin_amdgcn_s_setprio(1);
            #pragma unroll 2
            for (int kc = 0; kc < 8; ++kc) {
                const f16x8 bf = *(const f16x8*)(ws + (size_t)(112 + kc*16 + 4*w + j)*1024 + lane*16);
                #pragma unroll
                for (int rt = 0; rt < 4; ++rt) {
                    const int row = rt*16 + ln;
                    const f16x8 aX = *(const f16x8*)(s_x + row*512 + swzb(row, kc*64 + kg16));
                    accv[rt] = __builtin_amdgcn_mfma_f32_16x16x32_f16(aX, bf, accv[rt], 0, 0, 0);
                }
            }
            __builtin_amdgcn_s_setprio(0);
            // pack V to f16 pairs: pk[rt][p] = samples rt*16+g4+{2p,2p+1}
            u32 pk[4][2];
            #pragma unroll
            for (int rt = 0; rt < 4; ++rt) {
                pk[rt][0] = pk2(accv[rt][0], accv[rt][1]);
                pk[rt][1] = pk2(accv[rt][2], accv[rt][3]);
            }
            // route + XR MFMAs, result packed to f16 immediately
            f32x4 accrj[4] = {};
            #pragma unroll
            for (int kc = 0; kc < 2; ++kc) {
                union { u32 u[4]; f16x8 v; } bu;
                #pragma unroll
                for (int q = 0; q < 4; ++q) {
                    const int srcl = sbase + 16*(q >> 1);
                    const u32 lo = (u32)__shfl((int)pk[2*kc + 0][q & 1], srcl);
                    const u32 hi = (u32)__shfl((int)pk[2*kc + 1][q & 1], srcl);
                    bu.u[q] = hiHalf ? hi : lo;
                }
                #pragma unroll
                for (int rt = 0; rt < 4; ++rt)
                    accrj[rt] = __builtin_amdgcn_mfma_f32_16x16x32_f16(a2[kc][rt], bu.v, accrj[rt], 0, 0, 0);
            }
            #pragma unroll
            for (int rt = 0; rt < 4; ++rt) {
                xrpk[j][rt][0] = pk2(accrj[rt][0], accrj[rt][1]);
                xrpk[j][rt][1] = pk2(accrj[rt][2], accrj[rt][3]);
            }
        }
        // colsum via ones-MFMA after the j-loop (out of peak pressure)
        {
            f16x8 onef;
            #pragma unroll
            for (int i = 0; i < 8; ++i) onef[i] = (f16)1.0f;
            f32x4 accONE[4];
            #pragma unroll
            for (int rt = 0; rt < 4; ++rt) accONE[rt] = (f32x4){0.f,0.f,0.f,0.f};
            #pragma unroll
            for (int kc = 0; kc < 2; ++kc)
                #pragma unroll
                for (int rt = 0; rt < 4; ++rt)
                    accONE[rt] = __builtin_amdgcn_mfma_f32_16x16x32_f16(a2[kc][rt], onef, accONE[rt], 0, 0, 0);
            #pragma unroll
            for (int rt = 0; rt < 4; ++rt)
                #pragma unroll
                for (int r = 0; r < 4; ++r)
                    rinv[rt][r] = __builtin_amdgcn_rcpf(1e-9f + accONE[rt][r]);
        }
    }
    __syncthreads();  // all waves' X reads done before Y overwrite

    // ---------- D-epilogue: Y' = X - XR*rinv (in-place), keep X in regs -----
    f16x4v xsave[4][4];
    #pragma unroll
    for (int j = 0; j < 4; ++j) {
        const int col = (4*w + j)*16 + ln;
        #pragma unroll
        for (int rt = 0; rt < 4; ++rt) {
            const u32x2 p2 = { xrpk[j][rt][0], xrpk[j][rt][1] };
            const f16x4v xr4 = __builtin_bit_cast(f16x4v, p2);
            f16x4v xs4;
            #pragma unroll
            for (int r = 0; r < 4; ++r) {
                const int row = rt*16 + g4 + r;
                const f16 xv = *(const f16*)(s_x + row*512 + swzb(row, col*2));
                xs4[r] = xv;
                const float yv = (float)xv - (float)xr4[r] * rinv[rt][r];
                *(f16*)(s_x + row*512 + swzb(row, col*2)) = (f16)yv;
            }
            xsave[j][rt] = xs4;
        }
    }
    __syncthreads();

    // ---------- Phase E (split j-pairs): T = Y' @ WT; maxpool epilogue ------
    #pragma unroll
    for (int jp = 0; jp < 2; ++jp) {
        f32x4 acct[2][4] = {};   // [jj][rt] - 32 AGPR per pair
        __builtin_amdgcn_s_setprio(1);
        #pragma unroll 2
        for (int kc = 0; kc < 8; ++kc) {
            f16x8 a[4];
            #pragma unroll
            for (int rt = 0; rt < 4; ++rt) {
                const int row = rt*16 + ln;
                a[rt] = *(const f16x8*)(s_x + row*512 + swzb(row, kc*64 + kg16));  // Y'
            }
            #pragma unroll
            for (int jj = 0; jj < 2; ++jj) {
                const int j = jp*2 + jj;
                const f16x8 bf = *(const f16x8*)(ws + (size_t)(240 + kc*16 + 4*w + j)*1024 + lane*16);
                #pragma unroll
                for (int rt = 0; rt < 4; ++rt)
                    acct[jj][rt] = __builtin_amdgcn_mfma_f32_16x16x32_f16(a[rt], bf, acct[jj][rt], 0, 0, 0);
            }
        }
        __builtin_amdgcn_s_setprio(0);
        #pragma unroll
        for (int jj = 0; jj < 2; ++jj) {
            const int j = jp*2 + jj;
            const int col = (4*w + j)*16 + ln;
            const float g2 = G2[col], c2 = C2[col];
            float m = -3.4e38f;
            #pragma unroll
            for (int rt = 0; rt < 4; ++rt)
                #pragma unroll
                for (int r = 0; r < 4; ++r) {
                    const float rl = fmaxf(acct[jj][rt][r] * g2 + c2, 0.f);
                    const float xv = (float)xsave[j][rt][r];
                    m = fmaxf(m, xv + rl);
                }
            m = fmaxf(m, __shfl_xor(m, 16));
            m = fmaxf(m, __shfl_xor(m, 32));
            if (kg == 0)
                out[((size_t)bb*256 + col)*1024 + s] = m;
        }
    }
}

extern "C" void kernel_launch(void* const* d_in, const int* in_sizes, int n_in,
                              void* d_out, int out_size, void* d_ws, size_t ws_size,
                              hipStream_t stream) {
    (void)in_sizes; (void)n_in; (void)out_size; (void)ws_size;
    unsigned char* ws = (unsigned char*)d_ws;
    prep_kernel<<<92 + 314 + 1, 256, 0, stream>>>(
        (const float*)d_in[4],   // mlp_w
        (const float*)d_in[8],   // qk_w
        (const float*)d_in[9],   // v_w
        (const float*)d_in[11],  // t_w
        (const float*)d_in[3],   // up_feature
        (const float*)d_in[5],   // mlp_b
        (const float*)d_in[6],   // bn1_g
        (const float*)d_in[7],   // bn1_b
        (const float*)d_in[10],  // v_b
        (const float*)d_in[12],  // t_b
        (const float*)d_in[13],  // bn2_g
        (const float*)d_in[14],  // bn2_b
        ws);
    cloudcrop_mfma<<<2048, 256, 0, stream>>>(
        (const float*)d_in[0],   // seed_xyz
        (const float*)d_in[1],   // pointcloud
        (const float*)d_in[2],   // vp_rot
        ws,
        (float*)d_out);
}

// Round 13
// 95.921 us; speedup vs baseline: 1.7383x; 1.0069x over previous
//
#include <hip/hip_runtime.h>

// CloudCrop fused MFMA kernel, round 13: R12 + scan stores only cand_i
// (merge re-rotates), fully-vectorized guarded selection loop (no scalar
// tail), setprio on all MFMA clusters. B=2,S=1024,N=10000,C=128,NS=64.

typedef _Float16 f16;
typedef _Float16 f16x2 __attribute__((ext_vector_type(2)));
typedef _Float16 f16x8 __attribute__((ext_vector_type(8)));
typedef _Float16 f16x4v __attribute__((ext_vector_type(4)));
typedef float f32x4 __attribute__((ext_vector_type(4)));
typedef unsigned int u32;
typedef u32 u32x2 __attribute__((ext_vector_type(2)));

constexpr int Nn = 10000;
constexpr float RAD2 = 0.05f * 0.05f;
constexpr float HMINf = -0.02f, HMAXf = 0.02f;
constexpr float INVV = 0.99999500003749968747f; // 1/sqrt(1+1e-5)

#define UPT_OFF 376832
#define SCAL_OFF 5496832

// s_q (8KB) multiplex offsets (temporally disjoint users):
#define CAND_I   0      // int [4][64]  (scan..merge)
#define IDX_OFF  1024   // int [64]     (merge..A)
#define CN4_OFF  1280   // int [4]
#define XYZ_OFF  1312   // f16 [64][32] (merge..A)
// Q then attT: full [64][128B] from phase B onward.

__device__ __forceinline__ int swzb(int row, int colbyte) {
    return colbyte ^ ((row & 7) << 4);
}
__device__ __forceinline__ u32 pk2(float a, float b) {
    return __builtin_bit_cast(u32, __builtin_amdgcn_cvt_pkrtz(a, b));
}

__global__ void prep_kernel(const float* __restrict__ mlp_w,
                            const float* __restrict__ qk_w,
                            const float* __restrict__ v_w,
                            const float* __restrict__ t_w,
                            const float* __restrict__ up,
                            const float* __restrict__ mlp_b,
                            const float* __restrict__ bn1g,
                            const float* __restrict__ bn1b,
                            const float* __restrict__ v_b,
                            const float* __restrict__ t_b,
                            const float* __restrict__ bn2g,
                            const float* __restrict__ bn2b,
                            unsigned char* __restrict__ ws) {
    const int blk = blockIdx.x;
    if (blk < 92) {
        const int tid = blk * 256 + threadIdx.x;  // < 368*64
        const int tile = tid >> 6, lane = tid & 63;
        const int ln = lane & 15, kg = lane >> 4;
        f16x8 v;
        if (tile < 80) {
            const int kc = tile / 16, ct = tile % 16;
            const int n = ct * 16 + ln, kb = kc * 32 + kg * 8;
            #pragma unroll
            for (int i = 0; i < 8; ++i) {
                const int k = kb + i;
                float x = (k < 128) ? mlp_w[n * 131 + 3 + k]
                        : ((k < 131) ? mlp_w[n * 131 + (k - 128)] : 0.f);
                v[i] = (f16)x;
            }
        } else if (tile < 112) {
            const int t2 = tile - 80; const int kc = t2 >> 2, ct = t2 & 3;
            const int n = ct * 16 + ln, kb = kc * 32 + kg * 8;
            #pragma unroll
            for (int i = 0; i < 8; ++i) v[i] = (f16)qk_w[n * 256 + kb + i];
        } else if (tile < 240) {
            const int t2 = tile - 112; const int kc = t2 >> 4, ct = t2 & 15;
            const int n = ct * 16 + ln, kb = kc * 32 + kg * 8;
            #pragma unroll
            for (int i = 0; i < 8; ++i) v[i] = (f16)v_w[n * 256 + kb + i];
        } else {
            const int t2 = tile - 240; const int kc = t2 >> 4, ct = t2 & 15;
            const int n = ct * 16 + ln, kb = kc * 32 + kg * 8;
            #pragma unroll
            for (int i = 0; i < 8; ++i) v[i] = (f16)t_w[n * 256 + kb + i];
        }
        *(f16x8*)(ws + (size_t)tid * 16) = v;
    } else if (blk < 92 + 314) {
        __shared__ f16 tile[64 * 136];
        const int bidx = blk - 92;
        const int b = bidx / 157;
        const int n0 = (bidx % 157) * 64;
        const int lane = threadIdx.x & 63;
        const int cw = threadIdx.x >> 6;
        const int n = n0 + lane;
        const float* upb = up + (size_t)b * 128 * Nn;
        #pragma unroll
        for (int i = 0; i < 32; ++i) {
            const int c = cw * 32 + i;
            const float x = (n < Nn) ? upb[(size_t)c * Nn + n] : 0.f;
            tile[lane * 136 + c] = (f16)x;
        }
        __syncthreads();
        f16* dst = (f16*)(ws + UPT_OFF) + (size_t)b * Nn * 128;
        #pragma unroll
        for (int p = 0; p < 4; ++p) {
            const int flat8 = threadIdx.x + p * 256;
            const int row = flat8 >> 4;
            const int c = (flat8 & 15) * 8;
            if (n0 + row < Nn)
                *(f16x8*)(dst + ((size_t)(n0 + row)) * 128 + c) =
                    *(const f16x8*)(tile + row * 136 + c);
        }
    } else {
        const int o = threadIdx.x;   // 0..255
        float* G1 = (float*)(ws + SCAL_OFF);
        float* C1 = G1 + 256;
        float* G2 = G1 + 512;
        float* C2 = G1 + 768;
        const float g1 = bn1g[o] * INVV;
        G1[o] = g1;
        C1[o] = mlp_b[o] * g1 + bn1b[o];
        const float g2 = bn2g[o] * INVV;
        G2[o] = g2;
        float vbwt = 0.f;
        const float* tw = t_w + o * 256;
        #pragma unroll 4
        for (int c = 0; c < 256; ++c) vbwt += v_b[c] * tw[c];
        C2[o] = (t_b[o] - vbwt) * g2 + bn2b[o];
    }
}

__launch_bounds__(256, 4)
__global__ void cloudcrop_mfma(
    const float* __restrict__ seed,  // (B,S,3)
    const float* __restrict__ pc,    // (B,N,3)
    const float* __restrict__ rot,   // (B,S,3,3)
    const unsigned char* __restrict__ ws,
    float* __restrict__ out)         // (B,256,S) f32
{
    __shared__ __align__(16) unsigned char s_x[64 * 512]; // X [64][256] f16 swz; Y in-place
    __shared__ __align__(16) unsigned char s_q[8192];     // multiplexed

    int*   cand_i  = (int*)(s_q + CAND_I);
    int*   idx_s   = (int*)(s_q + IDX_OFF);
    int*   cand_n4 = (int*)(s_q + CN4_OFF);
    f16*   s_xyz   = (f16*)(s_q + XYZ_OFF);   // [64][32]

    const float* G1 = (const float*)(ws + SCAL_OFF);
    const float* C1 = G1 + 256;
    const float* G2 = G1 + 512;
    const float* C2 = G1 + 768;

    // XCD-bijective swizzle: XCD k owns 256 consecutive grps
    const int grp = ((blockIdx.x & 7) << 8) | (blockIdx.x >> 3);
    const int bb = grp >> 10;
    const int s  = grp & 1023;
    const int t  = threadIdx.x;
    const int lane = t & 63;
    const int w    = t >> 6;
    const int ln   = lane & 15;
    const int kg   = lane >> 4;
    const int kg16 = kg * 16;
    const int g4   = kg * 4;

    // ---------- Phase 0: selection scan, float4-vectorized, exact order -----
    // stores only cand_i; rel coords re-rotated in merge (hits are rare)
    {
        const float sx = seed[grp*3+0], sy = seed[grp*3+1], sz = seed[grp*3+2];
        const float R0 = rot[grp*9+0], R1 = rot[grp*9+1], R2 = rot[grp*9+2];
        const float R3 = rot[grp*9+3], R4 = rot[grp*9+4], R5 = rot[grp*9+5];
        const float R6 = rot[grp*9+6], R7 = rot[grp*9+7], R8 = rot[grp*9+8];
        const unsigned long long lmask = (1ull << lane) - 1ull;
        int count = 0;
        const int lo = w * 2500, hi = lo + 2500;
        // 10 iterations of 256 points; last partially filled (2500 % 4 == 0
        // so a single nb<hi guard covers all 4 of a lane's points)
        for (int it = 0; it < 10; ++it) {
            const int nb = lo + it*256 + lane*4;
            bool m[4] = {false, false, false, false};
            if (nb < hi) {
                const float* p0 = pc + ((size_t)bb*Nn + nb)*3;
                const f32x4 A0 = *(const f32x4*)(p0);
                const f32x4 A1 = *(const f32x4*)(p0 + 4);
                const f32x4 A2 = *(const f32x4*)(p0 + 8);
                const float X[4] = {A0.x, A0.w, A1.z, A2.y};
                const float Y[4] = {A0.y, A1.x, A1.w, A2.z};
                const float Z[4] = {A0.z, A1.y, A2.x, A2.w};
                #pragma unroll
                for (int p = 0; p < 4; ++p) {
                    const float px = X[p] - sx, py = Y[p] - sy, pz = Z[p] - sz;
                    const float rx = px*R0 + py*R3 + pz*R6;
                    const float ry = px*R1 + py*R4 + pz*R7;
                    const float rz = px*R2 + py*R5 + pz*R8;
                    m[p] = (ry*ry + rz*rz < RAD2) && (rx > HMINf) && (rx < HMAXf);
                }
            }
            unsigned long long b[4];
            #pragma unroll
            for (int p = 0; p < 4; ++p) b[p] = __ballot(m[p]);
            int below = 0, tot = 0;
            #pragma unroll
            for (int p = 0; p < 4; ++p) {
                below += __popcll(b[p] & lmask);
                tot   += __popcll(b[p]);
            }
            int prefix = 0;
            #pragma unroll
            for (int p = 0; p < 4; ++p) {
                const int pos = count + below + prefix;
                if (m[p] && pos < 64) cand_i[w*64 + pos] = nb + p;
                prefix += (int)((b[p] >> lane) & 1ull);
            }
            count += tot;
        }
        if (lane == 0) cand_n4[w] = count < 64 ? count : 64;
    }
    __syncthreads();

    // ---------- Merge (ordered) -> idx_s; re-rotate rel coords -> xyz tile --
    if (t < 64) {
        const int c0 = cand_n4[0], c1 = cand_n4[1], c2 = cand_n4[2], c3 = cand_n4[3];
        const int o1 = c0, o2 = c0 + c1, o3 = o2 + c2;
        int total = o3 + c3; if (total > 64) total = 64;
        int myi = 0;
        if (total > 0) {
            const int pp = (t < total) ? t : 0;   // fill slots with global-first
            int sw_, sq;
            if      (pp >= o3) { sw_ = 3; sq = pp - o3; }
            else if (pp >= o2) { sw_ = 2; sq = pp - o2; }
            else if (pp >= o1) { sw_ = 1; sq = pp - o1; }
            else               { sw_ = 0; sq = pp; }
            myi = cand_i[sw_*64 + sq];
        }
        idx_s[t] = myi;
        // re-rotate (same math as scan; for total==0, myi=0 matches fallback)
        const float sx = seed[grp*3+0], sy = seed[grp*3+1], sz = seed[grp*3+2];
        const float px = pc[((size_t)bb*Nn + myi)*3+0] - sx;
        const float py = pc[((size_t)bb*Nn + myi)*3+1] - sy;
        const float pz = pc[((size_t)bb*Nn + myi)*3+2] - sz;
        const float rx = px*rot[grp*9+0] + py*rot[grp*9+3] + pz*rot[grp*9+6];
        const float ry = px*rot[grp*9+1] + py*rot[grp*9+4] + pz*rot[grp*9+7];
        const float rz = px*rot[grp*9+2] + py*rot[grp*9+5] + pz*rot[grp*9+8];
        f16x8 z0 = {};
        z0[0] = (f16)rx; z0[1] = (f16)ry; z0[2] = (f16)rz;
        f16x8 zz = {};
        f16x8* xr = (f16x8*)(s_xyz + t * 32);
        xr[0] = z0; xr[1] = zz; xr[2] = zz; xr[3] = zz;
    }
    __syncthreads();

    // ---------- Phase A (swapped): H = WA @ [feat|xyz]^T -> X ---------------
    {
        int idxr[4];
        #pragma unroll
        for (int nt = 0; nt < 4; ++nt) idxr[nt] = idx_s[nt*16 + ln];
        const f16* upTb = (const f16*)(ws + UPT_OFF) + (size_t)bb * Nn * 128;

        f32x4 acc[4][4] = {};   // [ch-tile jt][sample-tile nt]
        __builtin_amdgcn_s_setprio(1);
        #pragma unroll
        for (int kc = 0; kc < 4; ++kc) {
            f16x8 bX[4];
            #pragma unroll
            for (int nt = 0; nt < 4; ++nt)
                bX[nt] = *(const f16x8*)(upTb + (size_t)idxr[nt]*128 + kc*32 + kg*8);
            #pragma unroll
            for (int jt = 0; jt < 4; ++jt) {
                const f16x8 aw = *(const f16x8*)(ws + (size_t)(kc*16 + 4*w + jt)*1024 + lane*16);
                #pragma unroll
                for (int nt = 0; nt < 4; ++nt)
                    acc[jt][nt] = __builtin_amdgcn_mfma_f32_16x16x32_f16(aw, bX[nt], acc[jt][nt], 0, 0, 0);
            }
        }
        {   // kc = 4: xyz from LDS
            f16x8 bX[4];
            #pragma unroll
            for (int nt = 0; nt < 4; ++nt)
                bX[nt] = *(const f16x8*)(s_xyz + (nt*16 + ln)*32 + kg*8);
            #pragma unroll
            for (int jt = 0; jt < 4; ++jt) {
                const f16x8 aw = *(const f16x8*)(ws + (size_t)(64 + 4*w + jt)*1024 + lane*16);
                #pragma unroll
                for (int nt = 0; nt < 4; ++nt)
                    acc[jt][nt] = __builtin_amdgcn_mfma_f32_16x16x32_f16(aw, bX[nt], acc[jt][nt], 0, 0, 0);
            }
        }
        __builtin_amdgcn_s_setprio(0);
        #pragma unroll
        for (int jt = 0; jt < 4; ++jt) {
            const int chb = (4*w + jt)*16 + g4;
            const f32x4 g14 = *(const f32x4*)(G1 + chb);
            const f32x4 c14 = *(const f32x4*)(C1 + chb);
            #pragma unroll
            for (int nt = 0; nt < 4; ++nt) {
                const int smp = nt*16 + ln;
                float h[4];
                #pragma unroll
                for (int r = 0; r < 4; ++r)
                    h[r] = fmaxf(acc[jt][nt][r] * g14[r] + c14[r], 0.f);
                const u32x2 hv = { pk2(h[0], h[1]), pk2(h[2], h[3]) };
                *(u32x2*)(s_x + smp*512 + swzb(smp, chb*2)) = hv;
            }
        }
    }
    __syncthreads();

    // ---------- Phase B (swapped): Q = WQ @ X^T -> Q[smp][qch] --------------
    {
        f32x4 accq[4] = {};   // [nt]
        __builtin_amdgcn_s_setprio(1);
        #pragma unroll
        for (int kc = 0; kc < 8; ++kc) {
            const f16x8 aw = *(const f16x8*)(ws + (size_t)(80 + kc*4 + w)*1024 + lane*16);
            #pragma unroll
            for (int nt = 0; nt < 4; ++nt) {
                const int row = nt*16 + ln;
                const f16x8 bX = *(const f16x8*)(s_x + row*512 + swzb(row, kc*64 + kg16));
                accq[nt] = __builtin_amdgcn_mfma_f32_16x16x32_f16(aw, bX, accq[nt], 0, 0, 0);
            }
        }
        __builtin_amdgcn_s_setprio(0);
        const int qb = (w*16 + g4) * 2;   // byte offset of 4 consec qch
        #pragma unroll
        for (int nt = 0; nt < 4; ++nt) {
            const int smp = nt*16 + ln;
            const u32x2 pk = { pk2(accq[nt][0], accq[nt][1]),
                               pk2(accq[nt][2], accq[nt][3]) };
            *(u32x2*)(s_q + smp*128 + swzb(smp, qb)) = pk;
        }
    }
    __syncthreads();

    // ---------- Phase C: wave w owns rows w*16..+15 of S; in-wave softmax ---
    {
        f16x8 aQ[2];
        #pragma unroll
        for (int kc = 0; kc < 2; ++kc) {
            const int rowA = w*16 + ln;
            aQ[kc] = *(const f16x8*)(s_q + rowA*128 + swzb(rowA, kc*64 + kg16));
        }
        f32x4 accs[4];  // [ct]: S[w*16 + kg*4 + r][ct*16 + ln]
        #pragma unroll
        for (int ct = 0; ct < 4; ++ct) accs[ct] = (f32x4){0.f,0.f,0.f,0.f};
        __builtin_amdgcn_s_setprio(1);
        #pragma unroll
        for (int kc = 0; kc < 2; ++kc) {
            #pragma unroll
            for (int ct = 0; ct < 4; ++ct) {
                const int rowB = ct*16 + ln;
                const f16x8 bQ = *(const f16x8*)(s_q + rowB*128 + swzb(rowB, kc*64 + kg16));
                accs[ct] = __builtin_amdgcn_mfma_f32_16x16x32_f16(aQ[kc], bQ, accs[ct], 0, 0, 0);
            }
        }
        __builtin_amdgcn_s_setprio(0);
        // in-wave softmax per row r (row's 64 vals: 4 regs x 16 ln-lanes)
        float inv[4];
        #pragma unroll
        for (int r = 0; r < 4; ++r) {
            float mx = fmaxf(fmaxf(accs[0][r], accs[1][r]),
                             fmaxf(accs[2][r], accs[3][r]));
            mx = fmaxf(mx, __shfl_xor(mx, 1));
            mx = fmaxf(mx, __shfl_xor(mx, 2));
            mx = fmaxf(mx, __shfl_xor(mx, 4));
            mx = fmaxf(mx, __shfl_xor(mx, 8));
            float sm = 0.f;
            #pragma unroll
            for (int ct = 0; ct < 4; ++ct) {
                const float e = __expf(accs[ct][r] - mx);
                accs[ct][r] = e; sm += e;
            }
            sm += __shfl_xor(sm, 1);
            sm += __shfl_xor(sm, 2);
            sm += __shfl_xor(sm, 4);
            sm += __shfl_xor(sm, 8);
            inv[r] = __builtin_amdgcn_rcpf(sm);
        }
        __syncthreads();   // all waves done reading Q before attT overwrites
        const int ib = (w*16 + g4) * 2;   // byte offset of 4 consec i
        #pragma unroll
        for (int ct = 0; ct < 4; ++ct) {
            const int j = ct*16 + ln;
            const u32x2 pk = { pk2(accs[ct][0]*inv[0], accs[ct][1]*inv[1]),
                               pk2(accs[ct][2]*inv[2], accs[ct][3]*inv[3]) };
            *(u32x2*)(s_q + j*128 + swzb(j, ib)) = pk;
        }
    }
    __syncthreads();

    // ---------- Phase D: V=X@WV; shfl transpose; XR=attT@V -> f16 regs ------
    u32 xrpk[4][4][2];   // [j][rt][pair] f16x2, XR unscaled (32 VGPR)
    float rinv[4][4];
    {
        f16x8 a2[2][4];
        #pragma unroll
        for (int kc = 0; kc < 2; ++kc)
            #pragma unroll
            for (int rt = 0; rt < 4; ++rt) {
                const int row = rt*16 + ln;
                a2[kc][rt] = *(const f16x8*)(s_q + row*128 + swzb(row, kc*64 + kg16));
            }

        const int sbase = ln + ((lane >> 4) & 1) * 32;   // shfl src base
        const bool hiHalf = (kg >= 2);
        #pragma unroll
        for (int j = 0; j < 4; ++j) {
            f32x4 accv[4] = {};
            __builtin_amdgcn_s_setprio(1);
            #pragma unroll 2
            for (int kc = 0; kc < 8; ++kc) {
                const f16x8 bf = *(const f16x8*)(ws + (size_t)(112 + kc*16 + 4*w + j)*1024 + lane*16);
                #pragma unroll
                for (int rt = 0; rt < 4; ++rt) {
                    const int row = rt*16 + ln;
                    const f16x8 aX = *(const f16x8*)(s_x + row*512 + swzb(row, kc*64 + kg16));
                    accv[rt] = __builtin_amdgcn_mfma_f32_16x16x32_f16(aX, bf, accv[rt], 0, 0, 0);
                }
            }
            __builtin_amdgcn_s_setprio(0);
            // pack V to f16 pairs: pk[rt][p] = samples rt*16+g4+{2p,2p+1}
            u32 pk[4][2];
            #pragma unroll
            for (int rt = 0; rt < 4; ++rt) {
                pk[rt][0] = pk2(accv[rt][0], accv[rt][1]);
                pk[rt][1] = pk2(accv[rt][2], accv[rt][3]);
            }
            // route + XR MFMAs, result packed to f16 immediately
            f32x4 accrj[4] = {};
            #pragma unroll
            for (int kc = 0; kc < 2; ++kc) {
                union { u32 u[4]; f16x8 v; } bu;
                #pragma unroll
                for (int q = 0; q < 4; ++q) {
                    const int srcl = sbase + 16*(q >> 1);
                    const u32 lo = (u32)__shfl((int)pk[2*kc + 0][q & 1], srcl);
                    const u32 hi = (u32)__shfl((int)pk[2*kc + 1][q & 1], srcl);
                    bu.u[q] = hiHalf ? hi : lo;
                }
                #pragma unroll
                for (int rt = 0; rt < 4; ++rt)
                    accrj[rt] = __builtin_amdgcn_mfma_f32_16x16x32_f16(a2[kc][rt], bu.v, accrj[rt], 0, 0, 0);
            }
            #pragma unroll
            for (int rt = 0; rt < 4; ++rt) {
                xrpk[j][rt][0] = pk2(accrj[rt][0], accrj[rt][1]);
                xrpk[j][rt][1] = pk2(accrj[rt][2], accrj[rt][3]);
            }
        }
        // colsum via ones-MFMA after the j-loop (out of peak pressure)
        {
            f16x8 onef;
            #pragma unroll
            for (int i = 0; i < 8; ++i) onef[i] = (f16)1.0f;
            f32x4 accONE[4];
            #pragma unroll
            for (int rt = 0; rt < 4; ++rt) accONE[rt] = (f32x4){0.f,0.f,0.f,0.f};
            #pragma unroll
            for (int kc = 0; kc < 2; ++kc)
                #pragma unroll
                for (int rt = 0; rt < 4; ++rt)
                    accONE[rt] = __builtin_amdgcn_mfma_f32_16x16x32_f16(a2[kc][rt], onef, accONE[rt], 0, 0, 0);
            #pragma unroll
            for (int rt = 0; rt < 4; ++rt)
                #pragma unroll
                for (int r = 0; r < 4; ++r)
                    rinv[rt][r] = __builtin_amdgcn_rcpf(1e-9f + accONE[rt][r]);
        }
    }
    __syncthreads();  // all waves' X reads done before Y overwrite

    // ---------- D-epilogue: Y' = X - XR*rinv (in-place), keep X in regs -----
    f16x4v xsave[4][4];
    #pragma unroll
    for (int j = 0; j < 4; ++j) {
        const int col = (4*w + j)*16 + ln;
        #pragma unroll
        for (int rt = 0; rt < 4; ++rt) {
            const u32x2 p2 = { xrpk[j][rt][0], xrpk[j][rt][1] };
            const f16x4v xr4 = __builtin_bit_cast(f16x4v, p2);
            f16x4v xs4;
            #pragma unroll
            for (int r = 0; r < 4; ++r) {
                const int row = rt*16 + g4 + r;
                const f16 xv = *(const f16*)(s_x + row*512 + swzb(row, col*2));
                xs4[r] = xv;
                const float yv = (float)xv - (float)xr4[r] * rinv[rt][r];
                *(f16*)(s_x + row*512 + swzb(row, col*2)) = (f16)yv;
            }
            xsave[j][rt] = xs4;
        }
    }
    __syncthreads();

    // ---------- Phase E (split j-pairs): T = Y' @ WT; maxpool epilogue ------
    #pragma unroll
    for (int jp = 0; jp < 2; ++jp) {
        f32x4 acct[2][4] = {};   // [jj][rt] - 32 AGPR per pair
        __builtin_amdgcn_s_setprio(1);
        #pragma unroll 2
        for (int kc = 0; kc < 8; ++kc) {
            f16x8 a[4];
            #pragma unroll
            for (int rt = 0; rt < 4; ++rt) {
                const int row = rt*16 + ln;
                a[rt] = *(const f16x8*)(s_x + row*512 + swzb(row, kc*64 + kg16));  // Y'
            }
            #pragma unroll
            for (int jj = 0; jj < 2; ++jj) {
                const int j = jp*2 + jj;
                const f16x8 bf = *(const f16x8*)(ws + (size_t)(240 + kc*16 + 4*w + j)*1024 + lane*16);
                #pragma unroll
                for (int rt = 0; rt < 4; ++rt)
                    acct[jj][rt] = __builtin_amdgcn_mfma_f32_16x16x32_f16(a[rt], bf, acct[jj][rt], 0, 0, 0);
            }
        }
        __builtin_amdgcn_s_setprio(0);
        #pragma unroll
        for (int jj = 0; jj < 2; ++jj) {
            const int j = jp*2 + jj;
            const int col = (4*w + j)*16 + ln;
            const float g2 = G2[col], c2 = C2[col];
            float m = -3.4e38f;
            #pragma unroll
            for (int rt = 0; rt < 4; ++rt)
                #pragma unroll
                for (int r = 0; r < 4; ++r) {
                    const float rl = fmaxf(acct[jj][rt][r] * g2 + c2, 0.f);
                    const float xv = (float)xsave[j][rt][r];
                    m = fmaxf(m, xv + rl);
                }
            m = fmaxf(m, __shfl_xor(m, 16));
            m = fmaxf(m, __shfl_xor(m, 32));
            if (kg == 0)
                out[((size_t)bb*256 + col)*1024 + s] = m;
        }
    }
}

extern "C" void kernel_launch(void* const* d_in, const int* in_sizes, int n_in,
                              void* d_out, int out_size, void* d_ws, size_t ws_size,
                              hipStream_t stream) {
    (void)in_sizes; (void)n_in; (void)out_size; (void)ws_size;
    unsigned char* ws = (unsigned char*)d_ws;
    prep_kernel<<<92 + 314 + 1, 256, 0, stream>>>(
        (const float*)d_in[4],   // mlp_w
        (const float*)d_in[8],   // qk_w
        (const float*)d_in[9],   // v_w
        (const float*)d_in[11],  // t_w
        (const float*)d_in[3],   // up_feature
        (const float*)d_in[5],   // mlp_b
        (const float*)d_in[6],   // bn1_g
        (const float*)d_in[7],   // bn1_b
        (const float*)d_in[10],  // v_b
        (const float*)d_in[12],  // t_b
        (const float*)d_in[13],  // bn2_g
        (const float*)d_in[14],  // bn2_b
        ws);
    cloudcrop_mfma<<<2048, 256, 0, stream>>>(
        (const float*)d_in[0],   // seed_xyz
        (const float*)d_in[1],   // pointcloud
        (const float*)d_in[2],   // vp_rot
        ws,
        (float*)d_out);
}

// Round 14
// 88.515 us; speedup vs baseline: 1.8838x; 1.0837x over previous
//
#include <hip/hip_runtime.h>

// CloudCrop fused MFMA kernel, round 14: R13 + phase-D V-computation hoisted
// out of the j-loop (accv[4][4], X A-frags read once not 4x; attT frags
// loaded after V loop to keep peak regs ~90/108 <= 128).
// B=2,S=1024,N=10000,C=128,NS=64,hidden=256.

typedef _Float16 f16;
typedef _Float16 f16x2 __attribute__((ext_vector_type(2)));
typedef _Float16 f16x8 __attribute__((ext_vector_type(8)));
typedef _Float16 f16x4v __attribute__((ext_vector_type(4)));
typedef float f32x4 __attribute__((ext_vector_type(4)));
typedef unsigned int u32;
typedef u32 u32x2 __attribute__((ext_vector_type(2)));

constexpr int Nn = 10000;
constexpr float RAD2 = 0.05f * 0.05f;
constexpr float HMINf = -0.02f, HMAXf = 0.02f;
constexpr float INVV = 0.99999500003749968747f; // 1/sqrt(1+1e-5)

#define UPT_OFF 376832
#define SCAL_OFF 5496832

// s_q (8KB) multiplex offsets (temporally disjoint users):
#define CAND_I   0      // int [4][64]  (scan..merge)
#define IDX_OFF  1024   // int [64]     (merge..A)
#define CN4_OFF  1280   // int [4]
#define XYZ_OFF  1312   // f16 [64][32] (merge..A)
// Q then attT: full [64][128B] from phase B onward.

__device__ __forceinline__ int swzb(int row, int colbyte) {
    return colbyte ^ ((row & 7) << 4);
}
__device__ __forceinline__ u32 pk2(float a, float b) {
    return __builtin_bit_cast(u32, __builtin_amdgcn_cvt_pkrtz(a, b));
}

__global__ void prep_kernel(const float* __restrict__ mlp_w,
                            const float* __restrict__ qk_w,
                            const float* __restrict__ v_w,
                            const float* __restrict__ t_w,
                            const float* __restrict__ up,
                            const float* __restrict__ mlp_b,
                            const float* __restrict__ bn1g,
                            const float* __restrict__ bn1b,
                            const float* __restrict__ v_b,
                            const float* __restrict__ t_b,
                            const float* __restrict__ bn2g,
                            const float* __restrict__ bn2b,
                            unsigned char* __restrict__ ws) {
    const int blk = blockIdx.x;
    if (blk < 92) {
        const int tid = blk * 256 + threadIdx.x;  // < 368*64
        const int tile = tid >> 6, lane = tid & 63;
        const int ln = lane & 15, kg = lane >> 4;
        f16x8 v;
        if (tile < 80) {
            const int kc = tile / 16, ct = tile % 16;
            const int n = ct * 16 + ln, kb = kc * 32 + kg * 8;
            #pragma unroll
            for (int i = 0; i < 8; ++i) {
                const int k = kb + i;
                float x = (k < 128) ? mlp_w[n * 131 + 3 + k]
                        : ((k < 131) ? mlp_w[n * 131 + (k - 128)] : 0.f);
                v[i] = (f16)x;
            }
        } else if (tile < 112) {
            const int t2 = tile - 80; const int kc = t2 >> 2, ct = t2 & 3;
            const int n = ct * 16 + ln, kb = kc * 32 + kg * 8;
            #pragma unroll
            for (int i = 0; i < 8; ++i) v[i] = (f16)qk_w[n * 256 + kb + i];
        } else if (tile < 240) {
            const int t2 = tile - 112; const int kc = t2 >> 4, ct = t2 & 15;
            const int n = ct * 16 + ln, kb = kc * 32 + kg * 8;
            #pragma unroll
            for (int i = 0; i < 8; ++i) v[i] = (f16)v_w[n * 256 + kb + i];
        } else {
            const int t2 = tile - 240; const int kc = t2 >> 4, ct = t2 & 15;
            const int n = ct * 16 + ln, kb = kc * 32 + kg * 8;
            #pragma unroll
            for (int i = 0; i < 8; ++i) v[i] = (f16)t_w[n * 256 + kb + i];
        }
        *(f16x8*)(ws + (size_t)tid * 16) = v;
    } else if (blk < 92 + 314) {
        __shared__ f16 tile[64 * 136];
        const int bidx = blk - 92;
        const int b = bidx / 157;
        const int n0 = (bidx % 157) * 64;
        const int lane = threadIdx.x & 63;
        const int cw = threadIdx.x >> 6;
        const int n = n0 + lane;
        const float* upb = up + (size_t)b * 128 * Nn;
        #pragma unroll
        for (int i = 0; i < 32; ++i) {
            const int c = cw * 32 + i;
            const float x = (n < Nn) ? upb[(size_t)c * Nn + n] : 0.f;
            tile[lane * 136 + c] = (f16)x;
        }
        __syncthreads();
        f16* dst = (f16*)(ws + UPT_OFF) + (size_t)b * Nn * 128;
        #pragma unroll
        for (int p = 0; p < 4; ++p) {
            const int flat8 = threadIdx.x + p * 256;
            const int row = flat8 >> 4;
            const int c = (flat8 & 15) * 8;
            if (n0 + row < Nn)
                *(f16x8*)(dst + ((size_t)(n0 + row)) * 128 + c) =
                    *(const f16x8*)(tile + row * 136 + c);
        }
    } else {
        const int o = threadIdx.x;   // 0..255
        float* G1 = (float*)(ws + SCAL_OFF);
        float* C1 = G1 + 256;
        float* G2 = G1 + 512;
        float* C2 = G1 + 768;
        const float g1 = bn1g[o] * INVV;
        G1[o] = g1;
        C1[o] = mlp_b[o] * g1 + bn1b[o];
        const float g2 = bn2g[o] * INVV;
        G2[o] = g2;
        float vbwt = 0.f;
        const float* tw = t_w + o * 256;
        #pragma unroll 4
        for (int c = 0; c < 256; ++c) vbwt += v_b[c] * tw[c];
        C2[o] = (t_b[o] - vbwt) * g2 + bn2b[o];
    }
}

__launch_bounds__(256, 4)
__global__ void cloudcrop_mfma(
    const float* __restrict__ seed,  // (B,S,3)
    const float* __restrict__ pc,    // (B,N,3)
    const float* __restrict__ rot,   // (B,S,3,3)
    const unsigned char* __restrict__ ws,
    float* __restrict__ out)         // (B,256,S) f32
{
    __shared__ __align__(16) unsigned char s_x[64 * 512]; // X [64][256] f16 swz; Y in-place
    __shared__ __align__(16) unsigned char s_q[8192];     // multiplexed

    int*   cand_i  = (int*)(s_q + CAND_I);
    int*   idx_s   = (int*)(s_q + IDX_OFF);
    int*   cand_n4 = (int*)(s_q + CN4_OFF);
    f16*   s_xyz   = (f16*)(s_q + XYZ_OFF);   // [64][32]

    const float* G1 = (const float*)(ws + SCAL_OFF);
    const float* C1 = G1 + 256;
    const float* G2 = G1 + 512;
    const float* C2 = G1 + 768;

    // XCD-bijective swizzle: XCD k owns 256 consecutive grps
    const int grp = ((blockIdx.x & 7) << 8) | (blockIdx.x >> 3);
    const int bb = grp >> 10;
    const int s  = grp & 1023;
    const int t  = threadIdx.x;
    const int lane = t & 63;
    const int w    = t >> 6;
    const int ln   = lane & 15;
    const int kg   = lane >> 4;
    const int kg16 = kg * 16;
    const int g4   = kg * 4;

    // ---------- Phase 0: selection scan, float4-vectorized, exact order -----
    {
        const float sx = seed[grp*3+0], sy = seed[grp*3+1], sz = seed[grp*3+2];
        const float R0 = rot[grp*9+0], R1 = rot[grp*9+1], R2 = rot[grp*9+2];
        const float R3 = rot[grp*9+3], R4 = rot[grp*9+4], R5 = rot[grp*9+5];
        const float R6 = rot[grp*9+6], R7 = rot[grp*9+7], R8 = rot[grp*9+8];
        const unsigned long long lmask = (1ull << lane) - 1ull;
        int count = 0;
        const int lo = w * 2500, hi = lo + 2500;
        for (int it = 0; it < 10; ++it) {
            const int nb = lo + it*256 + lane*4;
            bool m[4] = {false, false, false, false};
            if (nb < hi) {
                const float* p0 = pc + ((size_t)bb*Nn + nb)*3;
                const f32x4 A0 = *(const f32x4*)(p0);
                const f32x4 A1 = *(const f32x4*)(p0 + 4);
                const f32x4 A2 = *(const f32x4*)(p0 + 8);
                const float X[4] = {A0.x, A0.w, A1.z, A2.y};
                const float Y[4] = {A0.y, A1.x, A1.w, A2.z};
                const float Z[4] = {A0.z, A1.y, A2.x, A2.w};
                #pragma unroll
                for (int p = 0; p < 4; ++p) {
                    const float px = X[p] - sx, py = Y[p] - sy, pz = Z[p] - sz;
                    const float rx = px*R0 + py*R3 + pz*R6;
                    const float ry = px*R1 + py*R4 + pz*R7;
                    const float rz = px*R2 + py*R5 + pz*R8;
                    m[p] = (ry*ry + rz*rz < RAD2) && (rx > HMINf) && (rx < HMAXf);
                }
            }
            unsigned long long b[4];
            #pragma unroll
            for (int p = 0; p < 4; ++p) b[p] = __ballot(m[p]);
            int below = 0, tot = 0;
            #pragma unroll
            for (int p = 0; p < 4; ++p) {
                below += __popcll(b[p] & lmask);
                tot   += __popcll(b[p]);
            }
            int prefix = 0;
            #pragma unroll
            for (int p = 0; p < 4; ++p) {
                const int pos = count + below + prefix;
                if (m[p] && pos < 64) cand_i[w*64 + pos] = nb + p;
                prefix += (int)((b[p] >> lane) & 1ull);
            }
            count += tot;
        }
        if (lane == 0) cand_n4[w] = count < 64 ? count : 64;
    }
    __syncthreads();

    // ---------- Merge (ordered) -> idx_s; re-rotate rel coords -> xyz tile --
    if (t < 64) {
        const int c0 = cand_n4[0], c1 = cand_n4[1], c2 = cand_n4[2], c3 = cand_n4[3];
        const int o1 = c0, o2 = c0 + c1, o3 = o2 + c2;
        int total = o3 + c3; if (total > 64) total = 64;
        int myi = 0;
        if (total > 0) {
            const int pp = (t < total) ? t : 0;   // fill slots with global-first
            int sw_, sq;
            if      (pp >= o3) { sw_ = 3; sq = pp - o3; }
            else if (pp >= o2) { sw_ = 2; sq = pp - o2; }
            else if (pp >= o1) { sw_ = 1; sq = pp - o1; }
            else               { sw_ = 0; sq = pp; }
            myi = cand_i[sw_*64 + sq];
        }
        idx_s[t] = myi;
        const float sx = seed[grp*3+0], sy = seed[grp*3+1], sz = seed[grp*3+2];
        const float px = pc[((size_t)bb*Nn + myi)*3+0] - sx;
        const float py = pc[((size_t)bb*Nn + myi)*3+1] - sy;
        const float pz = pc[((size_t)bb*Nn + myi)*3+2] - sz;
        const float rx = px*rot[grp*9+0] + py*rot[grp*9+3] + pz*rot[grp*9+6];
        const float ry = px*rot[grp*9+1] + py*rot[grp*9+4] + pz*rot[grp*9+7];
        const float rz = px*rot[grp*9+2] + py*rot[grp*9+5] + pz*rot[grp*9+8];
        f16x8 z0 = {};
        z0[0] = (f16)rx; z0[1] = (f16)ry; z0[2] = (f16)rz;
        f16x8 zz = {};
        f16x8* xr = (f16x8*)(s_xyz + t * 32);
        xr[0] = z0; xr[1] = zz; xr[2] = zz; xr[3] = zz;
    }
    __syncthreads();

    // ---------- Phase A (swapped): H = WA @ [feat|xyz]^T -> X ---------------
    {
        int idxr[4];
        #pragma unroll
        for (int nt = 0; nt < 4; ++nt) idxr[nt] = idx_s[nt*16 + ln];
        const f16* upTb = (const f16*)(ws + UPT_OFF) + (size_t)bb * Nn * 128;

        f32x4 acc[4][4] = {};   // [ch-tile jt][sample-tile nt]
        __builtin_amdgcn_s_setprio(1);
        #pragma unroll
        for (int kc = 0; kc < 4; ++kc) {
            f16x8 bX[4];
            #pragma unroll
            for (int nt = 0; nt < 4; ++nt)
                bX[nt] = *(const f16x8*)(upTb + (size_t)idxr[nt]*128 + kc*32 + kg*8);
            #pragma unroll
            for (int jt = 0; jt < 4; ++jt) {
                const f16x8 aw = *(const f16x8*)(ws + (size_t)(kc*16 + 4*w + jt)*1024 + lane*16);
                #pragma unroll
                for (int nt = 0; nt < 4; ++nt)
                    acc[jt][nt] = __builtin_amdgcn_mfma_f32_16x16x32_f16(aw, bX[nt], acc[jt][nt], 0, 0, 0);
            }
        }
        {   // kc = 4: xyz from LDS
            f16x8 bX[4];
            #pragma unroll
            for (int nt = 0; nt < 4; ++nt)
                bX[nt] = *(const f16x8*)(s_xyz + (nt*16 + ln)*32 + kg*8);
            #pragma unroll
            for (int jt = 0; jt < 4; ++jt) {
                const f16x8 aw = *(const f16x8*)(ws + (size_t)(64 + 4*w + jt)*1024 + lane*16);
                #pragma unroll
                for (int nt = 0; nt < 4; ++nt)
                    acc[jt][nt] = __builtin_amdgcn_mfma_f32_16x16x32_f16(aw, bX[nt], acc[jt][nt], 0, 0, 0);
            }
        }
        __builtin_amdgcn_s_setprio(0);
        #pragma unroll
        for (int jt = 0; jt < 4; ++jt) {
            const int chb = (4*w + jt)*16 + g4;
            const f32x4 g14 = *(const f32x4*)(G1 + chb);
            const f32x4 c14 = *(const f32x4*)(C1 + chb);
            #pragma unroll
            for (int nt = 0; nt < 4; ++nt) {
                const int smp = nt*16 + ln;
                float h[4];
                #pragma unroll
                for (int r = 0; r < 4; ++r)
                    h[r] = fmaxf(acc[jt][nt][r] * g14[r] + c14[r], 0.f);
                const u32x2 hv = { pk2(h[0], h[1]), pk2(h[2], h[3]) };
                *(u32x2*)(s_x + smp*512 + swzb(smp, chb*2)) = hv;
            }
        }
    }
    __syncthreads();

    // ---------- Phase B (swapped): Q = WQ @ X^T -> Q[smp][qch] --------------
    {
        f32x4 accq[4] = {};   // [nt]
        __builtin_amdgcn_s_setprio(1);
        #pragma unroll
        for (int kc = 0; kc < 8; ++kc) {
            const f16x8 aw = *(const f16x8*)(ws + (size_t)(80 + kc*4 + w)*1024 + lane*16);
            #pragma unroll
            for (int nt = 0; nt < 4; ++nt) {
                const int row = nt*16 + ln;
                const f16x8 bX = *(const f16x8*)(s_x + row*512 + swzb(row, kc*64 + kg16));
                accq[nt] = __builtin_amdgcn_mfma_f32_16x16x32_f16(aw, bX, accq[nt], 0, 0, 0);
            }
        }
        __builtin_amdgcn_s_setprio(0);
        const int qb = (w*16 + g4) * 2;   // byte offset of 4 consec qch
        #pragma unroll
        for (int nt = 0; nt < 4; ++nt) {
            const int smp = nt*16 + ln;
            const u32x2 pk = { pk2(accq[nt][0], accq[nt][1]),
                               pk2(accq[nt][2], accq[nt][3]) };
            *(u32x2*)(s_q + smp*128 + swzb(smp, qb)) = pk;
        }
    }
    __syncthreads();

    // ---------- Phase C: wave w owns rows w*16..+15 of S; in-wave softmax ---
    {
        f16x8 aQ[2];
        #pragma unroll
        for (int kc = 0; kc < 2; ++kc) {
            const int rowA = w*16 + ln;
            aQ[kc] = *(const f16x8*)(s_q + rowA*128 + swzb(rowA, kc*64 + kg16));
        }
        f32x4 accs[4];  // [ct]: S[w*16 + kg*4 + r][ct*16 + ln]
        #pragma unroll
        for (int ct = 0; ct < 4; ++ct) accs[ct] = (f32x4){0.f,0.f,0.f,0.f};
        __builtin_amdgcn_s_setprio(1);
        #pragma unroll
        for (int kc = 0; kc < 2; ++kc) {
            #pragma unroll
            for (int ct = 0; ct < 4; ++ct) {
                const int rowB = ct*16 + ln;
                const f16x8 bQ = *(const f16x8*)(s_q + rowB*128 + swzb(rowB, kc*64 + kg16));
                accs[ct] = __builtin_amdgcn_mfma_f32_16x16x32_f16(aQ[kc], bQ, accs[ct], 0, 0, 0);
            }
        }
        __builtin_amdgcn_s_setprio(0);
        float inv[4];
        #pragma unroll
        for (int r = 0; r < 4; ++r) {
            float mx = fmaxf(fmaxf(accs[0][r], accs[1][r]),
                             fmaxf(accs[2][r], accs[3][r]));
            mx = fmaxf(mx, __shfl_xor(mx, 1));
            mx = fmaxf(mx, __shfl_xor(mx, 2));
            mx = fmaxf(mx, __shfl_xor(mx, 4));
            mx = fmaxf(mx, __shfl_xor(mx, 8));
            float sm = 0.f;
            #pragma unroll
            for (int ct = 0; ct < 4; ++ct) {
                const float e = __expf(accs[ct][r] - mx);
                accs[ct][r] = e; sm += e;
            }
            sm += __shfl_xor(sm, 1);
            sm += __shfl_xor(sm, 2);
            sm += __shfl_xor(sm, 4);
            sm += __shfl_xor(sm, 8);
            inv[r] = __builtin_amdgcn_rcpf(sm);
        }
        __syncthreads();   // all waves done reading Q before attT overwrites
        const int ib = (w*16 + g4) * 2;   // byte offset of 4 consec i
        #pragma unroll
        for (int ct = 0; ct < 4; ++ct) {
            const int j = ct*16 + ln;
            const u32x2 pk = { pk2(accs[ct][0]*inv[0], accs[ct][1]*inv[1]),
                               pk2(accs[ct][2]*inv[2], accs[ct][3]*inv[3]) };
            *(u32x2*)(s_q + j*128 + swzb(j, ib)) = pk;
        }
    }
    __syncthreads();

    // ---------- Phase D: V=X@WV hoisted (accv[4][4], X read once);
    //            then per-j {pack, shfl route, XR mfma -> f16 regs} ----------
    u32 xrpk[4][4][2];   // [j][rt][pair] f16x2, XR unscaled (32 VGPR)
    float rinv[4][4];
    {
        // V = X @ WV for all 4 channel tiles (X A-frags read ONCE)
        f32x4 accv[4][4];   // [j][rt] - 64 AGPR
        #pragma unroll
        for (int j = 0; j < 4; ++j)
            #pragma unroll
            for (int rt = 0; rt < 4; ++rt) accv[j][rt] = (f32x4){0.f,0.f,0.f,0.f};
        __builtin_amdgcn_s_setprio(1);
        #pragma unroll 2
        for (int kc = 0; kc < 8; ++kc) {
            f16x8 aX[4];
            #pragma unroll
            for (int rt = 0; rt < 4; ++rt) {
                const int row = rt*16 + ln;
                aX[rt] = *(const f16x8*)(s_x + row*512 + swzb(row, kc*64 + kg16));
            }
            #pragma unroll
            for (int j = 0; j < 4; ++j) {
                const f16x8 bf = *(const f16x8*)(ws + (size_t)(112 + kc*16 + 4*w + j)*1024 + lane*16);
                #pragma unroll
                for (int rt = 0; rt < 4; ++rt)
                    accv[j][rt] = __builtin_amdgcn_mfma_f32_16x16x32_f16(aX[rt], bf, accv[j][rt], 0, 0, 0);
            }
        }
        __builtin_amdgcn_s_setprio(0);

        // attT A-frags (loaded AFTER V loop to keep it out of the V peak)
        f16x8 a2[2][4];
        #pragma unroll
        for (int kc = 0; kc < 2; ++kc)
            #pragma unroll
            for (int rt = 0; rt < 4; ++rt) {
                const int row = rt*16 + ln;
                a2[kc][rt] = *(const f16x8*)(s_q + row*128 + swzb(row, kc*64 + kg16));
            }

        const int sbase = ln + ((lane >> 4) & 1) * 32;   // shfl src base
        const bool hiHalf = (kg >= 2);
        #pragma unroll
        for (int j = 0; j < 4; ++j) {
            // pack V[j] to f16 pairs (frees accv[j])
            u32 pk[4][2];
            #pragma unroll
            for (int rt = 0; rt < 4; ++rt) {
                pk[rt][0] = pk2(accv[j][rt][0], accv[j][rt][1]);
                pk[rt][1] = pk2(accv[j][rt][2], accv[j][rt][3]);
            }
            // route + XR MFMAs, result packed to f16 immediately
            f32x4 accrj[4] = {};
            #pragma unroll
            for (int kc = 0; kc < 2; ++kc) {
                union { u32 u[4]; f16x8 v; } bu;
                #pragma unroll
                for (int q = 0; q < 4; ++q) {
                    const int srcl = sbase + 16*(q >> 1);
                    const u32 lo = (u32)__shfl((int)pk[2*kc + 0][q & 1], srcl);
                    const u32 hi = (u32)__shfl((int)pk[2*kc + 1][q & 1], srcl);
                    bu.u[q] = hiHalf ? hi : lo;
                }
                #pragma unroll
                for (int rt = 0; rt < 4; ++rt)
                    accrj[rt] = __builtin_amdgcn_mfma_f32_16x16x32_f16(a2[kc][rt], bu.v, accrj[rt], 0, 0, 0);
            }
            #pragma unroll
            for (int rt = 0; rt < 4; ++rt) {
                xrpk[j][rt][0] = pk2(accrj[rt][0], accrj[rt][1]);
                xrpk[j][rt][1] = pk2(accrj[rt][2], accrj[rt][3]);
            }
        }
        // colsum via ones-MFMA after the j-loop (out of peak pressure)
        {
            f16x8 onef;
            #pragma unroll
            for (int i = 0; i < 8; ++i) onef[i] = (f16)1.0f;
            f32x4 accONE[4];
            #pragma unroll
            for (int rt = 0; rt < 4; ++rt) accONE[rt] = (f32x4){0.f,0.f,0.f,0.f};
            #pragma unroll
            for (int kc = 0; kc < 2; ++kc)
                #pragma unroll
                for (int rt = 0; rt < 4; ++rt)
                    accONE[rt] = __builtin_amdgcn_mfma_f32_16x16x32_f16(a2[kc][rt], onef, accONE[rt], 0, 0, 0);
            #pragma unroll
            for (int rt = 0; rt < 4; ++rt)
                #pragma unroll
                for (int r = 0; r < 4; ++r)
                    rinv[rt][r] = __builtin_amdgcn_rcpf(1e-9f + accONE[rt][r]);
        }
    }
    __syncthreads();  // all waves' X reads done before Y overwrite

    // ---------- D-epilogue: Y' = X - XR*rinv (in-place), keep X in regs -----
    f16x4v xsave[4][4];
    #pragma unroll
    for (int j = 0; j < 4; ++j) {
        const int col = (4*w + j)*16 + ln;
        #pragma unroll
        for (int rt = 0; rt < 4; ++rt) {
            const u32x2 p2 = { xrpk[j][rt][0], xrpk[j][rt][1] };
            const f16x4v xr4 = __builtin_bit_cast(f16x4v, p2);
            f16x4v xs4;
            #pragma unroll
            for (int r = 0; r < 4; ++r) {
                const int row = rt*16 + g4 + r;
                const f16 xv = *(const f16*)(s_x + row*512 + swzb(row, col*2));
                xs4[r] = xv;
                const float yv = (float)xv - (float)xr4[r] * rinv[rt][r];
                *(f16*)(s_x + row*512 + swzb(row, col*2)) = (f16)yv;
            }
            xsave[j][rt] = xs4;
        }
    }
    __syncthreads();

    // ---------- Phase E (split j-pairs): T = Y' @ WT; maxpool epilogue ------
    #pragma unroll
    for (int jp = 0; jp < 2; ++jp) {
        f32x4 acct[2][4] = {};   // [jj][rt] - 32 AGPR per pair
        __builtin_amdgcn_s_setprio(1);
        #pragma unroll 2
        for (int kc = 0; kc < 8; ++kc) {
            f16x8 a[4];
            #pragma unroll
            for (int rt = 0; rt < 4; ++rt) {
                const int row = rt*16 + ln;
                a[rt] = *(const f16x8*)(s_x + row*512 + swzb(row, kc*64 + kg16));  // Y'
            }
            #pragma unroll
            for (int jj = 0; jj < 2; ++jj) {
                const int j = jp*2 + jj;
                const f16x8 bf = *(const f16x8*)(ws + (size_t)(240 + kc*16 + 4*w + j)*1024 + lane*16);
                #pragma unroll
                for (int rt = 0; rt < 4; ++rt)
                    acct[jj][rt] = __builtin_amdgcn_mfma_f32_16x16x32_f16(a[rt], bf, acct[jj][rt], 0, 0, 0);
            }
        }
        __builtin_amdgcn_s_setprio(0);
        #pragma unroll
        for (int jj = 0; jj < 2; ++jj) {
            const int j = jp*2 + jj;
            const int col = (4*w + j)*16 + ln;
            const float g2 = G2[col], c2 = C2[col];
            float m = -3.4e38f;
            #pragma unroll
            for (int rt = 0; rt < 4; ++rt)
                #pragma unroll
                for (int r = 0; r < 4; ++r) {
                    const float rl = fmaxf(acct[jj][rt][r] * g2 + c2, 0.f);
                    const float xv = (float)xsave[j][rt][r];
                    m = fmaxf(m, xv + rl);
                }
            m = fmaxf(m, __shfl_xor(m, 16));
            m = fmaxf(m, __shfl_xor(m, 32));
            if (kg == 0)
                out[((size_t)bb*256 + col)*1024 + s] = m;
        }
    }
}

extern "C" void kernel_launch(void* const* d_in, const int* in_sizes, int n_in,
                              void* d_out, int out_size, void* d_ws, size_t ws_size,
                              hipStream_t stream) {
    (void)in_sizes; (void)n_in; (void)out_size; (void)ws_size;
    unsigned char* ws = (unsigned char*)d_ws;
    prep_kernel<<<92 + 314 + 1, 256, 0, stream>>>(
        (const float*)d_in[4],   // mlp_w
        (const float*)d_in[8],   // qk_w
        (const float*)d_in[9],   // v_w
        (const float*)d_in[11],  // t_w
        (const float*)d_in[3],   // up_feature
        (const float*)d_in[5],   // mlp_b
        (const float*)d_in[6],   // bn1_g
        (const float*)d_in[7],   // bn1_b
        (const float*)d_in[10],  // v_b
        (const float*)d_in[12],  // t_b
        (const float*)d_in[13],  // bn2_g
        (const float*)d_in[14],  // bn2_b
        ws);
    cloudcrop_mfma<<<2048, 256, 0, stream>>>(
        (const float*)d_in[0],   // seed_xyz
        (const float*)d_in[1],   // pointcloud
        (const float*)d_in[2],   // vp_rot
        ws,
        (float*)d_out);
}

// Round 15
// 88.416 us; speedup vs baseline: 1.8858x; 1.0011x over previous
//
#include <hip/hip_runtime.h>

// CloudCrop fused MFMA kernel, round 15: R14 + scan split 9-unconditional/
// 1-guarded iterations, prep vbwt fold vectorized (float4).
// B=2,S=1024,N=10000,C=128,NS=64,hidden=256.

typedef _Float16 f16;
typedef _Float16 f16x2 __attribute__((ext_vector_type(2)));
typedef _Float16 f16x8 __attribute__((ext_vector_type(8)));
typedef _Float16 f16x4v __attribute__((ext_vector_type(4)));
typedef float f32x4 __attribute__((ext_vector_type(4)));
typedef unsigned int u32;
typedef u32 u32x2 __attribute__((ext_vector_type(2)));

constexpr int Nn = 10000;
constexpr float RAD2 = 0.05f * 0.05f;
constexpr float HMINf = -0.02f, HMAXf = 0.02f;
constexpr float INVV = 0.99999500003749968747f; // 1/sqrt(1+1e-5)

#define UPT_OFF 376832
#define SCAL_OFF 5496832

// s_q (8KB) multiplex offsets (temporally disjoint users):
#define CAND_I   0      // int [4][64]  (scan..merge)
#define IDX_OFF  1024   // int [64]     (merge..A)
#define CN4_OFF  1280   // int [4]
#define XYZ_OFF  1312   // f16 [64][32] (merge..A)
// Q then attT: full [64][128B] from phase B onward.

__device__ __forceinline__ int swzb(int row, int colbyte) {
    return colbyte ^ ((row & 7) << 4);
}
__device__ __forceinline__ u32 pk2(float a, float b) {
    return __builtin_bit_cast(u32, __builtin_amdgcn_cvt_pkrtz(a, b));
}

__global__ void prep_kernel(const float* __restrict__ mlp_w,
                            const float* __restrict__ qk_w,
                            const float* __restrict__ v_w,
                            const float* __restrict__ t_w,
                            const float* __restrict__ up,
                            const float* __restrict__ mlp_b,
                            const float* __restrict__ bn1g,
                            const float* __restrict__ bn1b,
                            const float* __restrict__ v_b,
                            const float* __restrict__ t_b,
                            const float* __restrict__ bn2g,
                            const float* __restrict__ bn2b,
                            unsigned char* __restrict__ ws) {
    const int blk = blockIdx.x;
    if (blk < 92) {
        const int tid = blk * 256 + threadIdx.x;  // < 368*64
        const int tile = tid >> 6, lane = tid & 63;
        const int ln = lane & 15, kg = lane >> 4;
        f16x8 v;
        if (tile < 80) {
            const int kc = tile / 16, ct = tile % 16;
            const int n = ct * 16 + ln, kb = kc * 32 + kg * 8;
            #pragma unroll
            for (int i = 0; i < 8; ++i) {
                const int k = kb + i;
                float x = (k < 128) ? mlp_w[n * 131 + 3 + k]
                        : ((k < 131) ? mlp_w[n * 131 + (k - 128)] : 0.f);
                v[i] = (f16)x;
            }
        } else if (tile < 112) {
            const int t2 = tile - 80; const int kc = t2 >> 2, ct = t2 & 3;
            const int n = ct * 16 + ln, kb = kc * 32 + kg * 8;
            #pragma unroll
            for (int i = 0; i < 8; ++i) v[i] = (f16)qk_w[n * 256 + kb + i];
        } else if (tile < 240) {
            const int t2 = tile - 112; const int kc = t2 >> 4, ct = t2 & 15;
            const int n = ct * 16 + ln, kb = kc * 32 + kg * 8;
            #pragma unroll
            for (int i = 0; i < 8; ++i) v[i] = (f16)v_w[n * 256 + kb + i];
        } else {
            const int t2 = tile - 240; const int kc = t2 >> 4, ct = t2 & 15;
            const int n = ct * 16 + ln, kb = kc * 32 + kg * 8;
            #pragma unroll
            for (int i = 0; i < 8; ++i) v[i] = (f16)t_w[n * 256 + kb + i];
        }
        *(f16x8*)(ws + (size_t)tid * 16) = v;
    } else if (blk < 92 + 314) {
        __shared__ f16 tile[64 * 136];
        const int bidx = blk - 92;
        const int b = bidx / 157;
        const int n0 = (bidx % 157) * 64;
        const int lane = threadIdx.x & 63;
        const int cw = threadIdx.x >> 6;
        const int n = n0 + lane;
        const float* upb = up + (size_t)b * 128 * Nn;
        #pragma unroll
        for (int i = 0; i < 32; ++i) {
            const int c = cw * 32 + i;
            const float x = (n < Nn) ? upb[(size_t)c * Nn + n] : 0.f;
            tile[lane * 136 + c] = (f16)x;
        }
        __syncthreads();
        f16* dst = (f16*)(ws + UPT_OFF) + (size_t)b * Nn * 128;
        #pragma unroll
        for (int p = 0; p < 4; ++p) {
            const int flat8 = threadIdx.x + p * 256;
            const int row = flat8 >> 4;
            const int c = (flat8 & 15) * 8;
            if (n0 + row < Nn)
                *(f16x8*)(dst + ((size_t)(n0 + row)) * 128 + c) =
                    *(const f16x8*)(tile + row * 136 + c);
        }
    } else {
        const int o = threadIdx.x;   // 0..255
        float* G1 = (float*)(ws + SCAL_OFF);
        float* C1 = G1 + 256;
        float* G2 = G1 + 512;
        float* C2 = G1 + 768;
        const float g1 = bn1g[o] * INVV;
        G1[o] = g1;
        C1[o] = mlp_b[o] * g1 + bn1b[o];
        const float g2 = bn2g[o] * INVV;
        G2[o] = g2;
        // vbwt[o] = sum_c v_b[c]*t_w[o][c], vectorized float4
        float vbwt = 0.f;
        const f32x4* tw4 = (const f32x4*)(t_w + o * 256);
        const f32x4* vb4 = (const f32x4*)v_b;
        #pragma unroll 4
        for (int c4 = 0; c4 < 64; ++c4) {
            const f32x4 a = tw4[c4], b = vb4[c4];
            vbwt += a.x*b.x + a.y*b.y + a.z*b.z + a.w*b.w;
        }
        C2[o] = (t_b[o] - vbwt) * g2 + bn2b[o];
    }
}

__launch_bounds__(256, 4)
__global__ void cloudcrop_mfma(
    const float* __restrict__ seed,  // (B,S,3)
    const float* __restrict__ pc,    // (B,N,3)
    const float* __restrict__ rot,   // (B,S,3,3)
    const unsigned char* __restrict__ ws,
    float* __restrict__ out)         // (B,256,S) f32
{
    __shared__ __align__(16) unsigned char s_x[64 * 512]; // X [64][256] f16 swz; Y in-place
    __shared__ __align__(16) unsigned char s_q[8192];     // multiplexed

    int*   cand_i  = (int*)(s_q + CAND_I);
    int*   idx_s   = (int*)(s_q + IDX_OFF);
    int*   cand_n4 = (int*)(s_q + CN4_OFF);
    f16*   s_xyz   = (f16*)(s_q + XYZ_OFF);   // [64][32]

    const float* G1 = (const float*)(ws + SCAL_OFF);
    const float* C1 = G1 + 256;
    const float* G2 = G1 + 512;
    const float* C2 = G1 + 768;

    // XCD-bijective swizzle: XCD k owns 256 consecutive grps
    const int grp = ((blockIdx.x & 7) << 8) | (blockIdx.x >> 3);
    const int bb = grp >> 10;
    const int s  = grp & 1023;
    const int t  = threadIdx.x;
    const int lane = t & 63;
    const int w    = t >> 6;
    const int ln   = lane & 15;
    const int kg   = lane >> 4;
    const int kg16 = kg * 16;
    const int g4   = kg * 4;

    // ---------- Phase 0: selection scan, float4-vectorized, exact order -----
    {
        const float sx = seed[grp*3+0], sy = seed[grp*3+1], sz = seed[grp*3+2];
        const float R0 = rot[grp*9+0], R1 = rot[grp*9+1], R2 = rot[grp*9+2];
        const float R3 = rot[grp*9+3], R4 = rot[grp*9+4], R5 = rot[grp*9+5];
        const float R6 = rot[grp*9+6], R7 = rot[grp*9+7], R8 = rot[grp*9+8];
        const unsigned long long lmask = (1ull << lane) - 1ull;
        int count = 0;
        const int lo = w * 2500, hi = lo + 2500;
        // 9 unconditional iterations of 256 points (lane holds 4 consecutive)
        for (int it = 0; it < 9; ++it) {
            const int nb = lo + it*256 + lane*4;
            const float* p0 = pc + ((size_t)bb*Nn + nb)*3;
            const f32x4 A0 = *(const f32x4*)(p0);
            const f32x4 A1 = *(const f32x4*)(p0 + 4);
            const f32x4 A2 = *(const f32x4*)(p0 + 8);
            const float X[4] = {A0.x, A0.w, A1.z, A2.y};
            const float Y[4] = {A0.y, A1.x, A1.w, A2.z};
            const float Z[4] = {A0.z, A1.y, A2.x, A2.w};
            bool m[4];
            #pragma unroll
            for (int p = 0; p < 4; ++p) {
                const float px = X[p] - sx, py = Y[p] - sy, pz = Z[p] - sz;
                const float rx = px*R0 + py*R3 + pz*R6;
                const float ry = px*R1 + py*R4 + pz*R7;
                const float rz = px*R2 + py*R5 + pz*R8;
                m[p] = (ry*ry + rz*rz < RAD2) && (rx > HMINf) && (rx < HMAXf);
            }
            unsigned long long b[4];
            #pragma unroll
            for (int p = 0; p < 4; ++p) b[p] = __ballot(m[p]);
            int below = 0, tot = 0;
            #pragma unroll
            for (int p = 0; p < 4; ++p) {
                below += __popcll(b[p] & lmask);
                tot   += __popcll(b[p]);
            }
            int prefix = 0;
            #pragma unroll
            for (int p = 0; p < 4; ++p) {
                const int pos = count + below + prefix;
                if (m[p] && pos < 64) cand_i[w*64 + pos] = nb + p;
                prefix += (int)((b[p] >> lane) & 1ull);
            }
            count += tot;
        }
        {   // final guarded iteration: points lo+2304 .. hi-1 (196 pts)
            const int nb = lo + 2304 + lane*4;
            bool m[4] = {false, false, false, false};
            if (nb < hi) {
                const float* p0 = pc + ((size_t)bb*Nn + nb)*3;
                const f32x4 A0 = *(const f32x4*)(p0);
                const f32x4 A1 = *(const f32x4*)(p0 + 4);
                const f32x4 A2 = *(const f32x4*)(p0 + 8);
                const float X[4] = {A0.x, A0.w, A1.z, A2.y};
                const float Y[4] = {A0.y, A1.x, A1.w, A2.z};
                const float Z[4] = {A0.z, A1.y, A2.x, A2.w};
                #pragma unroll
                for (int p = 0; p < 4; ++p) {
                    const float px = X[p] - sx, py = Y[p] - sy, pz = Z[p] - sz;
                    const float rx = px*R0 + py*R3 + pz*R6;
                    const float ry = px*R1 + py*R4 + pz*R7;
                    const float rz = px*R2 + py*R5 + pz*R8;
                    m[p] = (ry*ry + rz*rz < RAD2) && (rx > HMINf) && (rx < HMAXf);
                }
            }
            unsigned long long b[4];
            #pragma unroll
            for (int p = 0; p < 4; ++p) b[p] = __ballot(m[p]);
            int below = 0, tot = 0;
            #pragma unroll
            for (int p = 0; p < 4; ++p) {
                below += __popcll(b[p] & lmask);
                tot   += __popcll(b[p]);
            }
            int prefix = 0;
            #pragma unroll
            for (int p = 0; p < 4; ++p) {
                const int pos = count + below + prefix;
                if (m[p] && pos < 64) cand_i[w*64 + pos] = nb + p;
                prefix += (int)((b[p] >> lane) & 1ull);
            }
            count += tot;
        }
        if (lane == 0) cand_n4[w] = count < 64 ? count : 64;
    }
    __syncthreads();

    // ---------- Merge (ordered) -> idx_s; re-rotate rel coords -> xyz tile --
    if (t < 64) {
        const int c0 = cand_n4[0], c1 = cand_n4[1], c2 = cand_n4[2], c3 = cand_n4[3];
        const int o1 = c0, o2 = c0 + c1, o3 = o2 + c2;
        int total = o3 + c3; if (total > 64) total = 64;
        int myi = 0;
        if (total > 0) {
            const int pp = (t < total) ? t : 0;   // fill slots with global-first
            int sw_, sq;
            if      (pp >= o3) { sw_ = 3; sq = pp - o3; }
            else if (pp >= o2) { sw_ = 2; sq = pp - o2; }
            else if (pp >= o1) { sw_ = 1; sq = pp - o1; }
            else               { sw_ = 0; sq = pp; }
            myi = cand_i[sw_*64 + sq];
        }
        idx_s[t] = myi;
        const float sx = seed[grp*3+0], sy = seed[grp*3+1], sz = seed[grp*3+2];
        const float px = pc[((size_t)bb*Nn + myi)*3+0] - sx;
        const float py = pc[((size_t)bb*Nn + myi)*3+1] - sy;
        const float pz = pc[((size_t)bb*Nn + myi)*3+2] - sz;
        const float rx = px*rot[grp*9+0] + py*rot[grp*9+3] + pz*rot[grp*9+6];
        const float ry = px*rot[grp*9+1] + py*rot[grp*9+4] + pz*rot[grp*9+7];
        const float rz = px*rot[grp*9+2] + py*rot[grp*9+5] + pz*rot[grp*9+8];
        f16x8 z0 = {};
        z0[0] = (f16)rx; z0[1] = (f16)ry; z0[2] = (f16)rz;
        f16x8 zz = {};
        f16x8* xr = (f16x8*)(s_xyz + t * 32);
        xr[0] = z0; xr[1] = zz; xr[2] = zz; xr[3] = zz;
    }
    __syncthreads();

    // ---------- Phase A (swapped): H = WA @ [feat|xyz]^T -> X ---------------
    {
        int idxr[4];
        #pragma unroll
        for (int nt = 0; nt < 4; ++nt) idxr[nt] = idx_s[nt*16 + ln];
        const f16* upTb = (const f16*)(ws + UPT_OFF) + (size_t)bb * Nn * 128;

        f32x4 acc[4][4] = {};   // [ch-tile jt][sample-tile nt]
        __builtin_amdgcn_s_setprio(1);
        #pragma unroll
        for (int kc = 0; kc < 4; ++kc) {
            f16x8 bX[4];
            #pragma unroll
            for (int nt = 0; nt < 4; ++nt)
                bX[nt] = *(const f16x8*)(upTb + (size_t)idxr[nt]*128 + kc*32 + kg*8);
            #pragma unroll
            for (int jt = 0; jt < 4; ++jt) {
                const f16x8 aw = *(const f16x8*)(ws + (size_t)(kc*16 + 4*w + jt)*1024 + lane*16);
                #pragma unroll
                for (int nt = 0; nt < 4; ++nt)
                    acc[jt][nt] = __builtin_amdgcn_mfma_f32_16x16x32_f16(aw, bX[nt], acc[jt][nt], 0, 0, 0);
            }
        }
        {   // kc = 4: xyz from LDS
            f16x8 bX[4];
            #pragma unroll
            for (int nt = 0; nt < 4; ++nt)
                bX[nt] = *(const f16x8*)(s_xyz + (nt*16 + ln)*32 + kg*8);
            #pragma unroll
            for (int jt = 0; jt < 4; ++jt) {
                const f16x8 aw = *(const f16x8*)(ws + (size_t)(64 + 4*w + jt)*1024 + lane*16);
                #pragma unroll
                for (int nt = 0; nt < 4; ++nt)
                    acc[jt][nt] = __builtin_amdgcn_mfma_f32_16x16x32_f16(aw, bX[nt], acc[jt][nt], 0, 0, 0);
            }
        }
        __builtin_amdgcn_s_setprio(0);
        #pragma unroll
        for (int jt = 0; jt < 4; ++jt) {
            const int chb = (4*w + jt)*16 + g4;
            const f32x4 g14 = *(const f32x4*)(G1 + chb);
            const f32x4 c14 = *(const f32x4*)(C1 + chb);
            #pragma unroll
            for (int nt = 0; nt < 4; ++nt) {
                const int smp = nt*16 + ln;
                float h[4];
                #pragma unroll
                for (int r = 0; r < 4; ++r)
                    h[r] = fmaxf(acc[jt][nt][r] * g14[r] + c14[r], 0.f);
                const u32x2 hv = { pk2(h[0], h[1]), pk2(h[2], h[3]) };
                *(u32x2*)(s_x + smp*512 + swzb(smp, chb*2)) = hv;
            }
        }
    }
    __syncthreads();

    // ---------- Phase B (swapped): Q = WQ @ X^T -> Q[smp][qch] --------------
    {
        f32x4 accq[4] = {};   // [nt]
        __builtin_amdgcn_s_setprio(1);
        #pragma unroll
        for (int kc = 0; kc < 8; ++kc) {
            const f16x8 aw = *(const f16x8*)(ws + (size_t)(80 + kc*4 + w)*1024 + lane*16);
            #pragma unroll
            for (int nt = 0; nt < 4; ++nt) {
                const int row = nt*16 + ln;
                const f16x8 bX = *(const f16x8*)(s_x + row*512 + swzb(row, kc*64 + kg16));
                accq[nt] = __builtin_amdgcn_mfma_f32_16x16x32_f16(aw, bX, accq[nt], 0, 0, 0);
            }
        }
        __builtin_amdgcn_s_setprio(0);
        const int qb = (w*16 + g4) * 2;   // byte offset of 4 consec qch
        #pragma unroll
        for (int nt = 0; nt < 4; ++nt) {
            const int smp = nt*16 + ln;
            const u32x2 pk = { pk2(accq[nt][0], accq[nt][1]),
                               pk2(accq[nt][2], accq[nt][3]) };
            *(u32x2*)(s_q + smp*128 + swzb(smp, qb)) = pk;
        }
    }
    __syncthreads();

    // ---------- Phase C: wave w owns rows w*16..+15 of S; in-wave softmax ---
    {
        f16x8 aQ[2];
        #pragma unroll
        for (int kc = 0; kc < 2; ++kc) {
            const int rowA = w*16 + ln;
            aQ[kc] = *(const f16x8*)(s_q + rowA*128 + swzb(rowA, kc*64 + kg16));
        }
        f32x4 accs[4];  // [ct]: S[w*16 + kg*4 + r][ct*16 + ln]
        #pragma unroll
        for (int ct = 0; ct < 4; ++ct) accs[ct] = (f32x4){0.f,0.f,0.f,0.f};
        __builtin_amdgcn_s_setprio(1);
        #pragma unroll
        for (int kc = 0; kc < 2; ++kc) {
            #pragma unroll
            for (int ct = 0; ct < 4; ++ct) {
                const int rowB = ct*16 + ln;
                const f16x8 bQ = *(const f16x8*)(s_q + rowB*128 + swzb(rowB, kc*64 + kg16));
                accs[ct] = __builtin_amdgcn_mfma_f32_16x16x32_f16(aQ[kc], bQ, accs[ct], 0, 0, 0);
            }
        }
        __builtin_amdgcn_s_setprio(0);
        float inv[4];
        #pragma unroll
        for (int r = 0; r < 4; ++r) {
            float mx = fmaxf(fmaxf(accs[0][r], accs[1][r]),
                             fmaxf(accs[2][r], accs[3][r]));
            mx = fmaxf(mx, __shfl_xor(mx, 1));
            mx = fmaxf(mx, __shfl_xor(mx, 2));
            mx = fmaxf(mx, __shfl_xor(mx, 4));
            mx = fmaxf(mx, __shfl_xor(mx, 8));
            float sm = 0.f;
            #pragma unroll
            for (int ct = 0; ct < 4; ++ct) {
                const float e = __expf(accs[ct][r] - mx);
                accs[ct][r] = e; sm += e;
            }
            sm += __shfl_xor(sm, 1);
            sm += __shfl_xor(sm, 2);
            sm += __shfl_xor(sm, 4);
            sm += __shfl_xor(sm, 8);
            inv[r] = __builtin_amdgcn_rcpf(sm);
        }
        __syncthreads();   // all waves done reading Q before attT overwrites
        const int ib = (w*16 + g4) * 2;   // byte offset of 4 consec i
        #pragma unroll
        for (int ct = 0; ct < 4; ++ct) {
            const int j = ct*16 + ln;
            const u32x2 pk = { pk2(accs[ct][0]*inv[0], accs[ct][1]*inv[1]),
                               pk2(accs[ct][2]*inv[2], accs[ct][3]*inv[3]) };
            *(u32x2*)(s_q + j*128 + swzb(j, ib)) = pk;
        }
    }
    __syncthreads();

    // ---------- Phase D: V=X@WV hoisted (accv[4][4], X read once);
    //            then per-j {pack, shfl route, XR mfma -> f16 regs} ----------
    u32 xrpk[4][4][2];   // [j][rt][pair] f16x2, XR unscaled (32 VGPR)
    float rinv[4][4];
    {
        f32x4 accv[4][4];   // [j][rt] - 64 AGPR
        #pragma unroll
        for (int j = 0; j < 4; ++j)
            #pragma unroll
            for (int rt = 0; rt < 4; ++rt) accv[j][rt] = (f32x4){0.f,0.f,0.f,0.f};
        __builtin_amdgcn_s_setprio(1);
        #pragma unroll 2
        for (int kc = 0; kc < 8; ++kc) {
            f16x8 aX[4];
            #pragma unroll
            for (int rt = 0; rt < 4; ++rt) {
                const int row = rt*16 + ln;
                aX[rt] = *(const f16x8*)(s_x + row*512 + swzb(row, kc*64 + kg16));
            }
            #pragma unroll
            for (int j = 0; j < 4; ++j) {
                const f16x8 bf = *(const f16x8*)(ws + (size_t)(112 + kc*16 + 4*w + j)*1024 + lane*16);
                #pragma unroll
                for (int rt = 0; rt < 4; ++rt)
                    accv[j][rt] = __builtin_amdgcn_mfma_f32_16x16x32_f16(aX[rt], bf, accv[j][rt], 0, 0, 0);
            }
        }
        __builtin_amdgcn_s_setprio(0);

        f16x8 a2[2][4];
        #pragma unroll
        for (int kc = 0; kc < 2; ++kc)
            #pragma unroll
            for (int rt = 0; rt < 4; ++rt) {
                const int row = rt*16 + ln;
                a2[kc][rt] = *(const f16x8*)(s_q + row*128 + swzb(row, kc*64 + kg16));
            }

        const int sbase = ln + ((lane >> 4) & 1) * 32;   // shfl src base
        const bool hiHalf = (kg >= 2);
        #pragma unroll
        for (int j = 0; j < 4; ++j) {
            u32 pk[4][2];
            #pragma unroll
            for (int rt = 0; rt < 4; ++rt) {
                pk[rt][0] = pk2(accv[j][rt][0], accv[j][rt][1]);
                pk[rt][1] = pk2(accv[j][rt][2], accv[j][rt][3]);
            }
            f32x4 accrj[4] = {};
            #pragma unroll
            for (int kc = 0; kc < 2; ++kc) {
                union { u32 u[4]; f16x8 v; } bu;
                #pragma unroll
                for (int q = 0; q < 4; ++q) {
                    const int srcl = sbase + 16*(q >> 1);
                    const u32 lo = (u32)__shfl((int)pk[2*kc + 0][q & 1], srcl);
                    const u32 hi = (u32)__shfl((int)pk[2*kc + 1][q & 1], srcl);
                    bu.u[q] = hiHalf ? hi : lo;
                }
                #pragma unroll
                for (int rt = 0; rt < 4; ++rt)
                    accrj[rt] = __builtin_amdgcn_mfma_f32_16x16x32_f16(a2[kc][rt], bu.v, accrj[rt], 0, 0, 0);
            }
            #pragma unroll
            for (int rt = 0; rt < 4; ++rt) {
                xrpk[j][rt][0] = pk2(accrj[rt][0], accrj[rt][1]);
                xrpk[j][rt][1] = pk2(accrj[rt][2], accrj[rt][3]);
            }
        }
        // colsum via ones-MFMA after the j-loop (out of peak pressure)
        {
            f16x8 onef;
            #pragma unroll
            for (int i = 0; i < 8; ++i) onef[i] = (f16)1.0f;
            f32x4 accONE[4];
            #pragma unroll
            for (int rt = 0; rt < 4; ++rt) accONE[rt] = (f32x4){0.f,0.f,0.f,0.f};
            #pragma unroll
            for (int kc = 0; kc < 2; ++kc)
                #pragma unroll
                for (int rt = 0; rt < 4; ++rt)
                    accONE[rt] = __builtin_amdgcn_mfma_f32_16x16x32_f16(a2[kc][rt], onef, accONE[rt], 0, 0, 0);
            #pragma unroll
            for (int rt = 0; rt < 4; ++rt)
                #pragma unroll
                for (int r = 0; r < 4; ++r)
                    rinv[rt][r] = __builtin_amdgcn_rcpf(1e-9f + accONE[rt][r]);
        }
    }
    __syncthreads();  // all waves' X reads done before Y overwrite

    // ---------- D-epilogue: Y' = X - XR*rinv (in-place), keep X in regs -----
    f16x4v xsave[4][4];
    #pragma unroll
    for (int j = 0; j < 4; ++j) {
        const int col = (4*w + j)*16 + ln;
        #pragma unroll
        for (int rt = 0; rt < 4; ++rt) {
            const u32x2 p2 = { xrpk[j][rt][0], xrpk[j][rt][1] };
            const f16x4v xr4 = __builtin_bit_cast(f16x4v, p2);
            f16x4v xs4;
            #pragma unroll
            for (int r = 0; r < 4; ++r) {
                const int row = rt*16 + g4 + r;
                const f16 xv = *(const f16*)(s_x + row*512 + swzb(row, col*2));
                xs4[r] = xv;
                const float yv = (float)xv - (float)xr4[r] * rinv[rt][r];
                *(f16*)(s_x + row*512 + swzb(row, col*2)) = (f16)yv;
            }
            xsave[j][rt] = xs4;
        }
    }
    __syncthreads();

    // ---------- Phase E (split j-pairs): T = Y' @ WT; maxpool epilogue ------
    #pragma unroll
    for (int jp = 0; jp < 2; ++jp) {
        f32x4 acct[2][4] = {};   // [jj][rt] - 32 AGPR per pair
        __builtin_amdgcn_s_setprio(1);
        #pragma unroll 2
        for (int kc = 0; kc < 8; ++kc) {
            f16x8 a[4];
            #pragma unroll
            for (int rt = 0; rt < 4; ++rt) {
                const int row = rt*16 + ln;
                a[rt] = *(const f16x8*)(s_x + row*512 + swzb(row, kc*64 + kg16));  // Y'
            }
            #pragma unroll
            for (int jj = 0; jj < 2; ++jj) {
                const int j = jp*2 + jj;
                const f16x8 bf = *(const f16x8*)(ws + (size_t)(240 + kc*16 + 4*w + j)*1024 + lane*16);
                #pragma unroll
                for (int rt = 0; rt < 4; ++rt)
                    acct[jj][rt] = __builtin_amdgcn_mfma_f32_16x16x32_f16(a[rt], bf, acct[jj][rt], 0, 0, 0);
            }
        }
        __builtin_amdgcn_s_setprio(0);
        #pragma unroll
        for (int jj = 0; jj < 2; ++jj) {
            const int j = jp*2 + jj;
            const int col = (4*w + j)*16 + ln;
            const float g2 = G2[col], c2 = C2[col];
            float m = -3.4e38f;
            #pragma unroll
            for (int rt = 0; rt < 4; ++rt)
                #pragma unroll
                for (int r = 0; r < 4; ++r) {
                    const float rl = fmaxf(acct[jj][rt][r] * g2 + c2, 0.f);
                    const float xv = (float)xsave[j][rt][r];
                    m = fmaxf(m, xv + rl);
                }
            m = fmaxf(m, __shfl_xor(m, 16));
            m = fmaxf(m, __shfl_xor(m, 32));
            if (kg == 0)
                out[((size_t)bb*256 + col)*1024 + s] = m;
        }
    }
}

extern "C" void kernel_launch(void* const* d_in, const int* in_sizes, int n_in,
                              void* d_out, int out_size, void* d_ws, size_t ws_size,
                              hipStream_t stream) {
    (void)in_sizes; (void)n_in; (void)out_size; (void)ws_size;
    unsigned char* ws = (unsigned char*)d_ws;
    prep_kernel<<<92 + 314 + 1, 256, 0, stream>>>(
        (const float*)d_in[4],   // mlp_w
        (const float*)d_in[8],   // qk_w
        (const float*)d_in[9],   // v_w
        (const float*)d_in[11],  // t_w
        (const float*)d_in[3],   // up_feature
        (const float*)d_in[5],   // mlp_b
        (const float*)d_in[6],   // bn1_g
        (const float*)d_in[7],   // bn1_b
        (const float*)d_in[10],  // v_b
        (const float*)d_in[12],  // t_b
        (const float*)d_in[13],  // bn2_g
        (const float*)d_in[14],  // bn2_b
        ws);
    cloudcrop_mfma<<<2048, 256, 0, stream>>>(
        (const float*)d_in[0],   // seed_xyz
        (const float*)d_in[1],   // pointcloud
        (const float*)d_in[2],   // vp_rot
        ws,
        (float*)d_out);
}